// Round 1
// baseline (1115.882 us; speedup 1.0000x reference)
//
#include <hip/hip_runtime.h>

// Problem constants (SpeakerAwareCTC): B=16, T=1000, D=512, V=5000, U=64, S=2U+1=129
#define NB 16
#define NT 1000
#define ND 512
#define NV 5000
#define NU 64

typedef short short8v __attribute__((ext_vector_type(8)));
typedef float float4v __attribute__((ext_vector_type(4)));

#define NEGINF (-__builtin_inff())

__device__ __forceinline__ short f2bf(float x) {
  unsigned int u = __builtin_bit_cast(unsigned int, x);
  unsigned int r = (u + 0x7fffu + ((u >> 16) & 1u)) >> 16;
  return (short)(unsigned short)r;
}

__device__ __forceinline__ float lae2(float a, float b) {
  float m = fmaxf(a, b);
  if (m == NEGINF) return NEGINF;
  return m + __logf(__expf(a - m) + __expf(b - m));
}
__device__ __forceinline__ float lae3(float a, float b, float c) {
  float m = fmaxf(fmaxf(a, b), c);
  if (m == NEGINF) return NEGINF;
  return m + __logf(__expf(a - m) + __expf(b - m) + __expf(c - m));
}
// faithful port of reference log_substraction_exp (incl. sentinel branch)
__device__ __forceinline__ float log_sub_exp(float a, float b) {
  bool inf_a = __builtin_isinf(a), inf_b = __builtin_isinf(b);
  bool mask1 = (!inf_a) && (!inf_b);
  float a_ = mask1 ? a : -1.0f;
  float b_ = mask1 ? b : -2.0f;
  float tmp = b_ + __logf(__expf(a_ - b_) - 1.0f);
  if (__builtin_isinf(tmp)) {
    a_ = -2000.0f; b_ = -2001.0f;
    tmp = b_ + __logf(__expf(a_ - b_) - 1.0f);
  }
  float res = mask1 ? tmp : NEGINF;
  if ((!inf_a) && inf_b) res = a;
  return res;
}
__device__ __forceinline__ void lse_upd(float& m, float& s, float x) {
  if (x == NEGINF) return;
  if (x > m) { s = s * __expf(m - x) + 1.0f; m = x; }
  else       { s += __expf(x - m); }
}

// ---------------- kernel 0: zero the scalar output -------------------------
__global__ void k_zero(float* out) {
  if (threadIdx.x == 0) out[0] = 0.0f;
}

// ---------------- kernel 1: hs f32 -> bf16 (same layout) -------------------
__global__ __launch_bounds__(256) void k_cvt_hs(const float* __restrict__ in,
                                                short* __restrict__ out) {
  size_t i = (size_t)blockIdx.x * 256 + threadIdx.x;  // 1,024,000 threads, 8 elems each
  const float4* p = (const float4*)in + i * 2;
  float4 v0 = p[0], v1 = p[1];
  short8v r;
  r[0] = f2bf(v0.x); r[1] = f2bf(v0.y); r[2] = f2bf(v0.z); r[3] = f2bf(v0.w);
  r[4] = f2bf(v1.x); r[5] = f2bf(v1.y); r[6] = f2bf(v1.z); r[7] = f2bf(v1.w);
  *(short8v*)(out + i * 8) = r;
}

// ------------- kernel 2: W [512][5000] f32 -> WT [5000][512] bf16 ----------
__global__ __launch_bounds__(256) void k_cvt_wt(const float* __restrict__ W,
                                                short* __restrict__ WT) {
  __shared__ short tile[64 * 72];
  int n0 = blockIdx.x * 64, k0 = blockIdx.y * 64;
  int tid = threadIdx.x;
  int kr = tid >> 2, part = tid & 3;
  const float* src = W + (size_t)(k0 + kr) * NV + n0 + part * 16;
#pragma unroll
  for (int jj = 0; jj < 4; ++jj) {
    int c = n0 + part * 16 + jj * 4;
    float4 v;
    if (c + 3 < NV) {
      v = *(const float4*)(src + jj * 4);
    } else {
      v.x = (c + 0 < NV) ? src[jj * 4 + 0] : 0.f;
      v.y = (c + 1 < NV) ? src[jj * 4 + 1] : 0.f;
      v.z = (c + 2 < NV) ? src[jj * 4 + 2] : 0.f;
      v.w = (c + 3 < NV) ? src[jj * 4 + 3] : 0.f;
    }
    int base = kr * 72 + part * 16 + jj * 4;
    tile[base + 0] = f2bf(v.x); tile[base + 1] = f2bf(v.y);
    tile[base + 2] = f2bf(v.z); tile[base + 3] = f2bf(v.w);
  }
  __syncthreads();
  int n = tid & 63, kq = tid >> 6;
  if (n0 + n < NV) {
#pragma unroll
    for (int half = 0; half < 2; ++half) {
      short8v val;
#pragma unroll
      for (int jj = 0; jj < 8; ++jj) val[jj] = tile[(kq * 16 + half * 8 + jj) * 72 + n];
      *(short8v*)(WT + (size_t)(n0 + n) * ND + k0 + kq * 16 + half * 8) = val;
    }
  }
}

// -------- kernel 3: gather Wg[b][k][u] = W[k][lab(b,u)] (f32) --------------
__global__ void k_gather(const float* __restrict__ W, const int* __restrict__ ys,
                         float* __restrict__ Wg) {
  int k = blockIdx.x, b = blockIdx.y, u = threadIdx.x;
  if (u < NU + 1) {
    int lab = (u == 0) ? 0 : ys[b * NU + u - 1];
    Wg[((size_t)b * ND + k) * (NU + 1) + u] = W[(size_t)k * NV + lab];
  }
}

// -------- kernel 4: ll[b][t][u] = hs[b,t,:] . Wg[b,:,u] + bias[lab] --------
__global__ __launch_bounds__(128) void k_lab(const float* __restrict__ hs,
                                             const float* __restrict__ Wg,
                                             const int* __restrict__ ys,
                                             const float* __restrict__ bias,
                                             float* __restrict__ ll) {
  __shared__ float hsr[ND];
  int t = blockIdx.x, b = blockIdx.y, tid = threadIdx.x;
  ((float4*)hsr)[tid] = ((const float4*)(hs + ((size_t)(b * NT + t)) * ND))[tid];
  __syncthreads();
  if (tid < NU + 1) {
    const float* wg = Wg + (size_t)b * ND * (NU + 1) + tid;
    float acc = 0.f;
#pragma unroll 8
    for (int k = 0; k < ND; ++k) acc += hsr[k] * wg[(size_t)k * (NU + 1)];
    int lab = (tid == 0) ? 0 : ys[b * NU + tid - 1];
    ll[((size_t)(b * NT + t)) * (NU + 1) + tid] = acc + bias[lab];
  }
}

// -------- kernel 5: denom[b][t] = logsumexp_v(hs@W + b) via bf16 MFMA ------
// block: 256 thr (4 waves as 2x2), tile 64 rows x 128 cols/chunk, K-stage 64,
// double-buffered LDS, online (m,s) per row; cross-wave merge at end.
__global__ __launch_bounds__(256) void k_denom(const short* __restrict__ hsb,
                                               const short* __restrict__ WT,
                                               const float* __restrict__ bias,
                                               float* __restrict__ denom) {
  constexpr int NCHUNK = 40;          // ceil(5000/128)
  constexpr int NST = NCHUNK * 8;     // 8 K-stages (of 64) per chunk
  __shared__ short As[2][64 * 72];
  __shared__ short Ws[2][128 * 72];
  __shared__ float mred[64][2];
  __shared__ float sred[64][2];

  int b = blockIdx.y, t0 = blockIdx.x * 64;
  int tid = threadIdx.x;
  int lane = tid & 63, wave = tid >> 6;
  int wm = wave >> 1, wn = wave & 1;
  int lrow = lane & 15, lkhi = lane >> 4;

  // staging assignments (consecutive lanes -> consecutive LDS rows: 2-way banks)
  int ar = tid & 63, apart = tid >> 6;      // A: 64 rows x (4 x 16 halves)
  int wr = tid & 127, whalf = tid >> 7;     // W: 128 rows x (2 x 32 halves)
  bool avalid = (t0 + ar) < NT;
  const short* arow = hsb + ((size_t)(b * NT) + (t0 + ar)) * ND;

  float4v acc[2][4];
  float mrun[2][4], srun[2][4];
#pragma unroll
  for (int fa = 0; fa < 2; ++fa)
#pragma unroll
    for (int fb = 0; fb < 4; ++fb) {
#pragma unroll
      for (int j = 0; j < 4; ++j) acc[fa][fb][j] = 0.f;
    }
#pragma unroll
  for (int fa = 0; fa < 2; ++fa)
#pragma unroll
    for (int j = 0; j < 4; ++j) { mrun[fa][j] = NEGINF; srun[fa][j] = 0.f; }

  short8v a_rg[2], w_rg[4];
  const short8v zero8 = {0, 0, 0, 0, 0, 0, 0, 0};

  auto issue_loads = [&](int s) {
    int chunk = s >> 3, ks = s & 7;
    int k0 = ks * 64, n0 = chunk * 128;
    if (avalid) {
      const short8v* pa = (const short8v*)(arow + k0 + apart * 16);
      a_rg[0] = pa[0]; a_rg[1] = pa[1];
    } else { a_rg[0] = zero8; a_rg[1] = zero8; }
    int n = n0 + wr;
    if (n < NV) {
      const short8v* pw = (const short8v*)(WT + (size_t)n * ND + k0 + whalf * 32);
      w_rg[0] = pw[0]; w_rg[1] = pw[1]; w_rg[2] = pw[2]; w_rg[3] = pw[3];
    } else { w_rg[0] = zero8; w_rg[1] = zero8; w_rg[2] = zero8; w_rg[3] = zero8; }
  };
  auto write_stage = [&](int bw) {
    *(short8v*)&As[bw][ar * 72 + apart * 16 + 0] = a_rg[0];
    *(short8v*)&As[bw][ar * 72 + apart * 16 + 8] = a_rg[1];
    short* wd = &Ws[bw][wr * 72 + whalf * 32];
    *(short8v*)(wd + 0)  = w_rg[0];
    *(short8v*)(wd + 8)  = w_rg[1];
    *(short8v*)(wd + 16) = w_rg[2];
    *(short8v*)(wd + 24) = w_rg[3];
  };
  auto compute = [&](int s) {
    int buf = s & 1;
#pragma unroll
    for (int kk = 0; kk < 2; ++kk) {
      short8v a0 = *(const short8v*)&As[buf][(wm * 32 + 0 + lrow) * 72 + kk * 32 + lkhi * 8];
      short8v a1 = *(const short8v*)&As[buf][(wm * 32 + 16 + lrow) * 72 + kk * 32 + lkhi * 8];
#pragma unroll
      for (int fb = 0; fb < 4; ++fb) {
        short8v bv = *(const short8v*)&Ws[buf][(wn * 64 + fb * 16 + lrow) * 72 + kk * 32 + lkhi * 8];
        acc[0][fb] = __builtin_amdgcn_mfma_f32_16x16x32_bf16(a0, bv, acc[0][fb], 0, 0, 0);
        acc[1][fb] = __builtin_amdgcn_mfma_f32_16x16x32_bf16(a1, bv, acc[1][fb], 0, 0, 0);
      }
    }
  };
  auto epilogue = [&](int chunk) {
    int n0 = chunk * 128;
    float bcol[4]; bool cval[4];
#pragma unroll
    for (int fb = 0; fb < 4; ++fb) {
      int c = n0 + wn * 64 + fb * 16 + lrow;
      cval[fb] = c < NV;
      bcol[fb] = cval[fb] ? bias[c] : 0.f;
    }
#pragma unroll
    for (int fa = 0; fa < 2; ++fa)
#pragma unroll
      for (int j = 0; j < 4; ++j) {
        float mx = NEGINF;
#pragma unroll
        for (int fb = 0; fb < 4; ++fb) {
          float v = cval[fb] ? acc[fa][fb][j] + bcol[fb] : NEGINF;
          mx = fmaxf(mx, v);
        }
#pragma unroll
        for (int d = 1; d < 16; d <<= 1) mx = fmaxf(mx, __shfl_xor(mx, d));
        float mn = fmaxf(mrun[fa][j], mx);
        float p = 0.f;
#pragma unroll
        for (int fb = 0; fb < 4; ++fb) {
          float v = cval[fb] ? acc[fa][fb][j] + bcol[fb] : NEGINF;
          p += __expf(v - mn);
        }
#pragma unroll
        for (int d = 1; d < 16; d <<= 1) p += __shfl_xor(p, d);
        srun[fa][j] = srun[fa][j] * __expf(mrun[fa][j] - mn) + p;
        mrun[fa][j] = mn;
      }
#pragma unroll
    for (int fa = 0; fa < 2; ++fa)
#pragma unroll
      for (int fb = 0; fb < 4; ++fb)
#pragma unroll
        for (int j = 0; j < 4; ++j) acc[fa][fb][j] = 0.f;
  };

  // prologue: stage 0 into buf 0
  issue_loads(0);
  write_stage(0);
  for (int s = 0; s < NST; ++s) {
    __syncthreads();
    if (s + 1 < NST) issue_loads(s + 1);
    compute(s);
    if (s + 1 < NST) write_stage((s + 1) & 1);
    if ((s & 7) == 7) epilogue(s >> 3);
  }

  // cross-wave (wn) merge
  if (lrow == 0) {
#pragma unroll
    for (int fa = 0; fa < 2; ++fa)
#pragma unroll
      for (int j = 0; j < 4; ++j) {
        int row = wm * 32 + fa * 16 + lkhi * 4 + j;
        mred[row][wn] = mrun[fa][j];
        sred[row][wn] = srun[fa][j];
      }
  }
  __syncthreads();
  if (tid < 64) {
    int t = t0 + tid;
    if (t < NT) {
      float m0 = mred[tid][0], m1 = mred[tid][1];
      float m = fmaxf(m0, m1);
      float ss = sred[tid][0] * __expf(m0 - m) + sred[tid][1] * __expf(m1 - m);
      denom[b * NT + t] = m + __logf(ss);
    }
  }
}

// -------- kernel 6: CTC trellis fwd+bwd + fused loss, 1 wave per batch -----
__global__ __launch_bounds__(64) void k_trellis(const float* __restrict__ ll,
                                                const float* __restrict__ denom,
                                                const int* __restrict__ ys,
                                                const int* __restrict__ hlens,
                                                float* __restrict__ aod,
                                                float* __restrict__ out) {
  int b = blockIdx.x, l = threadIdx.x;  // lane l holds states 2l, 2l+1
  int lab = ys[b * NU + l];
  bool skip  = (l >= 1) && (lab != ys[b * NU + l - 1]);
  bool skipn = (l < NU - 1) && (ys[b * NU + l + 1] != lab);
  const float* llb = ll + (size_t)b * NT * (NU + 1);
  const float* denb = denom + b * NT;
  float* aodb = aod + (size_t)b * NT * NU;

  // ---------------- forward ----------------
  float den = denb[0];
  float lpb = llb[0] - den;
  float lpl = llb[1 + l] - den;
  float ae = (l == 0) ? lpb : NEGINF;  // even state 2l (blank)
  float ao = (l == 0) ? lpl : NEGINF;  // odd state 2l+1 (label l)
  aodb[l] = ao;

  float cd[8], cb[8], cl[8];
#pragma unroll
  for (int j = 0; j < 8; ++j) {
    int tt = 1 + j; if (tt > NT - 1) tt = NT - 1;
    cd[j] = denb[tt]; cb[j] = llb[tt * (NU + 1)]; cl[j] = llb[tt * (NU + 1) + 1 + l];
  }
  for (int g = 0; g < 125; ++g) {
    float nd[8], nb[8], nl[8];
    if (g < 124) {
#pragma unroll
      for (int j = 0; j < 8; ++j) {
        int tt = 9 + g * 8 + j; if (tt > NT - 1) tt = NT - 1;
        nd[j] = denb[tt]; nb[j] = llb[tt * (NU + 1)]; nl[j] = llb[tt * (NU + 1) + 1 + l];
      }
    } else {
#pragma unroll
      for (int j = 0; j < 8; ++j) { nd[j] = 0.f; nb[j] = 0.f; nl[j] = 0.f; }
    }
#pragma unroll
    for (int j = 0; j < 8; ++j) {
      int t = 1 + g * 8 + j;
      if (t < NT) {
        float d2 = cd[j], pb = cb[j] - d2, pl = cl[j] - d2;
        float po = __shfl_up(ao, 1); if (l == 0) po = NEGINF;
        float aen = pb + lae2(ae, po);
        float aon = pl + lae3(ao, ae, skip ? po : NEGINF);
        ae = aen; ao = aon;
        aodb[t * NU + l] = ao;
      }
    }
#pragma unroll
    for (int j = 0; j < 8; ++j) { cd[j] = nd[j]; cb[j] = nb[j]; cl[j] = nl[j]; }
  }

  // ---------------- backward + fused loss ----------------
  float bo = (l == NU - 1) ? 0.0f : NEGINF;  // state 127
  float be = NEGINF;                          // even states
  float b128 = 0.0f;                          // state 128
  float mlse = NEGINF, slse = 0.f;
  { // t = T-1: bp = beta_last(odd)
    float ls = aodb[(NT - 1) * NU + l] + bo;
    if (__builtin_isnan(ls)) ls = NEGINF;
    lse_upd(mlse, slse, ls);
  }
  float bd[8], bb[8], blv[8], ba[8];
#pragma unroll
  for (int j = 0; j < 8; ++j) {
    int tt = NT - 2 - j; if (tt < 0) tt = 0;
    bd[j] = denb[tt + 1]; bb[j] = llb[(tt + 1) * (NU + 1)];
    blv[j] = llb[(tt + 1) * (NU + 1) + 1 + l]; ba[j] = aodb[tt * NU + l];
  }
  for (int g = 0; g < 125; ++g) {
    float nd[8], nb[8], nl2[8], na[8];
    if (g < 124) {
#pragma unroll
      for (int j = 0; j < 8; ++j) {
        int tt = NT - 2 - 8 * (g + 1) - j; if (tt < 0) tt = 0;
        nd[j] = denb[tt + 1]; nb[j] = llb[(tt + 1) * (NU + 1)];
        nl2[j] = llb[(tt + 1) * (NU + 1) + 1 + l]; na[j] = aodb[tt * NU + l];
      }
    } else {
#pragma unroll
      for (int j = 0; j < 8; ++j) { nd[j] = 0.f; nb[j] = 0.f; nl2[j] = 0.f; na[j] = 0.f; }
    }
#pragma unroll
    for (int j = 0; j < 8; ++j) {
      int t = NT - 2 - 8 * g - j;
      if (t >= 0) {
        float d2 = bd[j], pb = bb[j] - d2, pl = blv[j] - d2;
        float me = pb + be;        // m[2l]
        float mo = pl + bo;        // m[2l+1]
        float m128 = pb + b128;    // m[128]
        float ne = __shfl_down(me, 1); if (l == NU - 1) ne = m128;
        float no = __shfl_down(mo, 1); if (l == NU - 1) no = NEGINF;
        float ben = lae2(me, mo);
        float bon = lae3(mo, ne, skipn ? no : NEGINF);
        float bp = log_sub_exp(bon, mo);
        float ls = ba[j] + bp;
        if (__builtin_isnan(ls)) ls = NEGINF;
        lse_upd(mlse, slse, ls);
        be = ben; bo = bon; b128 = m128;
      }
    }
#pragma unroll
    for (int j = 0; j < 8; ++j) { bd[j] = nd[j]; bb[j] = nb[j]; blv[j] = nl2[j]; ba[j] = na[j]; }
  }

  float lu = (slse > 0.f) ? mlse + __logf(slse) : NEGINF;
  bool msk = __builtin_isinf(lu);
  float sv = msk ? 0.f : lu;
  float cv = msk ? 0.f : 1.f;
#pragma unroll
  for (int d = 1; d < 64; d <<= 1) { sv += __shfl_xor(sv, d); cv += __shfl_xor(cv, d); }
  if (l == 0) {
    float lf = sv / cv;
    if (hlens[b] < NU) lf = 0.f;
    atomicAdd(out, -lf * (1.0f / NB));
  }
}

// ---------------------------------------------------------------------------
extern "C" void kernel_launch(void* const* d_in, const int* in_sizes, int n_in,
                              void* d_out, int out_size, void* d_ws, size_t ws_size,
                              hipStream_t stream) {
  const float* hs    = (const float*)d_in[0];
  const int*   hlens = (const int*)d_in[1];
  const int*   ys    = (const int*)d_in[2];
  const float* W     = (const float*)d_in[4];
  const float* bias  = (const float*)d_in[5];
  float* out = (float*)d_out;

  char* ws = (char*)d_ws;
  short* hsb   = (short*)(ws + 0);           // 16,384,000 B  [16000][512] bf16
  short* WT    = (short*)(ws + 16384000);    //  5,120,000 B  [5000][512] bf16
  float* Wg    = (float*)(ws + 21504000);    //  8,519,680 B  [16][512][65] f32
  float* ll    = (float*)(ws + 30023680);    //  4,160,000 B  [16][1000][65] f32
  float* dnm   = (float*)(ws + 34183680);    //     64,000 B  [16][1000] f32
  float* aod   = (float*)(ws + 34247680);    //  4,096,000 B  [16][1000][64] f32

  k_zero<<<1, 64, 0, stream>>>(out);
  k_cvt_hs<<<4000, 256, 0, stream>>>(hs, hsb);
  k_cvt_wt<<<dim3(79, 8), 256, 0, stream>>>(W, WT);
  k_gather<<<dim3(512, 16), 128, 0, stream>>>(W, ys, Wg);
  k_lab<<<dim3(1000, 16), 128, 0, stream>>>(hs, Wg, ys, bias, ll);
  k_denom<<<dim3(16, 16), 256, 0, stream>>>(hsb, WT, bias, dnm);
  k_trellis<<<16, 64, 0, stream>>>(ll, dnm, ys, hlens, aod, out);
}

// Round 2
// 839.589 us; speedup vs baseline: 1.3291x; 1.3291x over previous
//
#include <hip/hip_runtime.h>

// Problem constants (SpeakerAwareCTC): B=16, T=1000, D=512, V=5000, U=64, S=2U+1=129
#define NB 16
#define NT 1000
#define ND 512
#define NV 5000
#define NU 64

typedef short short8v __attribute__((ext_vector_type(8)));
typedef float float4v __attribute__((ext_vector_type(4)));

#define NEGINF (-__builtin_inff())
#define LOG2E 1.4426950408889634f
#define LN2F  0.6931471805599453f
// reference sentinel: -2001 + logf(expf(1)-1) = -2000.4586751f (natural), in base-2:
#define SENT2 (-2000.4586751f * LOG2E)

__device__ __forceinline__ float fexp2(float x) { return __builtin_amdgcn_exp2f(x); }
__device__ __forceinline__ float flog2(float x) { return __builtin_amdgcn_logf(x); }

__device__ __forceinline__ short f2bf(float x) {
  unsigned int u = __builtin_bit_cast(unsigned int, x);
  unsigned int r = (u + 0x7fffu + ((u >> 16) & 1u)) >> 16;
  return (short)(unsigned short)r;
}

// branchless base-2 logaddexp (clamp instead of -inf branch; exact same results)
__device__ __forceinline__ float lae2b(float a, float b) {
  float m = fmaxf(fmaxf(a, b), -3.0e38f);
  return m + flog2(fexp2(a - m) + fexp2(b - m));
}
__device__ __forceinline__ float lae3b(float a, float b, float c) {
  float m = fmaxf(fmaxf(a, b), fmaxf(c, -3.0e38f));
  return m + flog2(fexp2(a - m) + fexp2(b - m) + fexp2(c - m));
}
// faithful base-2 port of reference log_substraction_exp (sentinel -> constant)
__device__ __forceinline__ float lsub2(float a, float b) {
  bool ia = __builtin_isinf(a), ib = __builtin_isinf(b);
  float tmp = b + flog2(fexp2(a - b) - 1.0f);
  if (__builtin_isinf(tmp)) tmp = SENT2;
  float res = (!ia && !ib) ? tmp : NEGINF;
  if (!ia && ib) res = a;
  return res;
}

// ---------------- kernel 0: zero the scalar output -------------------------
__global__ void k_zero(float* out) {
  if (threadIdx.x == 0) out[0] = 0.0f;
}

// ---------------- kernel 1: hs f32 -> bf16 (same layout) -------------------
__global__ __launch_bounds__(256) void k_cvt_hs(const float* __restrict__ in,
                                                short* __restrict__ out) {
  size_t i = (size_t)blockIdx.x * 256 + threadIdx.x;
  const float4* p = (const float4*)in + i * 2;
  float4 v0 = p[0], v1 = p[1];
  short8v r;
  r[0] = f2bf(v0.x); r[1] = f2bf(v0.y); r[2] = f2bf(v0.z); r[3] = f2bf(v0.w);
  r[4] = f2bf(v1.x); r[5] = f2bf(v1.y); r[6] = f2bf(v1.z); r[7] = f2bf(v1.w);
  *(short8v*)(out + i * 8) = r;
}

// ------------- kernel 2: W [512][5000] f32 -> WT [5000][512] bf16 ----------
__global__ __launch_bounds__(256) void k_cvt_wt(const float* __restrict__ W,
                                                short* __restrict__ WT) {
  __shared__ short tile[64 * 72];
  int n0 = blockIdx.x * 64, k0 = blockIdx.y * 64;
  int tid = threadIdx.x;
  int kr = tid >> 2, part = tid & 3;
  const float* src = W + (size_t)(k0 + kr) * NV + n0 + part * 16;
#pragma unroll
  for (int jj = 0; jj < 4; ++jj) {
    int c = n0 + part * 16 + jj * 4;
    float4 v;
    if (c + 3 < NV) {
      v = *(const float4*)(src + jj * 4);
    } else {
      v.x = (c + 0 < NV) ? src[jj * 4 + 0] : 0.f;
      v.y = (c + 1 < NV) ? src[jj * 4 + 1] : 0.f;
      v.z = (c + 2 < NV) ? src[jj * 4 + 2] : 0.f;
      v.w = (c + 3 < NV) ? src[jj * 4 + 3] : 0.f;
    }
    int base = kr * 72 + part * 16 + jj * 4;
    tile[base + 0] = f2bf(v.x); tile[base + 1] = f2bf(v.y);
    tile[base + 2] = f2bf(v.z); tile[base + 3] = f2bf(v.w);
  }
  __syncthreads();
  int n = tid & 63, kq = tid >> 6;
  if (n0 + n < NV) {
#pragma unroll
    for (int half = 0; half < 2; ++half) {
      short8v val;
#pragma unroll
      for (int jj = 0; jj < 8; ++jj) val[jj] = tile[(kq * 16 + half * 8 + jj) * 72 + n];
      *(short8v*)(WT + (size_t)(n0 + n) * ND + k0 + kq * 16 + half * 8) = val;
    }
  }
}

// -------- kernel 3: gather Wg[b][k][u] = W[k][lab(b,u)] (f32) --------------
__global__ void k_gather(const float* __restrict__ W, const int* __restrict__ ys,
                         float* __restrict__ Wg) {
  int k = blockIdx.x, b = blockIdx.y, u = threadIdx.x;
  if (u < NU + 1) {
    int lab = (u == 0) ? 0 : ys[b * NU + u - 1];
    Wg[((size_t)b * ND + k) * (NU + 1) + u] = W[(size_t)k * NV + lab];
  }
}

// -------- kernel 4: ll[b][t][u] = hs[b,t,:] . Wg[b,:,u] + bias[lab] --------
// split-K x2: threads (u, half), LDS combine
__global__ __launch_bounds__(192) void k_lab(const float* __restrict__ hs,
                                             const float* __restrict__ Wg,
                                             const int* __restrict__ ys,
                                             const float* __restrict__ bias,
                                             float* __restrict__ ll) {
  __shared__ float hsr[ND];
  __shared__ float part[130];
  int t = blockIdx.x, b = blockIdx.y, tid = threadIdx.x;
  if (tid < 128)
    ((float4*)hsr)[tid] = ((const float4*)(hs + ((size_t)(b * NT + t)) * ND))[tid];
  __syncthreads();
  if (tid < 130) {
    int u = (tid < 65) ? tid : tid - 65;
    int h = (tid < 65) ? 0 : 1;
    const float* wg = Wg + (size_t)b * ND * (NU + 1) + (size_t)(h * 256) * (NU + 1) + u;
    const float* hh = hsr + h * 256;
    float acc = 0.f;
#pragma unroll 8
    for (int k = 0; k < 256; ++k) acc += hh[k] * wg[(size_t)k * (NU + 1)];
    part[tid] = acc;
  }
  __syncthreads();
  if (tid < 65) {
    int lab = (tid == 0) ? 0 : ys[b * NU + tid - 1];
    ll[((size_t)(b * NT + t)) * (NU + 1) + tid] = part[tid] + part[tid + 65] + bias[lab];
  }
}

// -------- kernel 5: denom[b][t] = logsumexp_v(hs@W + b) via bf16 MFMA ------
__global__ __launch_bounds__(256) void k_denom(const short* __restrict__ hsb,
                                               const short* __restrict__ WT,
                                               const float* __restrict__ bias,
                                               float* __restrict__ denom) {
  constexpr int NCHUNK = 40;
  constexpr int NST = NCHUNK * 8;
  __shared__ short As[2][64 * 72];
  __shared__ short Ws[2][128 * 72];
  __shared__ float mred[64][2];
  __shared__ float sred[64][2];

  int b = blockIdx.y, t0 = blockIdx.x * 64;
  int tid = threadIdx.x;
  int lane = tid & 63, wave = tid >> 6;
  int wm = wave >> 1, wn = wave & 1;
  int lrow = lane & 15, lkhi = lane >> 4;

  int ar = tid & 63, apart = tid >> 6;
  int wr = tid & 127, whalf = tid >> 7;
  bool avalid = (t0 + ar) < NT;
  const short* arow = hsb + ((size_t)(b * NT) + (t0 + ar)) * ND;

  float4v acc[2][4];
  float mrun[2][4], srun[2][4];
#pragma unroll
  for (int fa = 0; fa < 2; ++fa)
#pragma unroll
    for (int fb = 0; fb < 4; ++fb)
#pragma unroll
      for (int j = 0; j < 4; ++j) acc[fa][fb][j] = 0.f;
#pragma unroll
  for (int fa = 0; fa < 2; ++fa)
#pragma unroll
    for (int j = 0; j < 4; ++j) { mrun[fa][j] = NEGINF; srun[fa][j] = 0.f; }

  short8v a_rg[2], w_rg[4];
  const short8v zero8 = {0, 0, 0, 0, 0, 0, 0, 0};

  auto issue_loads = [&](int s) {
    int chunk = s >> 3, ks = s & 7;
    int k0 = ks * 64, n0 = chunk * 128;
    if (avalid) {
      const short8v* pa = (const short8v*)(arow + k0 + apart * 16);
      a_rg[0] = pa[0]; a_rg[1] = pa[1];
    } else { a_rg[0] = zero8; a_rg[1] = zero8; }
    int n = n0 + wr;
    if (n < NV) {
      const short8v* pw = (const short8v*)(WT + (size_t)n * ND + k0 + whalf * 32);
      w_rg[0] = pw[0]; w_rg[1] = pw[1]; w_rg[2] = pw[2]; w_rg[3] = pw[3];
    } else { w_rg[0] = zero8; w_rg[1] = zero8; w_rg[2] = zero8; w_rg[3] = zero8; }
  };
  auto write_stage = [&](int bw) {
    *(short8v*)&As[bw][ar * 72 + apart * 16 + 0] = a_rg[0];
    *(short8v*)&As[bw][ar * 72 + apart * 16 + 8] = a_rg[1];
    short* wd = &Ws[bw][wr * 72 + whalf * 32];
    *(short8v*)(wd + 0)  = w_rg[0];
    *(short8v*)(wd + 8)  = w_rg[1];
    *(short8v*)(wd + 16) = w_rg[2];
    *(short8v*)(wd + 24) = w_rg[3];
  };
  auto compute = [&](int s) {
    int buf = s & 1;
#pragma unroll
    for (int kk = 0; kk < 2; ++kk) {
      short8v a0 = *(const short8v*)&As[buf][(wm * 32 + 0 + lrow) * 72 + kk * 32 + lkhi * 8];
      short8v a1 = *(const short8v*)&As[buf][(wm * 32 + 16 + lrow) * 72 + kk * 32 + lkhi * 8];
#pragma unroll
      for (int fb = 0; fb < 4; ++fb) {
        short8v bv = *(const short8v*)&Ws[buf][(wn * 64 + fb * 16 + lrow) * 72 + kk * 32 + lkhi * 8];
        acc[0][fb] = __builtin_amdgcn_mfma_f32_16x16x32_bf16(a0, bv, acc[0][fb], 0, 0, 0);
        acc[1][fb] = __builtin_amdgcn_mfma_f32_16x16x32_bf16(a1, bv, acc[1][fb], 0, 0, 0);
      }
    }
  };
  auto epilogue = [&](int chunk) {
    int n0 = chunk * 128;
    float bcol[4]; bool cval[4];
#pragma unroll
    for (int fb = 0; fb < 4; ++fb) {
      int c = n0 + wn * 64 + fb * 16 + lrow;
      cval[fb] = c < NV;
      bcol[fb] = cval[fb] ? bias[c] : 0.f;
    }
#pragma unroll
    for (int fa = 0; fa < 2; ++fa)
#pragma unroll
      for (int j = 0; j < 4; ++j) {
        float mx = NEGINF;
#pragma unroll
        for (int fb = 0; fb < 4; ++fb) {
          float v = cval[fb] ? acc[fa][fb][j] + bcol[fb] : NEGINF;
          mx = fmaxf(mx, v);
        }
#pragma unroll
        for (int d = 1; d < 16; d <<= 1) mx = fmaxf(mx, __shfl_xor(mx, d));
        float mn = fmaxf(mrun[fa][j], mx);
        float p = 0.f;
#pragma unroll
        for (int fb = 0; fb < 4; ++fb) {
          float v = cval[fb] ? acc[fa][fb][j] + bcol[fb] : NEGINF;
          p += __expf(v - mn);
        }
#pragma unroll
        for (int d = 1; d < 16; d <<= 1) p += __shfl_xor(p, d);
        srun[fa][j] = srun[fa][j] * __expf(mrun[fa][j] - mn) + p;
        mrun[fa][j] = mn;
      }
#pragma unroll
    for (int fa = 0; fa < 2; ++fa)
#pragma unroll
      for (int fb = 0; fb < 4; ++fb)
#pragma unroll
        for (int j = 0; j < 4; ++j) acc[fa][fb][j] = 0.f;
  };

  issue_loads(0);
  write_stage(0);
  for (int s = 0; s < NST; ++s) {
    __syncthreads();
    if (s + 1 < NST) issue_loads(s + 1);
    compute(s);
    if (s + 1 < NST) write_stage((s + 1) & 1);
    if ((s & 7) == 7) epilogue(s >> 3);
  }

  if (lrow == 0) {
#pragma unroll
    for (int fa = 0; fa < 2; ++fa)
#pragma unroll
      for (int j = 0; j < 4; ++j) {
        int row = wm * 32 + fa * 16 + lkhi * 4 + j;
        mred[row][wn] = mrun[fa][j];
        sred[row][wn] = srun[fa][j];
      }
  }
  __syncthreads();
  if (tid < 64) {
    int t = t0 + tid;
    if (t < NT) {
      float m0 = mred[tid][0], m1 = mred[tid][1];
      float m = fmaxf(m0, m1);
      float ss = sred[tid][0] * __expf(m0 - m) + sred[tid][1] * __expf(m1 - m);
      denom[b * NT + t] = m + __logf(ss);
    }
  }
}

// -------- kernel 6: fwd (blocks 0..15) || bwd (blocks 16..31), base-2 ------
// fwd writes aod[b][t][l] = alpha at odd state 2l+1 (base-2)
// bwd writes bp [b][t][l] = beta' (log_sub_exp fused) at odd states (base-2)
__global__ __launch_bounds__(64) void k_fwdbwd(const float* __restrict__ ll,
                                               const float* __restrict__ denom,
                                               const int* __restrict__ ys,
                                               float* __restrict__ aod,
                                               float* __restrict__ bp) {
  int bid = blockIdx.x;
  int l = threadIdx.x;
  if (bid < NB) {
    // ---------------- forward ----------------
    int b = bid;
    int lab = ys[b * NU + l];
    int labp = ys[b * NU + ((l >= 1) ? (l - 1) : 0)];
    bool skip = (l >= 1) && (lab != labp);
    const float* llb = ll + (size_t)b * NT * (NU + 1);
    const float* denb = denom + b * NT;
    float* aodb = aod + (size_t)b * NT * NU;

    float den = denb[0];
    float ae = (l == 0) ? (llb[0] - den) * LOG2E : NEGINF;
    float ao = (l == 0) ? (llb[1] - den) * LOG2E : NEGINF;
    if (l == 0) aodb[0] = ao; else aodb[l] = NEGINF;

    float cd[8], cb[8], cl[8];
#pragma unroll
    for (int j = 0; j < 8; ++j) {
      int tt = 1 + j; if (tt > NT - 1) tt = NT - 1;
      cd[j] = denb[tt]; cb[j] = llb[tt * (NU + 1)]; cl[j] = llb[tt * (NU + 1) + 1 + l];
    }
    for (int g = 0; g < 125; ++g) {
      float nd[8], nb[8], nl[8];
      if (g < 124) {
#pragma unroll
        for (int j = 0; j < 8; ++j) {
          int tt = 9 + g * 8 + j; if (tt > NT - 1) tt = NT - 1;
          nd[j] = denb[tt]; nb[j] = llb[tt * (NU + 1)]; nl[j] = llb[tt * (NU + 1) + 1 + l];
        }
      } else {
#pragma unroll
        for (int j = 0; j < 8; ++j) { nd[j] = 0.f; nb[j] = 0.f; nl[j] = 0.f; }
      }
#pragma unroll
      for (int j = 0; j < 8; ++j) {
        int t = 1 + g * 8 + j;
        if (t < NT) {
          float d2 = cd[j];
          float pb = (cb[j] - d2) * LOG2E, pl = (cl[j] - d2) * LOG2E;
          float po = __shfl_up(ao, 1); if (l == 0) po = NEGINF;
          float aen = pb + lae2b(ae, po);
          float aon = pl + lae3b(ao, ae, skip ? po : NEGINF);
          ae = aen; ao = aon;
          aodb[t * NU + l] = ao;
        }
      }
#pragma unroll
      for (int j = 0; j < 8; ++j) { cd[j] = nd[j]; cb[j] = nb[j]; cl[j] = nl[j]; }
    }
  } else {
    // ---------------- backward ----------------
    int b = bid - NB;
    int lab = ys[b * NU + l];
    int labn = ys[b * NU + ((l < NU - 1) ? (l + 1) : l)];
    bool skipn = (l < NU - 1) && (labn != lab);
    const float* llb = ll + (size_t)b * NT * (NU + 1);
    const float* denb = denom + b * NT;
    float* bpb = bp + (size_t)b * NT * NU;

    float bo = (l == NU - 1) ? 0.0f : NEGINF;  // beta at odd state 2l+1
    float be = NEGINF;                          // beta at even state 2l
    float b128 = 0.0f;                          // beta at state 128
    bpb[(NT - 1) * NU + l] = bo;               // bp[:, :, -1] = beta_last(odd)

    float bd[8], bb[8], blv[8];
#pragma unroll
    for (int j = 0; j < 8; ++j) {
      int tt = NT - 2 - j; if (tt < 0) tt = 0;
      bd[j] = denb[tt + 1]; bb[j] = llb[(tt + 1) * (NU + 1)];
      blv[j] = llb[(tt + 1) * (NU + 1) + 1 + l];
    }
    for (int g = 0; g < 125; ++g) {
      float nd[8], nb[8], nl2[8];
      if (g < 124) {
#pragma unroll
        for (int j = 0; j < 8; ++j) {
          int tt = NT - 2 - 8 * (g + 1) - j; if (tt < 0) tt = 0;
          nd[j] = denb[tt + 1]; nb[j] = llb[(tt + 1) * (NU + 1)];
          nl2[j] = llb[(tt + 1) * (NU + 1) + 1 + l];
        }
      } else {
#pragma unroll
        for (int j = 0; j < 8; ++j) { nd[j] = 0.f; nb[j] = 0.f; nl2[j] = 0.f; }
      }
#pragma unroll
      for (int j = 0; j < 8; ++j) {
        int t = NT - 2 - 8 * g - j;
        if (t >= 0) {
          float d2 = bd[j];
          float pbv = (bb[j] - d2) * LOG2E, plv = (blv[j] - d2) * LOG2E;
          float me = pbv + be;
          float mo = plv + bo;
          float m128 = pbv + b128;
          float ne = __shfl_down(me, 1); if (l == NU - 1) ne = m128;
          float no = __shfl_down(mo, 1); if (l == NU - 1) no = NEGINF;
          float ben = lae2b(me, mo);
          float bon = lae3b(mo, ne, skipn ? no : NEGINF);
          bpb[t * NU + l] = lsub2(bon, mo);
          be = ben; bo = bon; b128 = m128;
        }
      }
#pragma unroll
      for (int j = 0; j < 8; ++j) { bd[j] = nd[j]; bb[j] = nb[j]; blv[j] = nl2[j]; }
    }
  }
}

// -------- kernel 7: loss = mean_b( -sum_u lse_t(alpha+bp) / count ) --------
__global__ __launch_bounds__(256) void k_loss(const float* __restrict__ aod,
                                              const float* __restrict__ bp,
                                              const int* __restrict__ hlens,
                                              float* __restrict__ out) {
  __shared__ float ms[4][64], ss[4][64];
  int b = blockIdx.x, tid = threadIdx.x;
  int w = tid >> 6, l = tid & 63;
  const float* ab = aod + (size_t)b * NT * NU;
  const float* pb = bp + (size_t)b * NT * NU;
  float m = NEGINF, s = 0.f;
  int t0 = w * 250, t1 = t0 + 250;
  for (int t = t0; t < t1; ++t) {
    float x = ab[t * NU + l] + pb[t * NU + l];
    if (__builtin_isnan(x) || x == NEGINF) continue;
    if (x > m) { s = s * fexp2(m - x) + 1.0f; m = x; }
    else       { s += fexp2(x - m); }
  }
  ms[w][l] = m; ss[w][l] = s;
  __syncthreads();
  if (w == 0) {
    float m0 = ms[0][l], m1 = ms[1][l], m2 = ms[2][l], m3 = ms[3][l];
    float mm = fmaxf(fmaxf(m0, m1), fmaxf(m2, m3));
    float lu;
    if (mm == NEGINF) lu = NEGINF;
    else {
      float st = ss[0][l] * fexp2(m0 - mm) + ss[1][l] * fexp2(m1 - mm) +
                 ss[2][l] * fexp2(m2 - mm) + ss[3][l] * fexp2(m3 - mm);
      lu = (mm + flog2(st)) * LN2F;
    }
    bool msk = __builtin_isinf(lu);
    float sv = msk ? 0.f : lu;
    float cv = msk ? 0.f : 1.f;
#pragma unroll
    for (int d = 1; d < 64; d <<= 1) { sv += __shfl_xor(sv, d); cv += __shfl_xor(cv, d); }
    if (l == 0) {
      float lf = sv / cv;
      if (hlens[b] < NU) lf = 0.f;
      atomicAdd(out, -lf * (1.0f / NB));
    }
  }
}

// ---------------------------------------------------------------------------
extern "C" void kernel_launch(void* const* d_in, const int* in_sizes, int n_in,
                              void* d_out, int out_size, void* d_ws, size_t ws_size,
                              hipStream_t stream) {
  const float* hs    = (const float*)d_in[0];
  const int*   hlens = (const int*)d_in[1];
  const int*   ys    = (const int*)d_in[2];
  const float* W     = (const float*)d_in[4];
  const float* bias  = (const float*)d_in[5];
  float* out = (float*)d_out;

  char* ws = (char*)d_ws;
  short* hsb   = (short*)(ws + 0);           // 16,384,000 B  [16000][512] bf16
  float* bpb   = (float*)(ws + 0);           //  4,096,000 B  aliases hsb (dead after k_denom)
  short* WT    = (short*)(ws + 16384000);    //  5,120,000 B  [5000][512] bf16
  float* Wg    = (float*)(ws + 21504000);    //  8,519,680 B  [16][512][65] f32
  float* ll    = (float*)(ws + 30023680);    //  4,160,000 B  [16][1000][65] f32
  float* dnm   = (float*)(ws + 34183680);    //     64,000 B  [16][1000] f32
  float* aod   = (float*)(ws + 34247680);    //  4,096,000 B  [16][1000][64] f32

  k_zero<<<1, 64, 0, stream>>>(out);
  k_cvt_hs<<<4000, 256, 0, stream>>>(hs, hsb);
  k_cvt_wt<<<dim3(79, 8), 256, 0, stream>>>(W, WT);
  k_gather<<<dim3(512, 16), 128, 0, stream>>>(W, ys, Wg);
  k_lab<<<dim3(1000, 16), 192, 0, stream>>>(hs, Wg, ys, bias, ll);
  k_denom<<<dim3(16, 16), 256, 0, stream>>>(hsb, WT, bias, dnm);
  k_fwdbwd<<<32, 64, 0, stream>>>(ll, dnm, ys, aod, bpb);
  k_loss<<<16, 256, 0, stream>>>(aod, bpb, hlens, out);
}

// Round 4
// 686.830 us; speedup vs baseline: 1.6247x; 1.2224x over previous
//
#include <hip/hip_runtime.h>

// Problem constants (SpeakerAwareCTC): B=16, T=1000, D=512, V=5000, U=64, S=2U+1=129
#define NB 16
#define NT 1000
#define ND 512
#define NV 5000
#define NU 64
#define NM (NB * NT)      // 16000 flattened rows
#define NCH 40            // N-chunks of 128 cols

typedef short short8v __attribute__((ext_vector_type(8)));
typedef float float4v __attribute__((ext_vector_type(4)));

#define NEGINF (-__builtin_inff())
#define LOG2E 1.4426950408889634f
#define LN2F  0.6931471805599453f
// reference sentinel: -2001 + logf(expf(1)-1) = -2000.4586751f (natural), in base-2:
#define SENT2 (-2000.4586751f * LOG2E)

__device__ __forceinline__ float fexp2(float x) { return __builtin_amdgcn_exp2f(x); }
__device__ __forceinline__ float flog2(float x) { return __builtin_amdgcn_logf(x); }

// DPP lane shifts (VALU-latency, replaces ds_bpermute-based __shfl in serial chain)
__device__ __forceinline__ float dpp_shr1(float x) {  // lane i <- lane i-1 (shfl_up 1)
  int xi = __builtin_bit_cast(int, x);
  int r = __builtin_amdgcn_update_dpp(xi, xi, 0x138, 0xf, 0xf, false);
  return __builtin_bit_cast(float, r);
}
__device__ __forceinline__ float dpp_shl1(float x) {  // lane i <- lane i+1 (shfl_down 1)
  int xi = __builtin_bit_cast(int, x);
  int r = __builtin_amdgcn_update_dpp(xi, xi, 0x130, 0xf, 0xf, false);
  return __builtin_bit_cast(float, r);
}

__device__ __forceinline__ short f2bf(float x) {
  unsigned int u = __builtin_bit_cast(unsigned int, x);
  unsigned int r = (u + 0x7fffu + ((u >> 16) & 1u)) >> 16;
  return (short)(unsigned short)r;
}

// branchless base-2 logaddexp (clamp instead of -inf branch)
__device__ __forceinline__ float lae2b(float a, float b) {
  float m = fmaxf(fmaxf(a, b), -3.0e38f);
  return m + flog2(fexp2(a - m) + fexp2(b - m));
}
__device__ __forceinline__ float lae3b(float a, float b, float c) {
  float m = fmaxf(fmaxf(a, b), fmaxf(c, -3.0e38f));
  return m + flog2(fexp2(a - m) + fexp2(b - m) + fexp2(c - m));
}
// faithful base-2 port of reference log_substraction_exp (sentinel -> constant)
__device__ __forceinline__ float lsub2(float a, float b) {
  bool ia = __builtin_isinf(a), ib = __builtin_isinf(b);
  float tmp = b + flog2(fexp2(a - b) - 1.0f);
  if (__builtin_isinf(tmp)) tmp = SENT2;
  float res = (!ia && !ib) ? tmp : NEGINF;
  if (!ia && ib) res = a;
  return res;
}

// ---------------- kernel 0: zero the scalar output -------------------------
__global__ void k_zero(float* out) {
  if (threadIdx.x == 0) out[0] = 0.0f;
}

// ---------------- kernel 1: hs f32 -> bf16 (same layout) -------------------
__global__ __launch_bounds__(256) void k_cvt_hs(const float* __restrict__ in,
                                                short* __restrict__ out) {
  size_t i = (size_t)blockIdx.x * 256 + threadIdx.x;
  const float4* p = (const float4*)in + i * 2;
  float4 v0 = p[0], v1 = p[1];
  short8v r;
  r[0] = f2bf(v0.x); r[1] = f2bf(v0.y); r[2] = f2bf(v0.z); r[3] = f2bf(v0.w);
  r[4] = f2bf(v1.x); r[5] = f2bf(v1.y); r[6] = f2bf(v1.z); r[7] = f2bf(v1.w);
  *(short8v*)(out + i * 8) = r;
}

// ------------- kernel 2: W [512][5000] f32 -> WT [5000][512] bf16 ----------
__global__ __launch_bounds__(256) void k_cvt_wt(const float* __restrict__ W,
                                                short* __restrict__ WT) {
  __shared__ short tile[64 * 72];
  int n0 = blockIdx.x * 64, k0 = blockIdx.y * 64;
  int tid = threadIdx.x;
  int kr = tid >> 2, part = tid & 3;
  const float* src = W + (size_t)(k0 + kr) * NV + n0 + part * 16;
#pragma unroll
  for (int jj = 0; jj < 4; ++jj) {
    int c = n0 + part * 16 + jj * 4;
    float4 v;
    if (c + 3 < NV) {
      v = *(const float4*)(src + jj * 4);
    } else {
      v.x = (c + 0 < NV) ? src[jj * 4 + 0] : 0.f;
      v.y = (c + 1 < NV) ? src[jj * 4 + 1] : 0.f;
      v.z = (c + 2 < NV) ? src[jj * 4 + 2] : 0.f;
      v.w = (c + 3 < NV) ? src[jj * 4 + 3] : 0.f;
    }
    int base = kr * 72 + part * 16 + jj * 4;
    tile[base + 0] = f2bf(v.x); tile[base + 1] = f2bf(v.y);
    tile[base + 2] = f2bf(v.z); tile[base + 3] = f2bf(v.w);
  }
  __syncthreads();
  int n = tid & 63, kq = tid >> 6;
  if (n0 + n < NV) {
#pragma unroll
    for (int half = 0; half < 2; ++half) {
      short8v val;
#pragma unroll
      for (int jj = 0; jj < 8; ++jj) val[jj] = tile[(kq * 16 + half * 8 + jj) * 72 + n];
      *(short8v*)(WT + (size_t)(n0 + n) * ND + k0 + kq * 16 + half * 8) = val;
    }
  }
}

// -------- kernel 3: gather Wg[b][k][u] = W[k][lab(b,u)] (f32) --------------
__global__ void k_gather(const float* __restrict__ W, const int* __restrict__ ys,
                         float* __restrict__ Wg) {
  int k = blockIdx.x, b = blockIdx.y, u = threadIdx.x;
  if (u < NU + 1) {
    int lab = (u == 0) ? 0 : ys[b * NU + u - 1];
    Wg[((size_t)b * ND + k) * (NU + 1) + u] = W[(size_t)k * NV + lab];
  }
}

// -------- kernel 4: ll[b][t][u] = hs[b,t,:] . Wg[b,:,u] + bias[lab] --------
__global__ __launch_bounds__(192) void k_lab(const float* __restrict__ hs,
                                             const float* __restrict__ Wg,
                                             const int* __restrict__ ys,
                                             const float* __restrict__ bias,
                                             float* __restrict__ ll) {
  __shared__ float hsr[ND];
  __shared__ float part[130];
  int t = blockIdx.x, b = blockIdx.y, tid = threadIdx.x;
  if (tid < 128)
    ((float4*)hsr)[tid] = ((const float4*)(hs + ((size_t)(b * NT + t)) * ND))[tid];
  __syncthreads();
  if (tid < 130) {
    int u = (tid < 65) ? tid : tid - 65;
    int h = (tid < 65) ? 0 : 1;
    const float* wg = Wg + (size_t)b * ND * (NU + 1) + (size_t)(h * 256) * (NU + 1) + u;
    const float* hh = hsr + h * 256;
    float acc = 0.f;
#pragma unroll 8
    for (int k = 0; k < 256; ++k) acc += hh[k] * wg[(size_t)k * (NU + 1)];
    part[tid] = acc;
  }
  __syncthreads();
  if (tid < 65) {
    int lab = (tid == 0) ? 0 : ys[b * NU + tid - 1];
    ll[((size_t)(b * NT + t)) * (NU + 1) + tid] = part[tid] + part[tid + 65] + bias[lab];
  }
}

// -------- kernel 5: per-chunk partial logsumexp of hs@W + b (bf16 MFMA) ----
// grid (250 M-tiles, 40 N-chunks); block = 64 rows x 128 cols x K=512.
// writes partial (m,s) per row into pm/ps[chunk][row].
__global__ __launch_bounds__(256) void k_denom(const short* __restrict__ hsb,
                                               const short* __restrict__ WT,
                                               const float* __restrict__ bias,
                                               float* __restrict__ pm,
                                               float* __restrict__ ps) {
  __shared__ short As[2][64 * 72];
  __shared__ short Ws[2][128 * 72];
  __shared__ float mred[64][2];
  __shared__ float sred[64][2];

  int t0 = blockIdx.x * 64;
  int chunk = blockIdx.y;
  int n0 = chunk * 128;
  int tid = threadIdx.x;
  int lane = tid & 63, wave = tid >> 6;
  int wm = wave >> 1, wn = wave & 1;
  int lrow = lane & 15, lkhi = lane >> 4;

  int ar = tid & 63, apart = tid >> 6;
  int wr = tid & 127, whalf = tid >> 7;
  const short* arow = hsb + ((size_t)(t0 + ar)) * ND;

  float4v acc[2][4];
#pragma unroll
  for (int fa = 0; fa < 2; ++fa)
#pragma unroll
    for (int fb = 0; fb < 4; ++fb)
#pragma unroll
      for (int j = 0; j < 4; ++j) acc[fa][fb][j] = 0.f;

  short8v a_rg[2], w_rg[4];
  const short8v zero8 = {0, 0, 0, 0, 0, 0, 0, 0};

  auto issue_loads = [&](int s) {
    int k0 = s * 64;
    const short8v* pa = (const short8v*)(arow + k0 + apart * 16);
    a_rg[0] = pa[0]; a_rg[1] = pa[1];
    int n = n0 + wr;
    if (n < NV) {
      const short8v* pw = (const short8v*)(WT + (size_t)n * ND + k0 + whalf * 32);
      w_rg[0] = pw[0]; w_rg[1] = pw[1]; w_rg[2] = pw[2]; w_rg[3] = pw[3];
    } else { w_rg[0] = zero8; w_rg[1] = zero8; w_rg[2] = zero8; w_rg[3] = zero8; }
  };
  auto write_stage = [&](int bw) {
    *(short8v*)&As[bw][ar * 72 + apart * 16 + 0] = a_rg[0];
    *(short8v*)&As[bw][ar * 72 + apart * 16 + 8] = a_rg[1];
    short* wd = &Ws[bw][wr * 72 + whalf * 32];
    *(short8v*)(wd + 0)  = w_rg[0];
    *(short8v*)(wd + 8)  = w_rg[1];
    *(short8v*)(wd + 16) = w_rg[2];
    *(short8v*)(wd + 24) = w_rg[3];
  };
  auto compute = [&](int s) {
    int buf = s & 1;
#pragma unroll
    for (int kk = 0; kk < 2; ++kk) {
      short8v a0 = *(const short8v*)&As[buf][(wm * 32 + 0 + lrow) * 72 + kk * 32 + lkhi * 8];
      short8v a1 = *(const short8v*)&As[buf][(wm * 32 + 16 + lrow) * 72 + kk * 32 + lkhi * 8];
#pragma unroll
      for (int fb = 0; fb < 4; ++fb) {
        short8v bv = *(const short8v*)&Ws[buf][(wn * 64 + fb * 16 + lrow) * 72 + kk * 32 + lkhi * 8];
        acc[0][fb] = __builtin_amdgcn_mfma_f32_16x16x32_bf16(a0, bv, acc[0][fb], 0, 0, 0);
        acc[1][fb] = __builtin_amdgcn_mfma_f32_16x16x32_bf16(a1, bv, acc[1][fb], 0, 0, 0);
      }
    }
  };

  issue_loads(0);
  write_stage(0);
  for (int s = 0; s < 8; ++s) {
    __syncthreads();
    if (s + 1 < 8) issue_loads(s + 1);
    compute(s);
    if (s + 1 < 8) write_stage((s + 1) & 1);
  }

  // epilogue: per-row (m,s) over this chunk's 128 cols.
  // NaN guard: when an entire half-tile is out of range (ragged last chunk),
  // mx == -inf; clamp the subtraction base so exp(-inf - mxc) == 0, not NaN.
  float bcol[4]; bool cval[4];
#pragma unroll
  for (int fb = 0; fb < 4; ++fb) {
    int c = n0 + wn * 64 + fb * 16 + lrow;
    cval[fb] = c < NV;
    bcol[fb] = cval[fb] ? bias[c] : 0.f;
  }
  float mv[2][4], sv[2][4];
#pragma unroll
  for (int fa = 0; fa < 2; ++fa)
#pragma unroll
    for (int j = 0; j < 4; ++j) {
      float mx = NEGINF;
#pragma unroll
      for (int fb = 0; fb < 4; ++fb) {
        float v = cval[fb] ? acc[fa][fb][j] + bcol[fb] : NEGINF;
        mx = fmaxf(mx, v);
      }
#pragma unroll
      for (int d = 1; d < 16; d <<= 1) mx = fmaxf(mx, __shfl_xor(mx, d));
      float mxc = fmaxf(mx, -3.0e38f);   // <-- NaN guard
      float p = 0.f;
#pragma unroll
      for (int fb = 0; fb < 4; ++fb) {
        float v = cval[fb] ? acc[fa][fb][j] + bcol[fb] : NEGINF;
        p += __expf(v - mxc);
      }
#pragma unroll
      for (int d = 1; d < 16; d <<= 1) p += __shfl_xor(p, d);
      mv[fa][j] = mx; sv[fa][j] = p;
    }

  if (lrow == 0) {
#pragma unroll
    for (int fa = 0; fa < 2; ++fa)
#pragma unroll
      for (int j = 0; j < 4; ++j) {
        int row = wm * 32 + fa * 16 + lkhi * 4 + j;
        mred[row][wn] = mv[fa][j];
        sred[row][wn] = sv[fa][j];
      }
  }
  __syncthreads();
  if (tid < 64) {
    int row = t0 + tid;
    float m0 = mred[tid][0], m1 = mred[tid][1];
    float m = fmaxf(m0, m1);
    float ss;
    if (m == NEGINF) {
      ss = 0.f;
    } else {
      float mc = fmaxf(m, -3.0e38f);
      ss = sred[tid][0] * __expf(fmaxf(m0, -3.0e38f) - mc) * (m0 == NEGINF ? 0.f : 1.f)
         + sred[tid][1] * __expf(fmaxf(m1, -3.0e38f) - mc) * (m1 == NEGINF ? 0.f : 1.f);
      // note: sred is 0 whenever mred is -inf, so the multipliers are belt-and-braces
      ss = sred[tid][0] * ((m0 == NEGINF) ? 0.f : __expf(m0 - m))
         + sred[tid][1] * ((m1 == NEGINF) ? 0.f : __expf(m1 - m));
    }
    pm[(size_t)chunk * NM + row] = m;
    ps[(size_t)chunk * NM + row] = ss;
  }
}

// -------- kernel 5b: combine 40 chunk partials -> denom[row] ---------------
__global__ __launch_bounds__(256) void k_dred(const float* __restrict__ pm,
                                              const float* __restrict__ ps,
                                              float* __restrict__ denom) {
  int row = blockIdx.x * 256 + threadIdx.x;
  if (row >= NM) return;
  float m = NEGINF, s = 0.f;
  for (int c = 0; c < NCH; ++c) {
    float mc = pm[(size_t)c * NM + row];
    float sc = ps[(size_t)c * NM + row];
    if (mc == NEGINF) continue;
    if (mc > m) { s = s * __expf(m - mc) + sc; m = mc; }
    else        { s += sc * __expf(mc - m); }
  }
  denom[row] = m + __logf(s);
}

// -------- kernel 6: fwd (blocks 0..15) || bwd (blocks 16..31), base-2 ------
__global__ __launch_bounds__(64) void k_fwdbwd(const float* __restrict__ ll,
                                               const float* __restrict__ denom,
                                               const int* __restrict__ ys,
                                               float* __restrict__ aod,
                                               float* __restrict__ bp) {
  int bid = blockIdx.x;
  int l = threadIdx.x;
  if (bid < NB) {
    // ---------------- forward ----------------
    int b = bid;
    int lab = ys[b * NU + l];
    int labp = ys[b * NU + ((l >= 1) ? (l - 1) : 0)];
    bool skip = (l >= 1) && (lab != labp);
    const float* llb = ll + (size_t)b * NT * (NU + 1);
    const float* denb = denom + b * NT;
    float* aodb = aod + (size_t)b * NT * NU;

    float den = denb[0];
    float ae = (l == 0) ? (llb[0] - den) * LOG2E : NEGINF;
    float ao = (l == 0) ? (llb[1] - den) * LOG2E : NEGINF;
    if (l == 0) aodb[0] = ao; else aodb[l] = NEGINF;

    float cd[8], cb[8], cl[8];
#pragma unroll
    for (int j = 0; j < 8; ++j) {
      int tt = 1 + j; if (tt > NT - 1) tt = NT - 1;
      cd[j] = denb[tt]; cb[j] = llb[tt * (NU + 1)]; cl[j] = llb[tt * (NU + 1) + 1 + l];
    }
    for (int g = 0; g < 125; ++g) {
      float nd[8], nb[8], nl[8];
      if (g < 124) {
#pragma unroll
        for (int j = 0; j < 8; ++j) {
          int tt = 9 + g * 8 + j; if (tt > NT - 1) tt = NT - 1;
          nd[j] = denb[tt]; nb[j] = llb[tt * (NU + 1)]; nl[j] = llb[tt * (NU + 1) + 1 + l];
        }
      } else {
#pragma unroll
        for (int j = 0; j < 8; ++j) { nd[j] = 0.f; nb[j] = 0.f; nl[j] = 0.f; }
      }
#pragma unroll
      for (int j = 0; j < 8; ++j) {
        int t = 1 + g * 8 + j;
        if (t < NT) {
          float d2 = cd[j];
          float pb = (cb[j] - d2) * LOG2E, pl = (cl[j] - d2) * LOG2E;
          float po = dpp_shr1(ao); if (l == 0) po = NEGINF;
          float aen = pb + lae2b(ae, po);
          float aon = pl + lae3b(ao, ae, skip ? po : NEGINF);
          ae = aen; ao = aon;
          aodb[t * NU + l] = ao;
        }
      }
#pragma unroll
      for (int j = 0; j < 8; ++j) { cd[j] = nd[j]; cb[j] = nb[j]; cl[j] = nl[j]; }
    }
  } else {
    // ---------------- backward ----------------
    int b = bid - NB;
    int lab = ys[b * NU + l];
    int labn = ys[b * NU + ((l < NU - 1) ? (l + 1) : l)];
    bool skipn = (l < NU - 1) && (labn != lab);
    const float* llb = ll + (size_t)b * NT * (NU + 1);
    const float* denb = denom + b * NT;
    float* bpb = bp + (size_t)b * NT * NU;

    float bo = (l == NU - 1) ? 0.0f : NEGINF;
    float be = NEGINF;
    float b128 = 0.0f;
    bpb[(NT - 1) * NU + l] = bo;

    float bd[8], bb[8], blv[8];
#pragma unroll
    for (int j = 0; j < 8; ++j) {
      int tt = NT - 2 - j; if (tt < 0) tt = 0;
      bd[j] = denb[tt + 1]; bb[j] = llb[(tt + 1) * (NU + 1)];
      blv[j] = llb[(tt + 1) * (NU + 1) + 1 + l];
    }
    for (int g = 0; g < 125; ++g) {
      float nd[8], nb[8], nl2[8];
      if (g < 124) {
#pragma unroll
        for (int j = 0; j < 8; ++j) {
          int tt = NT - 2 - 8 * (g + 1) - j; if (tt < 0) tt = 0;
          nd[j] = denb[tt + 1]; nb[j] = llb[(tt + 1) * (NU + 1)];
          nl2[j] = llb[(tt + 1) * (NU + 1) + 1 + l];
        }
      } else {
#pragma unroll
        for (int j = 0; j < 8; ++j) { nd[j] = 0.f; nb[j] = 0.f; nl2[j] = 0.f; }
      }
#pragma unroll
      for (int j = 0; j < 8; ++j) {
        int t = NT - 2 - 8 * g - j;
        if (t >= 0) {
          float d2 = bd[j];
          float pbv = (bb[j] - d2) * LOG2E, plv = (blv[j] - d2) * LOG2E;
          float me = pbv + be;
          float mo = plv + bo;
          float m128 = pbv + b128;
          float ne = dpp_shl1(me); if (l == NU - 1) ne = m128;
          float no = dpp_shl1(mo); if (l == NU - 1) no = NEGINF;
          float ben = lae2b(me, mo);
          float bon = lae3b(mo, ne, skipn ? no : NEGINF);
          bpb[t * NU + l] = lsub2(bon, mo);
          be = ben; bo = bon; b128 = m128;
        }
      }
#pragma unroll
      for (int j = 0; j < 8; ++j) { bd[j] = nd[j]; bb[j] = nb[j]; blv[j] = nl2[j]; }
    }
  }
}

// -------- kernel 7: loss = mean_b( -sum_u lse_t(alpha+bp) / count ) --------
__global__ __launch_bounds__(256) void k_loss(const float* __restrict__ aod,
                                              const float* __restrict__ bp,
                                              const int* __restrict__ hlens,
                                              float* __restrict__ out) {
  __shared__ float ms[4][64], ss[4][64];
  int b = blockIdx.x, tid = threadIdx.x;
  int w = tid >> 6, l = tid & 63;
  const float* ab = aod + (size_t)b * NT * NU;
  const float* pb = bp + (size_t)b * NT * NU;
  float m = NEGINF, s = 0.f;
  int t0 = w * 250, t1 = t0 + 250;
  for (int t = t0; t < t1; ++t) {
    float x = ab[t * NU + l] + pb[t * NU + l];
    if (__builtin_isnan(x) || x == NEGINF) continue;
    if (x > m) { s = s * fexp2(m - x) + 1.0f; m = x; }
    else       { s += fexp2(x - m); }
  }
  ms[w][l] = m; ss[w][l] = s;
  __syncthreads();
  if (w == 0) {
    float m0 = ms[0][l], m1 = ms[1][l], m2 = ms[2][l], m3 = ms[3][l];
    float mm = fmaxf(fmaxf(m0, m1), fmaxf(m2, m3));
    float lu;
    if (mm == NEGINF) lu = NEGINF;
    else {
      float st = ((m0 == NEGINF) ? 0.f : ss[0][l] * fexp2(m0 - mm))
               + ((m1 == NEGINF) ? 0.f : ss[1][l] * fexp2(m1 - mm))
               + ((m2 == NEGINF) ? 0.f : ss[2][l] * fexp2(m2 - mm))
               + ((m3 == NEGINF) ? 0.f : ss[3][l] * fexp2(m3 - mm));
      lu = (mm + flog2(st)) * LN2F;
    }
    bool msk = __builtin_isinf(lu);
    float sv = msk ? 0.f : lu;
    float cv = msk ? 0.f : 1.f;
#pragma unroll
    for (int d = 1; d < 64; d <<= 1) { sv += __shfl_xor(sv, d); cv += __shfl_xor(cv, d); }
    if (l == 0) {
      float lf = sv / cv;
      if (hlens[b] < NU) lf = 0.f;
      atomicAdd(out, -lf * (1.0f / NB));
    }
  }
}

// ---------------------------------------------------------------------------
extern "C" void kernel_launch(void* const* d_in, const int* in_sizes, int n_in,
                              void* d_out, int out_size, void* d_ws, size_t ws_size,
                              hipStream_t stream) {
  const float* hs    = (const float*)d_in[0];
  const int*   hlens = (const int*)d_in[1];
  const int*   ys    = (const int*)d_in[2];
  const float* W     = (const float*)d_in[4];
  const float* bias  = (const float*)d_in[5];
  float* out = (float*)d_out;

  char* ws = (char*)d_ws;
  short* hsb   = (short*)(ws + 0);           // 16,384,000 B  [16000][512] bf16
  float* bpb   = (float*)(ws + 0);           //  4,096,000 B  aliases hsb (dead after k_denom)
  short* WT    = (short*)(ws + 16384000);    //  5,120,000 B  [5000][512] bf16
  float* Wg    = (float*)(ws + 21504000);    //  8,519,680 B  [16][512][65] f32 (dead after k_lab)
  float* pm    = (float*)(ws + 21504000);    //  2,560,000 B  aliases Wg: [40][16000]
  float* psv   = (float*)(ws + 24064000);    //  2,560,000 B  aliases Wg: [40][16000]
  float* ll    = (float*)(ws + 30023680);    //  4,160,000 B  [16][1000][65] f32
  float* dnm   = (float*)(ws + 34183680);    //     64,000 B  [16][1000] f32
  float* aod   = (float*)(ws + 34247680);    //  4,096,000 B  [16][1000][64] f32

  k_zero<<<1, 64, 0, stream>>>(out);
  k_cvt_hs<<<4000, 256, 0, stream>>>(hs, hsb);
  k_cvt_wt<<<dim3(79, 8), 256, 0, stream>>>(W, WT);
  k_gather<<<dim3(512, 16), 128, 0, stream>>>(W, ys, Wg);
  k_lab<<<dim3(1000, 16), 192, 0, stream>>>(hs, Wg, ys, bias, ll);
  k_denom<<<dim3(250, 40), 256, 0, stream>>>(hsb, WT, bias, pm, psv);
  k_dred<<<63, 256, 0, stream>>>(pm, psv, dnm);
  k_fwdbwd<<<32, 64, 0, stream>>>(ll, dnm, ys, aod, bpb);
  k_loss<<<16, 256, 0, stream>>>(aod, bpb, hlens, out);
}

// Round 5
// 592.576 us; speedup vs baseline: 1.8831x; 1.1591x over previous
//
#include <hip/hip_runtime.h>

// Problem constants (SpeakerAwareCTC): B=16, T=1000, D=512, V=5000, U=64, S=2U+1=129
#define NB 16
#define NT 1000
#define ND 512
#define NV 5000
#define NVP 5120          // WT padded rows (zeros beyond 5000)
#define NU 64
#define NM (NB * NT)      // 16000 flattened rows
#define NCH 40            // N-chunks of 128 cols

typedef short short8v __attribute__((ext_vector_type(8)));
typedef float float4v __attribute__((ext_vector_type(4)));

#define NEGINF (-__builtin_inff())
#define LOG2E 1.4426950408889634f
#define LN2F  0.6931471805599453f
// reference sentinel: -2001 + logf(expf(1)-1) = -2000.4586751f (natural), in base-2:
#define SENT2 (-2000.4586751f * LOG2E)

__device__ __forceinline__ float fexp2(float x) { return __builtin_amdgcn_exp2f(x); }
__device__ __forceinline__ float flog2(float x) { return __builtin_amdgcn_logf(x); }

// DPP lane shifts (VALU-latency, replaces ds_bpermute-based __shfl in serial chain)
__device__ __forceinline__ float dpp_shr1(float x) {  // lane i <- lane i-1
  int xi = __builtin_bit_cast(int, x);
  int r = __builtin_amdgcn_update_dpp(xi, xi, 0x138, 0xf, 0xf, false);
  return __builtin_bit_cast(float, r);
}
__device__ __forceinline__ float dpp_shl1(float x) {  // lane i <- lane i+1
  int xi = __builtin_bit_cast(int, x);
  int r = __builtin_amdgcn_update_dpp(xi, xi, 0x130, 0xf, 0xf, false);
  return __builtin_bit_cast(float, r);
}

__device__ __forceinline__ short f2bf(float x) {
  unsigned int u = __builtin_bit_cast(unsigned int, x);
  unsigned int r = (u + 0x7fffu + ((u >> 16) & 1u)) >> 16;
  return (short)(unsigned short)r;
}

// async global->LDS, 16B per lane; LDS dest = wave-uniform base + lane*16
__device__ __forceinline__ void g2lds16(const short* g, short* l) {
  __builtin_amdgcn_global_load_lds(
      (const __attribute__((address_space(1))) void*)g,
      (__attribute__((address_space(3))) void*)l, 16, 0, 0);
}

// branchless base-2 logaddexp (clamp instead of -inf branch)
__device__ __forceinline__ float lae2b(float a, float b) {
  float m = fmaxf(fmaxf(a, b), -3.0e38f);
  return m + flog2(fexp2(a - m) + fexp2(b - m));
}
__device__ __forceinline__ float lae3b(float a, float b, float c) {
  float m = fmaxf(fmaxf(a, b), fmaxf(c, -3.0e38f));
  return m + flog2(fexp2(a - m) + fexp2(b - m) + fexp2(c - m));
}
// faithful base-2 port of reference log_substraction_exp (sentinel -> constant)
__device__ __forceinline__ float lsub2(float a, float b) {
  bool ia = __builtin_isinf(a), ib = __builtin_isinf(b);
  float tmp = b + flog2(fexp2(a - b) - 1.0f);
  if (__builtin_isinf(tmp)) tmp = SENT2;
  float res = (!ia && !ib) ? tmp : NEGINF;
  if (!ia && ib) res = a;
  return res;
}

// ---------------- kernel 0: zero the scalar output -------------------------
__global__ void k_zero(float* out) {
  if (threadIdx.x == 0) out[0] = 0.0f;
}

// ---------------- kernel 1: hs f32 -> bf16, granule-swizzled ---------------
// granule = 8 shorts (16B). Within each aligned 8-granule window of a row,
// store granule g at position g ^ (row&7)  (involution; undone by ds_read XOR)
__global__ __launch_bounds__(256) void k_cvt_hs(const float* __restrict__ in,
                                                short* __restrict__ out) {
  size_t i = (size_t)blockIdx.x * 256 + threadIdx.x;  // granule id, 1,024,000 total
  const float4* p = (const float4*)in + i * 2;
  float4 v0 = p[0], v1 = p[1];
  short8v r;
  r[0] = f2bf(v0.x); r[1] = f2bf(v0.y); r[2] = f2bf(v0.z); r[3] = f2bf(v0.w);
  r[4] = f2bf(v1.x); r[5] = f2bf(v1.y); r[6] = f2bf(v1.z); r[7] = f2bf(v1.w);
  int row = (int)(i >> 6);        // 64 granules per 512-col row
  int g = (int)(i & 63);
  int gs = (g & ~7) | ((g & 7) ^ (row & 7));
  *(short8v*)(out + (size_t)row * ND + gs * 8) = r;
}

// ------------- kernel 2: W [512][5000] f32 -> WT [5120][512] bf16 ----------
// transposed, granule-swizzled rows; rows >= 5000 are zero.
__global__ __launch_bounds__(256) void k_cvt_wt(const float* __restrict__ W,
                                                short* __restrict__ WT) {
  __shared__ short tile[64 * 72];
  int n0 = blockIdx.x * 64, k0 = blockIdx.y * 64;
  int tid = threadIdx.x;
  int kr = tid >> 2, part = tid & 3;
  const float* src = W + (size_t)(k0 + kr) * NV + n0 + part * 16;
#pragma unroll
  for (int jj = 0; jj < 4; ++jj) {
    int c = n0 + part * 16 + jj * 4;
    float4 v;
    if (c + 3 < NV) {
      v = *(const float4*)(src + jj * 4);
    } else {
      v.x = (c + 0 < NV) ? src[jj * 4 + 0] : 0.f;
      v.y = (c + 1 < NV) ? src[jj * 4 + 1] : 0.f;
      v.z = (c + 2 < NV) ? src[jj * 4 + 2] : 0.f;
      v.w = (c + 3 < NV) ? src[jj * 4 + 3] : 0.f;
    }
    int base = kr * 72 + part * 16 + jj * 4;
    tile[base + 0] = f2bf(v.x); tile[base + 1] = f2bf(v.y);
    tile[base + 2] = f2bf(v.z); tile[base + 3] = f2bf(v.w);
  }
  __syncthreads();
  int n = tid & 63, kq = tid >> 6;
  int nn = n0 + n;
  if (nn < NVP) {
#pragma unroll
    for (int half = 0; half < 2; ++half) {
      short8v val;
#pragma unroll
      for (int jj = 0; jj < 8; ++jj) val[jj] = tile[(kq * 16 + half * 8 + jj) * 72 + n];
      int g = (k0 >> 3) + kq * 2 + half;              // absolute granule in row
      int gs = (g & ~7) | ((g & 7) ^ (nn & 7));
      *(short8v*)(WT + (size_t)nn * ND + gs * 8) = val;
    }
  }
}

// -------- kernel 3: gather Wg[b][k][u] = W[k][lab(b,u)] (f32) --------------
__global__ void k_gather(const float* __restrict__ W, const int* __restrict__ ys,
                         float* __restrict__ Wg) {
  int k = blockIdx.x, b = blockIdx.y, u = threadIdx.x;
  if (u < NU + 1) {
    int lab = (u == 0) ? 0 : ys[b * NU + u - 1];
    Wg[((size_t)b * ND + k) * (NU + 1) + u] = W[(size_t)k * NV + lab];
  }
}

// -------- kernel 4: ll[b][t][u] = hs[b,t,:] . Wg[b,:,u] + bias[lab] --------
__global__ __launch_bounds__(192) void k_lab(const float* __restrict__ hs,
                                             const float* __restrict__ Wg,
                                             const int* __restrict__ ys,
                                             const float* __restrict__ bias,
                                             float* __restrict__ ll) {
  __shared__ float hsr[ND];
  __shared__ float part[130];
  int t = blockIdx.x, b = blockIdx.y, tid = threadIdx.x;
  if (tid < 128)
    ((float4*)hsr)[tid] = ((const float4*)(hs + ((size_t)(b * NT + t)) * ND))[tid];
  __syncthreads();
  if (tid < 130) {
    int u = (tid < 65) ? tid : tid - 65;
    int h = (tid < 65) ? 0 : 1;
    const float* wg = Wg + (size_t)b * ND * (NU + 1) + (size_t)(h * 256) * (NU + 1) + u;
    const float* hh = hsr + h * 256;
    float acc = 0.f;
#pragma unroll 8
    for (int k = 0; k < 256; ++k) acc += hh[k] * wg[(size_t)k * (NU + 1)];
    part[tid] = acc;
  }
  __syncthreads();
  if (tid < 65) {
    int lab = (tid == 0) ? 0 : ys[b * NU + tid - 1];
    ll[((size_t)(b * NT + t)) * (NU + 1) + tid] = part[tid] + part[tid + 65] + bias[lab];
  }
}

// -------- kernel 5: per-chunk partial logsumexp of hs@W + b (bf16 MFMA) ----
// m97 structure: 128x128 tile, BK=64, global_load_lds w16, swizzled LDS.
// grid (125 M-tiles, 40 N-chunks). 256 thr = 4 waves (2x2), 4x4 frags/wave.
__global__ __launch_bounds__(256) void k_denom(const short* __restrict__ hsb,
                                               const short* __restrict__ WT,
                                               const float* __restrict__ bias,
                                               float* __restrict__ pm,
                                               float* __restrict__ ps) {
  __shared__ short As[2][128 * 64];
  __shared__ short Ws[2][128 * 64];
  __shared__ float mred[128][2];
  __shared__ float sred[128][2];

  int t0 = blockIdx.x * 128;
  int chunk = blockIdx.y;
  int n0 = chunk * 128;
  int tid = threadIdx.x;
  int lane = tid & 63, wave = tid >> 6;
  int wm = wave >> 1, wn = wave & 1;
  int lrow = lane & 15, lkhi = lane >> 4;

  // staging: wave w covers rows 32w..32w+31 of each tile; 4 instrs x 8 rows.
  // lane l: row += l>>3, granule = l&7 (LDS dest = base + lane*16, linear).
  const short* gaBase = hsb + (size_t)(t0 + wave * 32 + (lane >> 3)) * ND + (lane & 7) * 8;
  const short* gwBase = WT + (size_t)(n0 + wave * 32 + (lane >> 3)) * ND + (lane & 7) * 8;

  float4v acc[4][4];
#pragma unroll
  for (int m = 0; m < 4; ++m)
#pragma unroll
    for (int n = 0; n < 4; ++n)
#pragma unroll
      for (int j = 0; j < 4; ++j) acc[m][n][j] = 0.f;

  auto stage = [&](int s, int bw) {
    int k0 = s * 64;
#pragma unroll
    for (int i = 0; i < 4; ++i) {
      g2lds16(gaBase + (size_t)(i * 8) * ND + k0, &As[bw][(wave * 32 + i * 8) * 64]);
      g2lds16(gwBase + (size_t)(i * 8) * ND + k0, &Ws[bw][(wave * 32 + i * 8) * 64]);
    }
  };
  auto compute = [&](int bw) {
#pragma unroll
    for (int kk = 0; kk < 2; ++kk) {
      short8v av[4], wv[4];
#pragma unroll
      for (int m = 0; m < 4; ++m) {
        int r = wm * 64 + m * 16 + lrow;
        int col = (kk * 32 + lkhi * 8) ^ ((r & 7) << 3);   // shorts; XOR un-swizzles
        av[m] = *(const short8v*)&As[bw][r * 64 + col];
      }
#pragma unroll
      for (int n = 0; n < 4; ++n) {
        int r = wn * 64 + n * 16 + lrow;
        int col = (kk * 32 + lkhi * 8) ^ ((r & 7) << 3);
        wv[n] = *(const short8v*)&Ws[bw][r * 64 + col];
      }
#pragma unroll
      for (int m = 0; m < 4; ++m)
#pragma unroll
        for (int n = 0; n < 4; ++n)
          acc[m][n] = __builtin_amdgcn_mfma_f32_16x16x32_bf16(av[m], wv[n], acc[m][n], 0, 0, 0);
    }
  };

  stage(0, 0);
  __syncthreads();
  int cur = 0;
  for (int s = 0; s < 8; ++s) {
    if (s + 1 < 8) stage(s + 1, cur ^ 1);   // loads in flight during compute
    compute(cur);
    __syncthreads();                         // drains vmcnt(0): next buf ready
    cur ^= 1;
  }

  // epilogue: per-row (m,s) over this chunk's 128 cols (mask cols >= NV)
  float bcol[4]; bool cval[4];
#pragma unroll
  for (int n = 0; n < 4; ++n) {
    int c = n0 + wn * 64 + n * 16 + lrow;
    cval[n] = c < NV;
    bcol[n] = cval[n] ? bias[c] : 0.f;
  }
#pragma unroll
  for (int m = 0; m < 4; ++m)
#pragma unroll
    for (int j = 0; j < 4; ++j) {
      float mx = NEGINF;
#pragma unroll
      for (int n = 0; n < 4; ++n) {
        float v = cval[n] ? acc[m][n][j] + bcol[n] : NEGINF;
        mx = fmaxf(mx, v);
      }
#pragma unroll
      for (int d = 1; d < 16; d <<= 1) mx = fmaxf(mx, __shfl_xor(mx, d));
      float mxc = fmaxf(mx, -3.0e38f);   // NaN guard (all-invalid half-tile)
      float p = 0.f;
#pragma unroll
      for (int n = 0; n < 4; ++n) {
        float v = cval[n] ? acc[m][n][j] + bcol[n] : NEGINF;
        p += __expf(v - mxc);
      }
#pragma unroll
      for (int d = 1; d < 16; d <<= 1) p += __shfl_xor(p, d);
      if (lrow == 0) {
        int rloc = wm * 64 + m * 16 + lkhi * 4 + j;
        mred[rloc][wn] = mx;
        sred[rloc][wn] = p;
      }
    }
  __syncthreads();
  if (tid < 128) {
    int row = t0 + tid;
    float m0 = mred[tid][0], m1 = mred[tid][1];
    float m = fmaxf(m0, m1);
    float ss = 0.f;
    if (m != NEGINF)
      ss = ((m0 == NEGINF) ? 0.f : sred[tid][0] * __expf(m0 - m))
         + ((m1 == NEGINF) ? 0.f : sred[tid][1] * __expf(m1 - m));
    pm[(size_t)chunk * NM + row] = m;
    ps[(size_t)chunk * NM + row] = ss;
  }
}

// -------- kernel 5b: combine 40 chunk partials -> denom[row] ---------------
__global__ __launch_bounds__(256) void k_dred(const float* __restrict__ pm,
                                              const float* __restrict__ ps,
                                              float* __restrict__ denom) {
  int row = blockIdx.x * 256 + threadIdx.x;
  if (row >= NM) return;
  float m = NEGINF, s = 0.f;
  for (int c = 0; c < NCH; ++c) {
    float mc = pm[(size_t)c * NM + row];
    float sc = ps[(size_t)c * NM + row];
    if (mc == NEGINF) continue;
    if (mc > m) { s = s * __expf(m - mc) + sc; m = mc; }
    else        { s += sc * __expf(mc - m); }
  }
  denom[row] = m + __logf(s);
}

// -------- kernel 6: fwd (blocks 0..15) || bwd (blocks 16..31), base-2 ------
__global__ __launch_bounds__(64) void k_fwdbwd(const float* __restrict__ ll,
                                               const float* __restrict__ denom,
                                               const int* __restrict__ ys,
                                               float* __restrict__ aod,
                                               float* __restrict__ bp) {
  int bid = blockIdx.x;
  int l = threadIdx.x;
  if (bid < NB) {
    // ---------------- forward ----------------
    int b = bid;
    int lab = ys[b * NU + l];
    int labp = ys[b * NU + ((l >= 1) ? (l - 1) : 0)];
    bool skip = (l >= 1) && (lab != labp);
    const float* llb = ll + (size_t)b * NT * (NU + 1);
    const float* denb = denom + b * NT;
    float* aodb = aod + (size_t)b * NT * NU;

    float den = denb[0];
    float ae = (l == 0) ? (llb[0] - den) * LOG2E : NEGINF;
    float ao = (l == 0) ? (llb[1] - den) * LOG2E : NEGINF;
    if (l == 0) aodb[0] = ao; else aodb[l] = NEGINF;

    float cd[8], cb[8], cl[8];
#pragma unroll
    for (int j = 0; j < 8; ++j) {
      int tt = 1 + j; if (tt > NT - 1) tt = NT - 1;
      cd[j] = denb[tt]; cb[j] = llb[tt * (NU + 1)]; cl[j] = llb[tt * (NU + 1) + 1 + l];
    }
    for (int g = 0; g < 125; ++g) {
      float nd[8], nb[8], nl[8];
      if (g < 124) {
#pragma unroll
        for (int j = 0; j < 8; ++j) {
          int tt = 9 + g * 8 + j; if (tt > NT - 1) tt = NT - 1;
          nd[j] = denb[tt]; nb[j] = llb[tt * (NU + 1)]; nl[j] = llb[tt * (NU + 1) + 1 + l];
        }
      } else {
#pragma unroll
        for (int j = 0; j < 8; ++j) { nd[j] = 0.f; nb[j] = 0.f; nl[j] = 0.f; }
      }
#pragma unroll
      for (int j = 0; j < 8; ++j) {
        int t = 1 + g * 8 + j;
        if (t < NT) {
          float d2 = cd[j];
          float pb = (cb[j] - d2) * LOG2E, pl = (cl[j] - d2) * LOG2E;
          float po = dpp_shr1(ao); if (l == 0) po = NEGINF;
          float aen = pb + lae2b(ae, po);
          float aon = pl + lae3b(ao, ae, skip ? po : NEGINF);
          ae = aen; ao = aon;
          aodb[t * NU + l] = ao;
        }
      }
#pragma unroll
      for (int j = 0; j < 8; ++j) { cd[j] = nd[j]; cb[j] = nb[j]; cl[j] = nl[j]; }
    }
  } else {
    // ---------------- backward ----------------
    int b = bid - NB;
    int lab = ys[b * NU + l];
    int labn = ys[b * NU + ((l < NU - 1) ? (l + 1) : l)];
    bool skipn = (l < NU - 1) && (labn != lab);
    const float* llb = ll + (size_t)b * NT * (NU + 1);
    const float* denb = denom + b * NT;
    float* bpb = bp + (size_t)b * NT * NU;

    float bo = (l == NU - 1) ? 0.0f : NEGINF;
    float be = NEGINF;
    float b128 = 0.0f;
    bpb[(NT - 1) * NU + l] = bo;

    float bd[8], bb[8], blv[8];
#pragma unroll
    for (int j = 0; j < 8; ++j) {
      int tt = NT - 2 - j; if (tt < 0) tt = 0;
      bd[j] = denb[tt + 1]; bb[j] = llb[(tt + 1) * (NU + 1)];
      blv[j] = llb[(tt + 1) * (NU + 1) + 1 + l];
    }
    for (int g = 0; g < 125; ++g) {
      float nd[8], nb[8], nl2[8];
      if (g < 124) {
#pragma unroll
        for (int j = 0; j < 8; ++j) {
          int tt = NT - 2 - 8 * (g + 1) - j; if (tt < 0) tt = 0;
          nd[j] = denb[tt + 1]; nb[j] = llb[(tt + 1) * (NU + 1)];
          nl2[j] = llb[(tt + 1) * (NU + 1) + 1 + l];
        }
      } else {
#pragma unroll
        for (int j = 0; j < 8; ++j) { nd[j] = 0.f; nb[j] = 0.f; nl2[j] = 0.f; }
      }
#pragma unroll
      for (int j = 0; j < 8; ++j) {
        int t = NT - 2 - 8 * g - j;
        if (t >= 0) {
          float d2 = bd[j];
          float pbv = (bb[j] - d2) * LOG2E, plv = (blv[j] - d2) * LOG2E;
          float me = pbv + be;
          float mo = plv + bo;
          float m128 = pbv + b128;
          float ne = dpp_shl1(me); if (l == NU - 1) ne = m128;
          float no = dpp_shl1(mo); if (l == NU - 1) no = NEGINF;
          float ben = lae2b(me, mo);
          float bon = lae3b(mo, ne, skipn ? no : NEGINF);
          bpb[t * NU + l] = lsub2(bon, mo);
          be = ben; bo = bon; b128 = m128;
        }
      }
#pragma unroll
      for (int j = 0; j < 8; ++j) { bd[j] = nd[j]; bb[j] = nb[j]; blv[j] = nl2[j]; }
    }
  }
}

// -------- kernel 7: loss = mean_b( -sum_u lse_t(alpha+bp) / count ) --------
__global__ __launch_bounds__(256) void k_loss(const float* __restrict__ aod,
                                              const float* __restrict__ bp,
                                              const int* __restrict__ hlens,
                                              float* __restrict__ out) {
  __shared__ float ms[4][64], ss[4][64];
  int b = blockIdx.x, tid = threadIdx.x;
  int w = tid >> 6, l = tid & 63;
  const float* ab = aod + (size_t)b * NT * NU;
  const float* pb = bp + (size_t)b * NT * NU;
  float m = NEGINF, s = 0.f;
  int t0 = w * 250, t1 = t0 + 250;
  for (int t = t0; t < t1; ++t) {
    float x = ab[t * NU + l] + pb[t * NU + l];
    if (__builtin_isnan(x) || x == NEGINF) continue;
    if (x > m) { s = s * fexp2(m - x) + 1.0f; m = x; }
    else       { s += fexp2(x - m); }
  }
  ms[w][l] = m; ss[w][l] = s;
  __syncthreads();
  if (w == 0) {
    float m0 = ms[0][l], m1 = ms[1][l], m2 = ms[2][l], m3 = ms[3][l];
    float mm = fmaxf(fmaxf(m0, m1), fmaxf(m2, m3));
    float lu;
    if (mm == NEGINF) lu = NEGINF;
    else {
      float st = ((m0 == NEGINF) ? 0.f : ss[0][l] * fexp2(m0 - mm))
               + ((m1 == NEGINF) ? 0.f : ss[1][l] * fexp2(m1 - mm))
               + ((m2 == NEGINF) ? 0.f : ss[2][l] * fexp2(m2 - mm))
               + ((m3 == NEGINF) ? 0.f : ss[3][l] * fexp2(m3 - mm));
      lu = (mm + flog2(st)) * LN2F;
    }
    bool msk = __builtin_isinf(lu);
    float sv = msk ? 0.f : lu;
    float cv = msk ? 0.f : 1.f;
#pragma unroll
    for (int d = 1; d < 64; d <<= 1) { sv += __shfl_xor(sv, d); cv += __shfl_xor(cv, d); }
    if (l == 0) {
      float lf = sv / cv;
      if (hlens[b] < NU) lf = 0.f;
      atomicAdd(out, -lf * (1.0f / NB));
    }
  }
}

// ---------------------------------------------------------------------------
extern "C" void kernel_launch(void* const* d_in, const int* in_sizes, int n_in,
                              void* d_out, int out_size, void* d_ws, size_t ws_size,
                              hipStream_t stream) {
  const float* hs    = (const float*)d_in[0];
  const int*   hlens = (const int*)d_in[1];
  const int*   ys    = (const int*)d_in[2];
  const float* W     = (const float*)d_in[4];
  const float* bias  = (const float*)d_in[5];
  float* out = (float*)d_out;

  char* ws = (char*)d_ws;
  // phase A (GEMM): hsb, WT, pm, ps live
  short* hsb   = (short*)(ws + 0);           // 16,384,000 B  [16000][512] bf16 (swizzled)
  short* WT    = (short*)(ws + 16384000);    //  5,242,880 B  [5120][512] bf16 (swizzled, zero-padded)
  float* pm    = (float*)(ws + 21626880);    //  2,560,000 B  [40][16000]
  float* psv   = (float*)(ws + 24186880);    //  2,560,000 B  [40][16000]
  // phase B (trellis): hsb/WT/pm/ps dead -> reuse
  float* bpb   = (float*)(ws + 0);           //  4,096,000 B  aliases hsb
  float* ll    = (float*)(ws + 4096000);     //  4,160,000 B  aliases hsb
  float* Wg    = (float*)(ws + 21626880);    //  8,519,680 B  aliases pm/ps (dead after k_dred)
  float* dnm   = (float*)(ws + 30146560);    //     64,000 B
  float* aod   = (float*)(ws + 30210560);    //  4,096,000 B  (total 34,306,560 B)

  k_zero<<<1, 64, 0, stream>>>(out);
  k_cvt_hs<<<4000, 256, 0, stream>>>(hs, hsb);
  k_cvt_wt<<<dim3(80, 8), 256, 0, stream>>>(W, WT);
  k_denom<<<dim3(125, 40), 256, 0, stream>>>(hsb, WT, bias, pm, psv);
  k_dred<<<63, 256, 0, stream>>>(pm, psv, dnm);
  k_gather<<<dim3(512, 16), 128, 0, stream>>>(W, ys, Wg);
  k_lab<<<dim3(1000, 16), 192, 0, stream>>>(hs, Wg, ys, bias, ll);
  k_fwdbwd<<<32, 64, 0, stream>>>(ll, dnm, ys, aod, bpb);
  k_loss<<<16, 256, 0, stream>>>(aod, bpb, hlens, out);
}

// Round 6
// 526.875 us; speedup vs baseline: 2.1179x; 1.1247x over previous
//
#include <hip/hip_runtime.h>

// Problem constants (SpeakerAwareCTC): B=16, T=1000, D=512, V=5000, U=64, S=2U+1=129
#define NB 16
#define NT 1000
#define ND 512
#define NV 5000
#define NVP 5120          // WT padded rows (zeros beyond 5000)
#define NU 64
#define NM (NB * NT)      // 16000 flattened rows
#define NCH 40            // N-chunks of 128 cols

typedef short short8v __attribute__((ext_vector_type(8)));
typedef float float4v __attribute__((ext_vector_type(4)));

#define NEGINF (-__builtin_inff())
#define SENTL  (-1.0e30f)   // finite "-inf": exp2(SENTL - m) == 0 for any sane m
#define LOG2E 1.4426950408889634f
#define LN2F  0.6931471805599453f
// reference sentinel: -2001 + logf(expf(1)-1) = -2000.4586751f (natural), in base-2:
#define SENT2 (-2000.4586751f * LOG2E)

__device__ __forceinline__ float fexp2(float x) { return __builtin_amdgcn_exp2f(x); }
__device__ __forceinline__ float flog2(float x) { return __builtin_amdgcn_logf(x); }

// DPP lane shifts (VALU-latency; serial-chain friendly)
__device__ __forceinline__ float dpp_shr1(float x) {  // lane i <- lane i-1
  int xi = __builtin_bit_cast(int, x);
  int r = __builtin_amdgcn_update_dpp(xi, xi, 0x138, 0xf, 0xf, false);
  return __builtin_bit_cast(float, r);
}
__device__ __forceinline__ float dpp_shl1(float x) {  // lane i <- lane i+1
  int xi = __builtin_bit_cast(int, x);
  int r = __builtin_amdgcn_update_dpp(xi, xi, 0x130, 0xf, 0xf, false);
  return __builtin_bit_cast(float, r);
}

__device__ __forceinline__ short f2bf(float x) {
  unsigned int u = __builtin_bit_cast(unsigned int, x);
  unsigned int r = (u + 0x7fffu + ((u >> 16) & 1u)) >> 16;
  return (short)(unsigned short)r;
}

// async global->LDS, 16B per lane; LDS dest = wave-uniform base + lane*16
__device__ __forceinline__ void g2lds16(const short* g, short* l) {
  __builtin_amdgcn_global_load_lds(
      (const __attribute__((address_space(1))) void*)g,
      (__attribute__((address_space(3))) void*)l, 16, 0, 0);
}

// base-2 logaddexp on sentinel-finite values (no clamp needed)
__device__ __forceinline__ float lae2s(float a, float b) {
  float m = fmaxf(a, b);
  return m + flog2(fexp2(a - m) + fexp2(b - m));
}
__device__ __forceinline__ float lae3s(float a, float b, float c) {
  float m = fmaxf(fmaxf(a, b), c);   // -> v_max3
  return m + flog2(fexp2(a - m) + fexp2(b - m) + fexp2(c - m));
}
// base-2 port of reference log_substraction_exp (finite-sentinel inputs).
// NaN when a<b slightly (rounding) matches reference NaN -> masked downstream.
__device__ __forceinline__ float lsub2(float a, float b) {
  float tmp = b + flog2(fexp2(a - b) - 1.0f);
  if (__builtin_isinf(tmp)) tmp = SENT2;
  return tmp;
}

// ---------------- kernel 0: zero the scalar output -------------------------
__global__ void k_zero(float* out) {
  if (threadIdx.x == 0) out[0] = 0.0f;
}

// ---------------- kernel 1: hs f32 -> bf16, granule-swizzled ---------------
// granule = 8 shorts (16B). Within each aligned 8-granule window of a row,
// store granule g at position g ^ (row&7)  (involution; undone by ds_read XOR)
__global__ __launch_bounds__(256) void k_cvt_hs(const float* __restrict__ in,
                                                short* __restrict__ out) {
  size_t i = (size_t)blockIdx.x * 256 + threadIdx.x;  // granule id, 1,024,000 total
  const float4* p = (const float4*)in + i * 2;
  float4 v0 = p[0], v1 = p[1];
  short8v r;
  r[0] = f2bf(v0.x); r[1] = f2bf(v0.y); r[2] = f2bf(v0.z); r[3] = f2bf(v0.w);
  r[4] = f2bf(v1.x); r[5] = f2bf(v1.y); r[6] = f2bf(v1.z); r[7] = f2bf(v1.w);
  int row = (int)(i >> 6);        // 64 granules per 512-col row
  int g = (int)(i & 63);
  int gs = (g & ~7) | ((g & 7) ^ (row & 7));
  *(short8v*)(out + (size_t)row * ND + gs * 8) = r;
}

// ------------- kernel 2: W [512][5000] f32 -> WT [5120][512] bf16 ----------
// transposed, granule-swizzled rows; rows >= 5000 are zero.
__global__ __launch_bounds__(256) void k_cvt_wt(const float* __restrict__ W,
                                                short* __restrict__ WT) {
  __shared__ short tile[64 * 72];
  int n0 = blockIdx.x * 64, k0 = blockIdx.y * 64;
  int tid = threadIdx.x;
  int kr = tid >> 2, part = tid & 3;
  const float* src = W + (size_t)(k0 + kr) * NV + n0 + part * 16;
#pragma unroll
  for (int jj = 0; jj < 4; ++jj) {
    int c = n0 + part * 16 + jj * 4;
    float4 v;
    if (c + 3 < NV) {
      v = *(const float4*)(src + jj * 4);
    } else {
      v.x = (c + 0 < NV) ? src[jj * 4 + 0] : 0.f;
      v.y = (c + 1 < NV) ? src[jj * 4 + 1] : 0.f;
      v.z = (c + 2 < NV) ? src[jj * 4 + 2] : 0.f;
      v.w = (c + 3 < NV) ? src[jj * 4 + 3] : 0.f;
    }
    int base = kr * 72 + part * 16 + jj * 4;
    tile[base + 0] = f2bf(v.x); tile[base + 1] = f2bf(v.y);
    tile[base + 2] = f2bf(v.z); tile[base + 3] = f2bf(v.w);
  }
  __syncthreads();
  int n = tid & 63, kq = tid >> 6;
  int nn = n0 + n;
  if (nn < NVP) {
#pragma unroll
    for (int half = 0; half < 2; ++half) {
      short8v val;
#pragma unroll
      for (int jj = 0; jj < 8; ++jj) val[jj] = tile[(kq * 16 + half * 8 + jj) * 72 + n];
      int g = (k0 >> 3) + kq * 2 + half;              // absolute granule in row
      int gs = (g & ~7) | ((g & 7) ^ (nn & 7));
      *(short8v*)(WT + (size_t)nn * ND + gs * 8) = val;
    }
  }
}

// -------- kernel 3: gather Wg[b][k][u] = W[k][lab(b,u)] (f32) --------------
__global__ void k_gather(const float* __restrict__ W, const int* __restrict__ ys,
                         float* __restrict__ Wg) {
  int k = blockIdx.x, b = blockIdx.y, u = threadIdx.x;
  if (u < NU + 1) {
    int lab = (u == 0) ? 0 : ys[b * NU + u - 1];
    Wg[((size_t)b * ND + k) * (NU + 1) + u] = W[(size_t)k * NV + lab];
  }
}

// -------- kernel 4: ll[b][t][u] = hs[b,t,:] . Wg[b,:,u] + bias[lab] --------
__global__ __launch_bounds__(192) void k_lab(const float* __restrict__ hs,
                                             const float* __restrict__ Wg,
                                             const int* __restrict__ ys,
                                             const float* __restrict__ bias,
                                             float* __restrict__ ll) {
  __shared__ float hsr[ND];
  __shared__ float part[130];
  int t = blockIdx.x, b = blockIdx.y, tid = threadIdx.x;
  if (tid < 128)
    ((float4*)hsr)[tid] = ((const float4*)(hs + ((size_t)(b * NT + t)) * ND))[tid];
  __syncthreads();
  if (tid < 130) {
    int u = (tid < 65) ? tid : tid - 65;
    int h = (tid < 65) ? 0 : 1;
    const float* wg = Wg + (size_t)b * ND * (NU + 1) + (size_t)(h * 256) * (NU + 1) + u;
    const float* hh = hsr + h * 256;
    float acc = 0.f;
#pragma unroll 8
    for (int k = 0; k < 256; ++k) acc += hh[k] * wg[(size_t)k * (NU + 1)];
    part[tid] = acc;
  }
  __syncthreads();
  if (tid < 65) {
    int lab = (tid == 0) ? 0 : ys[b * NU + tid - 1];
    ll[((size_t)(b * NT + t)) * (NU + 1) + tid] = part[tid] + part[tid + 65] + bias[lab];
  }
}

// -------- kernel 5: per-chunk partial logsumexp of hs@W + b (bf16 MFMA) ----
// m97 structure: 128x128 tile, BK=64, single-buffer LDS (34KB -> 4 blocks/CU),
// 2 barriers per K-step, global_load_lds w16, swizzled layout.
// 1D grid 5000; bijective XCD swizzle, m-major within XCD for L2 reuse.
__global__ __launch_bounds__(256) void k_denom(const short* __restrict__ hsb,
                                               const short* __restrict__ WT,
                                               const float* __restrict__ bias,
                                               float* __restrict__ pm,
                                               float* __restrict__ ps) {
  __shared__ short As[128 * 64];
  __shared__ short Ws[128 * 64];
  __shared__ float mred[128][2];
  __shared__ float sred[128][2];

  int lin = blockIdx.x;                       // 5000 = 8 * 625
  int wg = (lin & 7) * 625 + (lin >> 3);      // XCD-contiguous
  int mt = wg / NCH, chunk = wg % NCH;        // m-major within XCD
  int t0 = mt * 128;
  int n0 = chunk * 128;
  int tid = threadIdx.x;
  int lane = tid & 63, wave = tid >> 6;
  int wm = wave >> 1, wn = wave & 1;
  int lrow = lane & 15, lkhi = lane >> 4;

  // staging: wave w covers rows 32w..32w+31; lane l: row += l>>3, granule l&7
  const short* gaBase = hsb + (size_t)(t0 + wave * 32 + (lane >> 3)) * ND + (lane & 7) * 8;
  const short* gwBase = WT + (size_t)(n0 + wave * 32 + (lane >> 3)) * ND + (lane & 7) * 8;

  float4v acc[4][4];
#pragma unroll
  for (int m = 0; m < 4; ++m)
#pragma unroll
    for (int n = 0; n < 4; ++n)
#pragma unroll
      for (int j = 0; j < 4; ++j) acc[m][n][j] = 0.f;

  auto stage = [&](int s) {
    int k0 = s * 64;
#pragma unroll
    for (int i = 0; i < 4; ++i) {
      g2lds16(gaBase + (size_t)(i * 8) * ND + k0, &As[(wave * 32 + i * 8) * 64]);
      g2lds16(gwBase + (size_t)(i * 8) * ND + k0, &Ws[(wave * 32 + i * 8) * 64]);
    }
  };
  auto compute = [&]() {
#pragma unroll
    for (int kk = 0; kk < 2; ++kk) {
      short8v av[4], wv[4];
#pragma unroll
      for (int m = 0; m < 4; ++m) {
        int r = wm * 64 + m * 16 + lrow;
        int col = (kk * 32 + lkhi * 8) ^ ((r & 7) << 3);   // un-swizzle
        av[m] = *(const short8v*)&As[r * 64 + col];
      }
#pragma unroll
      for (int n = 0; n < 4; ++n) {
        int r = wn * 64 + n * 16 + lrow;
        int col = (kk * 32 + lkhi * 8) ^ ((r & 7) << 3);
        wv[n] = *(const short8v*)&Ws[r * 64 + col];
      }
#pragma unroll
      for (int m = 0; m < 4; ++m)
#pragma unroll
        for (int n = 0; n < 4; ++n)
          acc[m][n] = __builtin_amdgcn_mfma_f32_16x16x32_bf16(av[m], wv[n], acc[m][n], 0, 0, 0);
    }
  };

  for (int s = 0; s < 8; ++s) {
    stage(s);             // async loads in flight
    __syncthreads();      // drains vmcnt(0): data in LDS
    compute();
    __syncthreads();      // all waves done reading before next overwrite
  }

  // epilogue: per-row (m,s) over this chunk's 128 cols (mask cols >= NV)
  float bcol[4]; bool cval[4];
#pragma unroll
  for (int n = 0; n < 4; ++n) {
    int c = n0 + wn * 64 + n * 16 + lrow;
    cval[n] = c < NV;
    bcol[n] = cval[n] ? bias[c] : 0.f;
  }
#pragma unroll
  for (int m = 0; m < 4; ++m)
#pragma unroll
    for (int j = 0; j < 4; ++j) {
      float mx = NEGINF;
#pragma unroll
      for (int n = 0; n < 4; ++n) {
        float v = cval[n] ? acc[m][n][j] + bcol[n] : NEGINF;
        mx = fmaxf(mx, v);
      }
#pragma unroll
      for (int d = 1; d < 16; d <<= 1) mx = fmaxf(mx, __shfl_xor(mx, d));
      float mxc = fmaxf(mx, -3.0e38f);   // NaN guard (all-invalid half-tile)
      float p = 0.f;
#pragma unroll
      for (int n = 0; n < 4; ++n) {
        float v = cval[n] ? acc[m][n][j] + bcol[n] : NEGINF;
        p += __expf(v - mxc);
      }
#pragma unroll
      for (int d = 1; d < 16; d <<= 1) p += __shfl_xor(p, d);
      if (lrow == 0) {
        int rloc = wm * 64 + m * 16 + lkhi * 4 + j;
        mred[rloc][wn] = mx;
        sred[rloc][wn] = p;
      }
    }
  __syncthreads();
  if (tid < 128) {
    int row = t0 + tid;
    float m0 = mred[tid][0], m1 = mred[tid][1];
    float m = fmaxf(m0, m1);
    float ss = 0.f;
    if (m != NEGINF)
      ss = ((m0 == NEGINF) ? 0.f : sred[tid][0] * __expf(m0 - m))
         + ((m1 == NEGINF) ? 0.f : sred[tid][1] * __expf(m1 - m));
    pm[(size_t)chunk * NM + row] = m;
    ps[(size_t)chunk * NM + row] = ss;
  }
}

// -------- kernel 5b: combine 40 chunk partials -> denom[row] ---------------
__global__ __launch_bounds__(256) void k_dred(const float* __restrict__ pm,
                                              const float* __restrict__ ps,
                                              float* __restrict__ denom) {
  int row = blockIdx.x * 256 + threadIdx.x;
  if (row >= NM) return;
  float m = NEGINF, s = 0.f;
  for (int c = 0; c < NCH; ++c) {
    float mc = pm[(size_t)c * NM + row];
    float sc = ps[(size_t)c * NM + row];
    if (mc == NEGINF) continue;
    if (mc > m) { s = s * __expf(m - mc) + sc; m = mc; }
    else        { s += sc * __expf(mc - m); }
  }
  denom[row] = m + __logf(s);
}

// -------- kernel 6: fwd (blocks 0..15) || bwd (blocks 16..31) --------------
// base-2, finite sentinels (SENTL instead of -inf), group unroll 16.
__global__ __launch_bounds__(64) void k_fwdbwd(const float* __restrict__ ll,
                                               const float* __restrict__ denom,
                                               const int* __restrict__ ys,
                                               float* __restrict__ aod,
                                               float* __restrict__ bp) {
  int bid = blockIdx.x;
  int l = threadIdx.x;
  if (bid < NB) {
    // ---------------- forward ----------------
    int b = bid;
    int lab = ys[b * NU + l];
    int labp = ys[b * NU + ((l >= 1) ? (l - 1) : 0)];
    bool skip = (l >= 1) && (lab != labp);
    const float* llb = ll + (size_t)b * NT * (NU + 1);
    const float* denb = denom + b * NT;
    float* aodb = aod + (size_t)b * NT * NU;

    float den = denb[0];
    float ae = (l == 0) ? (llb[0] - den) * LOG2E : SENTL;
    float ao = (l == 0) ? (llb[1] - den) * LOG2E : SENTL;
    aodb[l] = ao;

    float cd[16], cb[16], cl[16];
#pragma unroll
    for (int j = 0; j < 16; ++j) {
      int tt = 1 + j; if (tt > NT - 1) tt = NT - 1;
      cd[j] = denb[tt]; cb[j] = llb[tt * (NU + 1)]; cl[j] = llb[tt * (NU + 1) + 1 + l];
    }
    for (int g = 0; g < 63; ++g) {
      float nd[16], nb[16], nl[16];
      if (g < 62) {
#pragma unroll
        for (int j = 0; j < 16; ++j) {
          int tt = 17 + g * 16 + j; if (tt > NT - 1) tt = NT - 1;
          nd[j] = denb[tt]; nb[j] = llb[tt * (NU + 1)]; nl[j] = llb[tt * (NU + 1) + 1 + l];
        }
      } else {
#pragma unroll
        for (int j = 0; j < 16; ++j) { nd[j] = 0.f; nb[j] = 0.f; nl[j] = 0.f; }
      }
#pragma unroll
      for (int j = 0; j < 16; ++j) {
        int t = 1 + g * 16 + j;
        if (t < NT) {
          float d2 = cd[j];
          float pb = (cb[j] - d2) * LOG2E, pl = (cl[j] - d2) * LOG2E;
          float po = dpp_shr1(ao); if (l == 0) po = SENTL;
          float aen = pb + lae2s(ae, po);
          float aon = pl + lae3s(ao, ae, skip ? po : SENTL);
          ae = aen; ao = aon;
          aodb[t * NU + l] = ao;
        }
      }
#pragma unroll
      for (int j = 0; j < 16; ++j) { cd[j] = nd[j]; cb[j] = nb[j]; cl[j] = nl[j]; }
    }
  } else {
    // ---------------- backward ----------------
    int b = bid - NB;
    int lab = ys[b * NU + l];
    int labn = ys[b * NU + ((l < NU - 1) ? (l + 1) : l)];
    bool skipn = (l < NU - 1) && (labn != lab);
    const float* llb = ll + (size_t)b * NT * (NU + 1);
    const float* denb = denom + b * NT;
    float* bpb = bp + (size_t)b * NT * NU;

    float bo = (l == NU - 1) ? 0.0f : SENTL;
    float be = SENTL;
    float b128 = 0.0f;
    bpb[(NT - 1) * NU + l] = bo;

    float bd[16], bb[16], blv[16];
#pragma unroll
    for (int j = 0; j < 16; ++j) {
      int tt = NT - 2 - j; if (tt < 0) tt = 0;
      bd[j] = denb[tt + 1]; bb[j] = llb[(tt + 1) * (NU + 1)];
      blv[j] = llb[(tt + 1) * (NU + 1) + 1 + l];
    }
    for (int g = 0; g < 63; ++g) {
      float nd[16], nb[16], nl2[16];
      if (g < 62) {
#pragma unroll
        for (int j = 0; j < 16; ++j) {
          int tt = NT - 2 - 16 * (g + 1) - j; if (tt < 0) tt = 0;
          nd[j] = denb[tt + 1]; nb[j] = llb[(tt + 1) * (NU + 1)];
          nl2[j] = llb[(tt + 1) * (NU + 1) + 1 + l];
        }
      } else {
#pragma unroll
        for (int j = 0; j < 16; ++j) { nd[j] = 0.f; nb[j] = 0.f; nl2[j] = 0.f; }
      }
#pragma unroll
      for (int j = 0; j < 16; ++j) {
        int t = NT - 2 - 16 * g - j;
        if (t >= 0) {
          float d2 = bd[j];
          float pbv = (bb[j] - d2) * LOG2E, plv = (blv[j] - d2) * LOG2E;
          float me = pbv + be;
          float mo = plv + bo;
          float m128 = pbv + b128;
          float ne = dpp_shl1(me); if (l == NU - 1) ne = m128;
          float no = dpp_shl1(mo); if (l == NU - 1) no = SENTL;
          float ben = lae2s(me, mo);
          float bon = lae3s(mo, ne, skipn ? no : SENTL);
          bpb[t * NU + l] = lsub2(bon, mo);
          be = ben; bo = bon; b128 = m128;
        }
      }
#pragma unroll
      for (int j = 0; j < 16; ++j) { bd[j] = nd[j]; bb[j] = nb[j]; blv[j] = nl2[j]; }
    }
  }
}

// -------- kernel 7: loss = mean_b( -sum_u lse_t(alpha+bp) / count ) --------
__global__ __launch_bounds__(256) void k_loss(const float* __restrict__ aod,
                                              const float* __restrict__ bp,
                                              const int* __restrict__ hlens,
                                              float* __restrict__ out) {
  __shared__ float ms[4][64], ss[4][64];
  int b = blockIdx.x, tid = threadIdx.x;
  int w = tid >> 6, l = tid & 63;
  const float* ab = aod + (size_t)b * NT * NU;
  const float* pb = bp + (size_t)b * NT * NU;
  float m = NEGINF, s = 0.f;
  int t0 = w * 250, t1 = t0 + 250;
  for (int t = t0; t < t1; ++t) {
    float x = ab[t * NU + l] + pb[t * NU + l];
    if (__builtin_isnan(x) || x < -1.0e29f) continue;   // sentinel == -inf
    if (x > m) { s = s * fexp2(m - x) + 1.0f; m = x; }
    else       { s += fexp2(x - m); }
  }
  ms[w][l] = m; ss[w][l] = s;
  __syncthreads();
  if (w == 0) {
    float m0 = ms[0][l], m1 = ms[1][l], m2 = ms[2][l], m3 = ms[3][l];
    float mm = fmaxf(fmaxf(m0, m1), fmaxf(m2, m3));
    float lu;
    if (mm == NEGINF) lu = NEGINF;
    else {
      float st = ((m0 == NEGINF) ? 0.f : ss[0][l] * fexp2(m0 - mm))
               + ((m1 == NEGINF) ? 0.f : ss[1][l] * fexp2(m1 - mm))
               + ((m2 == NEGINF) ? 0.f : ss[2][l] * fexp2(m2 - mm))
               + ((m3 == NEGINF) ? 0.f : ss[3][l] * fexp2(m3 - mm));
      lu = (mm + flog2(st)) * LN2F;
    }
    bool msk = __builtin_isinf(lu);
    float sv = msk ? 0.f : lu;
    float cv = msk ? 0.f : 1.f;
#pragma unroll
    for (int d = 1; d < 64; d <<= 1) { sv += __shfl_xor(sv, d); cv += __shfl_xor(cv, d); }
    if (l == 0) {
      float lf = sv / cv;
      if (hlens[b] < NU) lf = 0.f;
      atomicAdd(out, -lf * (1.0f / NB));
    }
  }
}

// ---------------------------------------------------------------------------
extern "C" void kernel_launch(void* const* d_in, const int* in_sizes, int n_in,
                              void* d_out, int out_size, void* d_ws, size_t ws_size,
                              hipStream_t stream) {
  const float* hs    = (const float*)d_in[0];
  const int*   hlens = (const int*)d_in[1];
  const int*   ys    = (const int*)d_in[2];
  const float* W     = (const float*)d_in[4];
  const float* bias  = (const float*)d_in[5];
  float* out = (float*)d_out;

  char* ws = (char*)d_ws;
  // phase A (GEMM): hsb, WT, pm, ps live
  short* hsb   = (short*)(ws + 0);           // 16,384,000 B  [16000][512] bf16 (swizzled)
  short* WT    = (short*)(ws + 16384000);    //  5,242,880 B  [5120][512] bf16 (swizzled, zero-padded)
  float* pm    = (float*)(ws + 21626880);    //  2,560,000 B  [40][16000]
  float* psv   = (float*)(ws + 24186880);    //  2,560,000 B  [40][16000]
  // phase B (trellis): hsb/WT/pm/ps dead -> reuse
  float* bpb   = (float*)(ws + 0);           //  4,096,000 B  aliases hsb
  float* ll    = (float*)(ws + 4096000);     //  4,160,000 B  aliases hsb
  float* Wg    = (float*)(ws + 21626880);    //  8,519,680 B  aliases pm/ps (dead after k_dred)
  float* dnm   = (float*)(ws + 30146560);    //     64,000 B
  float* aod   = (float*)(ws + 30210560);    //  4,096,000 B  (total 34,306,560 B)

  k_zero<<<1, 64, 0, stream>>>(out);
  k_cvt_hs<<<4000, 256, 0, stream>>>(hs, hsb);
  k_cvt_wt<<<dim3(80, 8), 256, 0, stream>>>(W, WT);
  k_denom<<<5000, 256, 0, stream>>>(hsb, WT, bias, pm, psv);
  k_dred<<<63, 256, 0, stream>>>(pm, psv, dnm);
  k_gather<<<dim3(512, 16), 128, 0, stream>>>(W, ys, Wg);
  k_lab<<<dim3(1000, 16), 192, 0, stream>>>(hs, Wg, ys, bias, ll);
  k_fwdbwd<<<32, 64, 0, stream>>>(ll, dnm, ys, aod, bpb);
  k_loss<<<16, 256, 0, stream>>>(aod, bpb, hlens, out);
}

// Round 7
// 413.621 us; speedup vs baseline: 2.6978x; 1.2738x over previous
//
#include <hip/hip_runtime.h>

// Problem constants (SpeakerAwareCTC): B=16, T=1000, D=512, V=5000, U=64, S=2U+1=129
#define NB 16
#define NT 1000
#define ND 512
#define NV 5000
#define NVP 5120          // WT padded rows (zeros beyond 5000)
#define NU 64
#define NM (NB * NT)      // 16000 flattened rows
#define NCH 40            // N-chunks of 128 cols

typedef short short8v __attribute__((ext_vector_type(8)));
typedef float float4v __attribute__((ext_vector_type(4)));

#define NEGINF (-__builtin_inff())
#define SENTL  (-1.0e30f)   // finite "-inf": exp2(SENTL - m) == 0 for any sane m
#define LOG2E 1.4426950408889634f
#define LN2F  0.6931471805599453f
// reference sentinel: -2001 + logf(expf(1)-1) = -2000.4586751f (natural), in base-2:
#define SENT2 (-2000.4586751f * LOG2E)

__device__ __forceinline__ float fexp2(float x) { return __builtin_amdgcn_exp2f(x); }
__device__ __forceinline__ float flog2(float x) { return __builtin_amdgcn_logf(x); }

// DPP lane shifts (VALU-latency; serial-chain friendly)
__device__ __forceinline__ float dpp_shr1(float x) {  // lane i <- lane i-1
  int xi = __builtin_bit_cast(int, x);
  int r = __builtin_amdgcn_update_dpp(xi, xi, 0x138, 0xf, 0xf, false);
  return __builtin_bit_cast(float, r);
}
__device__ __forceinline__ float dpp_shl1(float x) {  // lane i <- lane i+1
  int xi = __builtin_bit_cast(int, x);
  int r = __builtin_amdgcn_update_dpp(xi, xi, 0x130, 0xf, 0xf, false);
  return __builtin_bit_cast(float, r);
}

__device__ __forceinline__ short f2bf(float x) {
  unsigned int u = __builtin_bit_cast(unsigned int, x);
  unsigned int r = (u + 0x7fffu + ((u >> 16) & 1u)) >> 16;
  return (short)(unsigned short)r;
}
__device__ __forceinline__ float bf2f(short h) {
  unsigned int u = ((unsigned int)(unsigned short)h) << 16;
  return __builtin_bit_cast(float, u);
}

// async global->LDS, 16B per lane; LDS dest = wave-uniform base + lane*16
__device__ __forceinline__ void g2lds16(const short* g, short* l) {
  __builtin_amdgcn_global_load_lds(
      (const __attribute__((address_space(1))) void*)g,
      (__attribute__((address_space(3))) void*)l, 16, 0, 0);
}

// base-2 logaddexp on sentinel-finite values
__device__ __forceinline__ float lae2s(float a, float b) {
  float m = fmaxf(a, b);
  return m + flog2(fexp2(a - m) + fexp2(b - m));
}
__device__ __forceinline__ float lae3s(float a, float b, float c) {
  float m = fmaxf(fmaxf(a, b), c);
  return m + flog2(fexp2(a - m) + fexp2(b - m) + fexp2(c - m));
}
// base-2 port of reference log_substraction_exp (finite-sentinel inputs)
__device__ __forceinline__ float lsub2(float a, float b) {
  float tmp = b + flog2(fexp2(a - b) - 1.0f);
  if (__builtin_isinf(tmp)) tmp = SENT2;
  return tmp;
}

// ---------------- kernel 0: zero the scalar output -------------------------
__global__ void k_zero(float* out) {
  if (threadIdx.x == 0) out[0] = 0.0f;
}

// ---------------- kernel 1: hs f32 -> bf16, granule-swizzled ---------------
__global__ __launch_bounds__(256) void k_cvt_hs(const float* __restrict__ in,
                                                short* __restrict__ out) {
  size_t i = (size_t)blockIdx.x * 256 + threadIdx.x;  // granule id, 1,024,000 total
  const float4* p = (const float4*)in + i * 2;
  float4 v0 = p[0], v1 = p[1];
  short8v r;
  r[0] = f2bf(v0.x); r[1] = f2bf(v0.y); r[2] = f2bf(v0.z); r[3] = f2bf(v0.w);
  r[4] = f2bf(v1.x); r[5] = f2bf(v1.y); r[6] = f2bf(v1.z); r[7] = f2bf(v1.w);
  int row = (int)(i >> 6);        // 64 granules per 512-col row
  int g = (int)(i & 63);
  int gs = (g & ~7) | ((g & 7) ^ (row & 7));
  *(short8v*)(out + (size_t)row * ND + gs * 8) = r;
}

// ------------- kernel 2: W [512][5000] f32 -> WT [5120][512] bf16 ----------
__global__ __launch_bounds__(256) void k_cvt_wt(const float* __restrict__ W,
                                                short* __restrict__ WT) {
  __shared__ short tile[64 * 72];
  int n0 = blockIdx.x * 64, k0 = blockIdx.y * 64;
  int tid = threadIdx.x;
  int kr = tid >> 2, part = tid & 3;
  const float* src = W + (size_t)(k0 + kr) * NV + n0 + part * 16;
#pragma unroll
  for (int jj = 0; jj < 4; ++jj) {
    int c = n0 + part * 16 + jj * 4;
    float4 v;
    if (c + 3 < NV) {
      v = *(const float4*)(src + jj * 4);
    } else {
      v.x = (c + 0 < NV) ? src[jj * 4 + 0] : 0.f;
      v.y = (c + 1 < NV) ? src[jj * 4 + 1] : 0.f;
      v.z = (c + 2 < NV) ? src[jj * 4 + 2] : 0.f;
      v.w = (c + 3 < NV) ? src[jj * 4 + 3] : 0.f;
    }
    int base = kr * 72 + part * 16 + jj * 4;
    tile[base + 0] = f2bf(v.x); tile[base + 1] = f2bf(v.y);
    tile[base + 2] = f2bf(v.z); tile[base + 3] = f2bf(v.w);
  }
  __syncthreads();
  int n = tid & 63, kq = tid >> 6;
  int nn = n0 + n;
  if (nn < NVP) {
#pragma unroll
    for (int half = 0; half < 2; ++half) {
      short8v val;
#pragma unroll
      for (int jj = 0; jj < 8; ++jj) val[jj] = tile[(kq * 16 + half * 8 + jj) * 72 + n];
      int g = (k0 >> 3) + kq * 2 + half;
      int gs = (g & ~7) | ((g & 7) ^ (nn & 7));
      *(short8v*)(WT + (size_t)nn * ND + gs * 8) = val;
    }
  }
}

// -------- kernel 3: gather Wg_hi/lo[b][u][k] bf16, swizzled ----------------
// hi = bf16(W[k][lab]); lo = bf16(W - hi). Rows u>=65 zero.
__global__ __launch_bounds__(64) void k_gather2(const float* __restrict__ W,
                                                const int* __restrict__ ys,
                                                short* __restrict__ Wg_hi,
                                                short* __restrict__ Wg_lo) {
  int u = blockIdx.x, b = blockIdx.y, t = threadIdx.x;  // t = granule 0..63
  short8v hi = {0,0,0,0,0,0,0,0}, lo = {0,0,0,0,0,0,0,0};
  if (u < NU + 1) {
    int lab = (u == 0) ? 0 : ys[b * NU + u - 1];
#pragma unroll
    for (int i = 0; i < 8; ++i) {
      float w = W[(size_t)(t * 8 + i) * NV + lab];
      short h = f2bf(w);
      hi[i] = h;
      lo[i] = f2bf(w - bf2f(h));
    }
  }
  int gs = (t & ~7) | ((t & 7) ^ (u & 7));
  size_t base = ((size_t)(b * 128 + u)) * ND + gs * 8;
  *(short8v*)(Wg_hi + base) = hi;
  *(short8v*)(Wg_lo + base) = lo;
}

// -------- kernel 4: ll = hs @ Wg_b + bias (batched MFMA GEMM) --------------
// grid (8 mt, 16 b); 128x128 tile (24 tail rows masked), K=512, BK=64.
// acc = A_hi*B_hi + A_hi*B_lo  (W-rounding corrected; hs-rounding i.i.d.)
__global__ __launch_bounds__(256) void k_labg(const short* __restrict__ hsb,
                                              const short* __restrict__ Wg_hi,
                                              const short* __restrict__ Wg_lo,
                                              const int* __restrict__ ys,
                                              const float* __restrict__ bias,
                                              float* __restrict__ ll) {
  __shared__ short As[128 * 64];
  __shared__ short Bh[128 * 64];
  __shared__ short Bl[128 * 64];

  int mt = blockIdx.x, b = blockIdx.y;
  int t0 = mt * 128;
  int tid = threadIdx.x;
  int lane = tid & 63, wave = tid >> 6;
  int wm = wave >> 1, wn = wave & 1;
  int lrow = lane & 15, lkhi = lane >> 4;

  const short* gaBase = hsb + (size_t)(b * NT + t0 + wave * 32 + (lane >> 3)) * ND + (lane & 7) * 8;
  const short* ghBase = Wg_hi + (size_t)(b * 128 + wave * 32 + (lane >> 3)) * ND + (lane & 7) * 8;
  const short* glBase = Wg_lo + (size_t)(b * 128 + wave * 32 + (lane >> 3)) * ND + (lane & 7) * 8;

  float4v acc[4][4];
#pragma unroll
  for (int m = 0; m < 4; ++m)
#pragma unroll
    for (int n = 0; n < 4; ++n)
#pragma unroll
      for (int j = 0; j < 4; ++j) acc[m][n][j] = 0.f;

  for (int s = 0; s < 8; ++s) {
    int k0 = s * 64;
#pragma unroll
    for (int i = 0; i < 4; ++i) {
      g2lds16(gaBase + (size_t)(i * 8) * ND + k0, &As[(wave * 32 + i * 8) * 64]);
      g2lds16(ghBase + (size_t)(i * 8) * ND + k0, &Bh[(wave * 32 + i * 8) * 64]);
      g2lds16(glBase + (size_t)(i * 8) * ND + k0, &Bl[(wave * 32 + i * 8) * 64]);
    }
    __syncthreads();
#pragma unroll
    for (int kk = 0; kk < 2; ++kk) {
      short8v av[4], bhv[4], blv2[4];
#pragma unroll
      for (int m = 0; m < 4; ++m) {
        int r = wm * 64 + m * 16 + lrow;
        int col = (kk * 32 + lkhi * 8) ^ ((r & 7) << 3);
        av[m] = *(const short8v*)&As[r * 64 + col];
      }
#pragma unroll
      for (int n = 0; n < 4; ++n) {
        int r = wn * 64 + n * 16 + lrow;
        int col = (kk * 32 + lkhi * 8) ^ ((r & 7) << 3);
        bhv[n] = *(const short8v*)&Bh[r * 64 + col];
        blv2[n] = *(const short8v*)&Bl[r * 64 + col];
      }
#pragma unroll
      for (int m = 0; m < 4; ++m)
#pragma unroll
        for (int n = 0; n < 4; ++n) {
          acc[m][n] = __builtin_amdgcn_mfma_f32_16x16x32_bf16(av[m], bhv[n], acc[m][n], 0, 0, 0);
          acc[m][n] = __builtin_amdgcn_mfma_f32_16x16x32_bf16(av[m], blv2[n], acc[m][n], 0, 0, 0);
        }
    }
    __syncthreads();
  }

  // epilogue: bias per u-col, write valid (t<1000, u<65)
  float bu[4]; bool uval[4];
#pragma unroll
  for (int n = 0; n < 4; ++n) {
    int u = wn * 64 + n * 16 + lrow;
    uval[n] = u < NU + 1;
    int lab = (u == 0) ? 0 : (uval[n] ? ys[b * NU + u - 1] : 0);
    bu[n] = uval[n] ? bias[lab] : 0.f;
  }
#pragma unroll
  for (int m = 0; m < 4; ++m)
#pragma unroll
    for (int j = 0; j < 4; ++j) {
      int trow = t0 + wm * 64 + m * 16 + lkhi * 4 + j;
      if (trow < NT) {
#pragma unroll
        for (int n = 0; n < 4; ++n) {
          int u = wn * 64 + n * 16 + lrow;
          if (uval[n])
            ll[((size_t)(b * NT + trow)) * (NU + 1) + u] = acc[m][n][j] + bu[n];
        }
      }
    }
}

// -------- kernel 5: per-chunk partial logsumexp of hs@W + b (bf16 MFMA) ----
__global__ __launch_bounds__(256) void k_denom(const short* __restrict__ hsb,
                                               const short* __restrict__ WT,
                                               const float* __restrict__ bias,
                                               float* __restrict__ pm,
                                               float* __restrict__ ps) {
  __shared__ short As[128 * 64];
  __shared__ short Ws[128 * 64];
  __shared__ float mred[128][2];
  __shared__ float sred[128][2];

  int lin = blockIdx.x;                       // 5000 = 8 * 625
  int wg = (lin & 7) * 625 + (lin >> 3);      // XCD-contiguous
  int mt = wg / NCH, chunk = wg % NCH;        // m-major within XCD
  int t0 = mt * 128;
  int n0 = chunk * 128;
  int tid = threadIdx.x;
  int lane = tid & 63, wave = tid >> 6;
  int wm = wave >> 1, wn = wave & 1;
  int lrow = lane & 15, lkhi = lane >> 4;

  const short* gaBase = hsb + (size_t)(t0 + wave * 32 + (lane >> 3)) * ND + (lane & 7) * 8;
  const short* gwBase = WT + (size_t)(n0 + wave * 32 + (lane >> 3)) * ND + (lane & 7) * 8;

  float4v acc[4][4];
#pragma unroll
  for (int m = 0; m < 4; ++m)
#pragma unroll
    for (int n = 0; n < 4; ++n)
#pragma unroll
      for (int j = 0; j < 4; ++j) acc[m][n][j] = 0.f;

  auto stage = [&](int s) {
    int k0 = s * 64;
#pragma unroll
    for (int i = 0; i < 4; ++i) {
      g2lds16(gaBase + (size_t)(i * 8) * ND + k0, &As[(wave * 32 + i * 8) * 64]);
      g2lds16(gwBase + (size_t)(i * 8) * ND + k0, &Ws[(wave * 32 + i * 8) * 64]);
    }
  };
  auto compute = [&]() {
#pragma unroll
    for (int kk = 0; kk < 2; ++kk) {
      short8v av[4], wv[4];
#pragma unroll
      for (int m = 0; m < 4; ++m) {
        int r = wm * 64 + m * 16 + lrow;
        int col = (kk * 32 + lkhi * 8) ^ ((r & 7) << 3);
        av[m] = *(const short8v*)&As[r * 64 + col];
      }
#pragma unroll
      for (int n = 0; n < 4; ++n) {
        int r = wn * 64 + n * 16 + lrow;
        int col = (kk * 32 + lkhi * 8) ^ ((r & 7) << 3);
        wv[n] = *(const short8v*)&Ws[r * 64 + col];
      }
#pragma unroll
      for (int m = 0; m < 4; ++m)
#pragma unroll
        for (int n = 0; n < 4; ++n)
          acc[m][n] = __builtin_amdgcn_mfma_f32_16x16x32_bf16(av[m], wv[n], acc[m][n], 0, 0, 0);
    }
  };

  for (int s = 0; s < 8; ++s) {
    stage(s);
    __syncthreads();
    compute();
    __syncthreads();
  }

  float bcol[4]; bool cval[4];
#pragma unroll
  for (int n = 0; n < 4; ++n) {
    int c = n0 + wn * 64 + n * 16 + lrow;
    cval[n] = c < NV;
    bcol[n] = cval[n] ? bias[c] : 0.f;
  }
#pragma unroll
  for (int m = 0; m < 4; ++m)
#pragma unroll
    for (int j = 0; j < 4; ++j) {
      float mx = NEGINF;
#pragma unroll
      for (int n = 0; n < 4; ++n) {
        float v = cval[n] ? acc[m][n][j] + bcol[n] : NEGINF;
        mx = fmaxf(mx, v);
      }
#pragma unroll
      for (int d = 1; d < 16; d <<= 1) mx = fmaxf(mx, __shfl_xor(mx, d));
      float mxc = fmaxf(mx, -3.0e38f);   // NaN guard (all-invalid half-tile)
      float p = 0.f;
#pragma unroll
      for (int n = 0; n < 4; ++n) {
        float v = cval[n] ? acc[m][n][j] + bcol[n] : NEGINF;
        p += __expf(v - mxc);
      }
#pragma unroll
      for (int d = 1; d < 16; d <<= 1) p += __shfl_xor(p, d);
      if (lrow == 0) {
        int rloc = wm * 64 + m * 16 + lkhi * 4 + j;
        mred[rloc][wn] = mx;
        sred[rloc][wn] = p;
      }
    }
  __syncthreads();
  if (tid < 128) {
    int row = t0 + tid;
    float m0 = mred[tid][0], m1 = mred[tid][1];
    float m = fmaxf(m0, m1);
    float ss = 0.f;
    if (m != NEGINF)
      ss = ((m0 == NEGINF) ? 0.f : sred[tid][0] * __expf(m0 - m))
         + ((m1 == NEGINF) ? 0.f : sred[tid][1] * __expf(m1 - m));
    pm[(size_t)chunk * NM + row] = m;
    ps[(size_t)chunk * NM + row] = ss;
  }
}

// -------- kernel 5b: combine 40 chunk partials -> denom[row] ---------------
__global__ __launch_bounds__(256) void k_dred(const float* __restrict__ pm,
                                              const float* __restrict__ ps,
                                              float* __restrict__ denom) {
  int row = blockIdx.x * 256 + threadIdx.x;
  if (row >= NM) return;
  float m = NEGINF, s = 0.f;
  for (int c = 0; c < NCH; ++c) {
    float mc = pm[(size_t)c * NM + row];
    float sc = ps[(size_t)c * NM + row];
    if (mc == NEGINF) continue;
    if (mc > m) { s = s * __expf(m - mc) + sc; m = mc; }
    else        { s += sc * __expf(mc - m); }
  }
  denom[row] = m + __logf(s);
}

// -------- kernel 6: fwd (blocks 0..15) || bwd (blocks 16..31) --------------
// base-2, finite sentinels; den + blank-col staged in LDS.
__global__ __launch_bounds__(64) void k_fwdbwd(const float* __restrict__ ll,
                                               const float* __restrict__ denom,
                                               const int* __restrict__ ys,
                                               float* __restrict__ aod,
                                               float* __restrict__ bp) {
  __shared__ float denS[NT];
  __shared__ float blkS[NT];
  int bid = blockIdx.x;
  int l = threadIdx.x;
  int b = (bid < NB) ? bid : bid - NB;
  const float* llb = ll + (size_t)b * NT * (NU + 1);
  const float* denb = denom + b * NT;
#pragma unroll
  for (int i = 0; i < 16; ++i) {
    int idx = i * 64 + l;
    if (idx < NT) { denS[idx] = denb[idx]; blkS[idx] = llb[(size_t)idx * (NU + 1)]; }
  }
  __syncthreads();

  if (bid < NB) {
    // ---------------- forward ----------------
    int lab = ys[b * NU + l];
    int labp = ys[b * NU + ((l >= 1) ? (l - 1) : 0)];
    bool skip = (l >= 1) && (lab != labp);
    float* aodb = aod + (size_t)b * NT * NU;

    float den = denS[0];
    float ae = (l == 0) ? (blkS[0] - den) * LOG2E : SENTL;
    float ao = (l == 0) ? (llb[1] - den) * LOG2E : SENTL;
    aodb[l] = ao;

    float cl[16];
#pragma unroll
    for (int j = 0; j < 16; ++j) {
      int tt = 1 + j; if (tt > NT - 1) tt = NT - 1;
      cl[j] = llb[tt * (NU + 1) + 1 + l];
    }
    for (int g = 0; g < 63; ++g) {
      float nl[16];
      if (g < 62) {
#pragma unroll
        for (int j = 0; j < 16; ++j) {
          int tt = 17 + g * 16 + j; if (tt > NT - 1) tt = NT - 1;
          nl[j] = llb[tt * (NU + 1) + 1 + l];
        }
      } else {
#pragma unroll
        for (int j = 0; j < 16; ++j) nl[j] = 0.f;
      }
#pragma unroll
      for (int j = 0; j < 16; ++j) {
        int t = 1 + g * 16 + j;
        if (t < NT) {
          float d2 = denS[t];
          float pb = (blkS[t] - d2) * LOG2E, pl = (cl[j] - d2) * LOG2E;
          float po = dpp_shr1(ao); if (l == 0) po = SENTL;
          float aen = pb + lae2s(ae, po);
          float aon = pl + lae3s(ao, ae, skip ? po : SENTL);
          ae = aen; ao = aon;
          aodb[t * NU + l] = ao;
        }
      }
#pragma unroll
      for (int j = 0; j < 16; ++j) cl[j] = nl[j];
    }
  } else {
    // ---------------- backward ----------------
    int lab = ys[b * NU + l];
    int labn = ys[b * NU + ((l < NU - 1) ? (l + 1) : l)];
    bool skipn = (l < NU - 1) && (labn != lab);
    float* bpb = bp + (size_t)b * NT * NU;

    float bo = (l == NU - 1) ? 0.0f : SENTL;
    float be = SENTL;
    float b128 = 0.0f;
    bpb[(NT - 1) * NU + l] = bo;

    float blv[16];
#pragma unroll
    for (int j = 0; j < 16; ++j) {
      int tt = NT - 2 - j; if (tt < 0) tt = 0;
      blv[j] = llb[(tt + 1) * (NU + 1) + 1 + l];
    }
    for (int g = 0; g < 63; ++g) {
      float nl2[16];
      if (g < 62) {
#pragma unroll
        for (int j = 0; j < 16; ++j) {
          int tt = NT - 2 - 16 * (g + 1) - j; if (tt < 0) tt = 0;
          nl2[j] = llb[(tt + 1) * (NU + 1) + 1 + l];
        }
      } else {
#pragma unroll
        for (int j = 0; j < 16; ++j) nl2[j] = 0.f;
      }
#pragma unroll
      for (int j = 0; j < 16; ++j) {
        int t = NT - 2 - 16 * g - j;
        if (t >= 0) {
          float d2 = denS[t + 1];
          float pbv = (blkS[t + 1] - d2) * LOG2E, plv = (blv[j] - d2) * LOG2E;
          float me = pbv + be;
          float mo = plv + bo;
          float m128 = pbv + b128;
          float ne = dpp_shl1(me); if (l == NU - 1) ne = m128;
          float no = dpp_shl1(mo); if (l == NU - 1) no = SENTL;
          float ben = lae2s(me, mo);
          float bon = lae3s(mo, ne, skipn ? no : SENTL);
          bpb[t * NU + l] = lsub2(bon, mo);
          be = ben; bo = bon; b128 = m128;
        }
      }
#pragma unroll
      for (int j = 0; j < 16; ++j) blv[j] = nl2[j];
    }
  }
}

// -------- kernel 7: loss = mean_b( -sum_u lse_t(alpha+bp) / count ) --------
__global__ __launch_bounds__(256) void k_loss(const float* __restrict__ aod,
                                              const float* __restrict__ bp,
                                              const int* __restrict__ hlens,
                                              float* __restrict__ out) {
  __shared__ float ms[4][64], ss[4][64];
  int b = blockIdx.x, tid = threadIdx.x;
  int w = tid >> 6, l = tid & 63;
  const float* ab = aod + (size_t)b * NT * NU;
  const float* pb = bp + (size_t)b * NT * NU;
  float m = NEGINF, s = 0.f;
  int t0 = w * 250, t1 = t0 + 250;
  for (int t = t0; t < t1; ++t) {
    float x = ab[t * NU + l] + pb[t * NU + l];
    if (__builtin_isnan(x) || x < -1.0e29f) continue;   // sentinel == -inf
    if (x > m) { s = s * fexp2(m - x) + 1.0f; m = x; }
    else       { s += fexp2(x - m); }
  }
  ms[w][l] = m; ss[w][l] = s;
  __syncthreads();
  if (w == 0) {
    float m0 = ms[0][l], m1 = ms[1][l], m2 = ms[2][l], m3 = ms[3][l];
    float mm = fmaxf(fmaxf(m0, m1), fmaxf(m2, m3));
    float lu;
    if (mm == NEGINF) lu = NEGINF;
    else {
      float st = ((m0 == NEGINF) ? 0.f : ss[0][l] * fexp2(m0 - mm))
               + ((m1 == NEGINF) ? 0.f : ss[1][l] * fexp2(m1 - mm))
               + ((m2 == NEGINF) ? 0.f : ss[2][l] * fexp2(m2 - mm))
               + ((m3 == NEGINF) ? 0.f : ss[3][l] * fexp2(m3 - mm));
      lu = (mm + flog2(st)) * LN2F;
    }
    bool msk = __builtin_isinf(lu);
    float sv = msk ? 0.f : lu;
    float cv = msk ? 0.f : 1.f;
#pragma unroll
    for (int d = 1; d < 64; d <<= 1) { sv += __shfl_xor(sv, d); cv += __shfl_xor(cv, d); }
    if (l == 0) {
      float lf = sv / cv;
      if (hlens[b] < NU) lf = 0.f;
      atomicAdd(out, -lf * (1.0f / NB));
    }
  }
}

// ---------------------------------------------------------------------------
extern "C" void kernel_launch(void* const* d_in, const int* in_sizes, int n_in,
                              void* d_out, int out_size, void* d_ws, size_t ws_size,
                              hipStream_t stream) {
  const float* hs    = (const float*)d_in[0];
  const int*   hlens = (const int*)d_in[1];
  const int*   ys    = (const int*)d_in[2];
  const float* W     = (const float*)d_in[4];
  const float* bias  = (const float*)d_in[5];
  float* out = (float*)d_out;

  char* ws = (char*)d_ws;
  short* hsb   = (short*)(ws + 0);           // 16,384,000 B  [16000][512] bf16 (swizzled)
  short* WT    = (short*)(ws + 16384000);    //  5,242,880 B  [5120][512] bf16 (swizzled)
  float* pm    = (float*)(ws + 21626880);    //  2,560,000 B  [40][16000]
  float* psv   = (float*)(ws + 24186880);    //  2,560,000 B  [40][16000]
  short* Wg_hi = (short*)(ws + 26746880);    //  2,097,152 B  [16][128][512] bf16 (swizzled)
  short* Wg_lo = (short*)(ws + 28844032);    //  2,097,152 B
  float* ll    = (float*)(ws + 30941184);    //  4,160,000 B  [16][1000][65] f32
  float* dnm   = (float*)(ws + 35101184);    //     64,000 B  (end 35,165,184)
  // after k_labg: hsb dead -> reuse
  float* aod   = (float*)(ws + 0);           //  4,096,000 B
  float* bpb   = (float*)(ws + 4096000);     //  4,096,000 B

  k_zero<<<1, 64, 0, stream>>>(out);
  k_cvt_hs<<<4000, 256, 0, stream>>>(hs, hsb);
  k_cvt_wt<<<dim3(80, 8), 256, 0, stream>>>(W, WT);
  k_denom<<<5000, 256, 0, stream>>>(hsb, WT, bias, pm, psv);
  k_dred<<<63, 256, 0, stream>>>(pm, psv, dnm);
  k_gather2<<<dim3(128, 16), 64, 0, stream>>>(W, ys, Wg_hi, Wg_lo);
  k_labg<<<dim3(8, 16), 256, 0, stream>>>(hsb, Wg_hi, Wg_lo, ys, bias, ll);
  k_fwdbwd<<<32, 64, 0, stream>>>(ll, dnm, ys, aod, bpb);
  k_loss<<<16, 256, 0, stream>>>(aod, bpb, hlens, out);
}

// Round 8
// 374.120 us; speedup vs baseline: 2.9827x; 1.1056x over previous
//
#include <hip/hip_runtime.h>

// Problem constants (SpeakerAwareCTC): B=16, T=1000, D=512, V=5000, U=64, S=2U+1=129
#define NB 16
#define NT 1000
#define ND 512
#define NV 5000
#define NVP 5120          // WT padded rows (zeros beyond 5000)
#define NU 64
#define NM (NB * NT)      // 16000 flattened rows
#define NCH 40            // N-chunks of 128 cols

typedef short short8v __attribute__((ext_vector_type(8)));
typedef float float4v __attribute__((ext_vector_type(4)));

#define NEGINF (-__builtin_inff())
#define SENTL  (-1.0e30f)   // finite "-inf": exp2(SENTL - m) == 0 for any sane m
#define LOG2E 1.4426950408889634f
#define LN2F  0.6931471805599453f
// reference sentinel: -2001 + logf(expf(1)-1) = -2000.4586751f (natural), in base-2:
#define SENT2 (-2000.4586751f * LOG2E)

__device__ __forceinline__ float fexp2(float x) { return __builtin_amdgcn_exp2f(x); }
__device__ __forceinline__ float flog2(float x) { return __builtin_amdgcn_logf(x); }

// DPP lane shifts (VALU-latency; serial-chain friendly)
__device__ __forceinline__ float dpp_shr1(float x) {  // lane i <- lane i-1
  int xi = __builtin_bit_cast(int, x);
  int r = __builtin_amdgcn_update_dpp(xi, xi, 0x138, 0xf, 0xf, false);
  return __builtin_bit_cast(float, r);
}
__device__ __forceinline__ float dpp_shl1(float x) {  // lane i <- lane i+1
  int xi = __builtin_bit_cast(int, x);
  int r = __builtin_amdgcn_update_dpp(xi, xi, 0x130, 0xf, 0xf, false);
  return __builtin_bit_cast(float, r);
}

__device__ __forceinline__ short f2bf(float x) {
  unsigned int u = __builtin_bit_cast(unsigned int, x);
  unsigned int r = (u + 0x7fffu + ((u >> 16) & 1u)) >> 16;
  return (short)(unsigned short)r;
}
__device__ __forceinline__ float bf2f(short h) {
  unsigned int u = ((unsigned int)(unsigned short)h) << 16;
  return __builtin_bit_cast(float, u);
}

// async global->LDS, 16B per lane; LDS dest = wave-uniform base + lane*16
__device__ __forceinline__ void g2lds16(const short* g, short* l) {
  __builtin_amdgcn_global_load_lds(
      (const __attribute__((address_space(1))) void*)g,
      (__attribute__((address_space(3))) void*)l, 16, 0, 0);
}

// base-2 logaddexp on sentinel-finite values
__device__ __forceinline__ float lae2s(float a, float b) {
  float m = fmaxf(a, b);
  return m + flog2(fexp2(a - m) + fexp2(b - m));
}
__device__ __forceinline__ float lae3s(float a, float b, float c) {
  float m = fmaxf(fmaxf(a, b), c);
  return m + flog2(fexp2(a - m) + fexp2(b - m) + fexp2(c - m));
}
// base-2 port of reference log_substraction_exp (finite-sentinel inputs)
__device__ __forceinline__ float lsub2(float a, float b) {
  float tmp = b + flog2(fexp2(a - b) - 1.0f);
  if (__builtin_isinf(tmp)) tmp = SENT2;
  return tmp;
}

// ---------------- kernel 0: zero the scalar output -------------------------
__global__ void k_zero(float* out) {
  if (threadIdx.x == 0) out[0] = 0.0f;
}

// ---------------- kernel 1: hs f32 -> bf16, granule-swizzled ---------------
__global__ __launch_bounds__(256) void k_cvt_hs(const float* __restrict__ in,
                                                short* __restrict__ out) {
  size_t i = (size_t)blockIdx.x * 256 + threadIdx.x;  // granule id, 1,024,000 total
  const float4* p = (const float4*)in + i * 2;
  float4 v0 = p[0], v1 = p[1];
  short8v r;
  r[0] = f2bf(v0.x); r[1] = f2bf(v0.y); r[2] = f2bf(v0.z); r[3] = f2bf(v0.w);
  r[4] = f2bf(v1.x); r[5] = f2bf(v1.y); r[6] = f2bf(v1.z); r[7] = f2bf(v1.w);
  int row = (int)(i >> 6);        // 64 granules per 512-col row
  int g = (int)(i & 63);
  int gs = (g & ~7) | ((g & 7) ^ (row & 7));
  *(short8v*)(out + (size_t)row * ND + gs * 8) = r;
}

// ------------- kernel 2: W [512][5000] f32 -> WT [5120][512] bf16 ----------
__global__ __launch_bounds__(256) void k_cvt_wt(const float* __restrict__ W,
                                                short* __restrict__ WT) {
  __shared__ short tile[64 * 72];
  int n0 = blockIdx.x * 64, k0 = blockIdx.y * 64;
  int tid = threadIdx.x;
  int kr = tid >> 2, part = tid & 3;
  const float* src = W + (size_t)(k0 + kr) * NV + n0 + part * 16;
#pragma unroll
  for (int jj = 0; jj < 4; ++jj) {
    int c = n0 + part * 16 + jj * 4;
    float4 v;
    if (c + 3 < NV) {
      v = *(const float4*)(src + jj * 4);
    } else {
      v.x = (c + 0 < NV) ? src[jj * 4 + 0] : 0.f;
      v.y = (c + 1 < NV) ? src[jj * 4 + 1] : 0.f;
      v.z = (c + 2 < NV) ? src[jj * 4 + 2] : 0.f;
      v.w = (c + 3 < NV) ? src[jj * 4 + 3] : 0.f;
    }
    int base = kr * 72 + part * 16 + jj * 4;
    tile[base + 0] = f2bf(v.x); tile[base + 1] = f2bf(v.y);
    tile[base + 2] = f2bf(v.z); tile[base + 3] = f2bf(v.w);
  }
  __syncthreads();
  int n = tid & 63, kq = tid >> 6;
  int nn = n0 + n;
  if (nn < NVP) {
#pragma unroll
    for (int half = 0; half < 2; ++half) {
      short8v val;
#pragma unroll
      for (int jj = 0; jj < 8; ++jj) val[jj] = tile[(kq * 16 + half * 8 + jj) * 72 + n];
      int g = (k0 >> 3) + kq * 2 + half;
      int gs = (g & ~7) | ((g & 7) ^ (nn & 7));
      *(short8v*)(WT + (size_t)nn * ND + gs * 8) = val;
    }
  }
}

// -------- kernel 3: gather Wg_hi/lo[b][u][k] bf16, swizzled ----------------
__global__ __launch_bounds__(64) void k_gather2(const float* __restrict__ W,
                                                const int* __restrict__ ys,
                                                short* __restrict__ Wg_hi,
                                                short* __restrict__ Wg_lo) {
  int u = blockIdx.x, b = blockIdx.y, t = threadIdx.x;  // t = granule 0..63
  short8v hi = {0,0,0,0,0,0,0,0}, lo = {0,0,0,0,0,0,0,0};
  if (u < NU + 1) {
    int lab = (u == 0) ? 0 : ys[b * NU + u - 1];
#pragma unroll
    for (int i = 0; i < 8; ++i) {
      float w = W[(size_t)(t * 8 + i) * NV + lab];
      short h = f2bf(w);
      hi[i] = h;
      lo[i] = f2bf(w - bf2f(h));
    }
  }
  int gs = (t & ~7) | ((t & 7) ^ (u & 7));
  size_t base = ((size_t)(b * 128 + u)) * ND + gs * 8;
  *(short8v*)(Wg_hi + base) = hi;
  *(short8v*)(Wg_lo + base) = lo;
}

// -------- kernel 4: ll[b][u][t] = hs[b,t,:] . W[:,lab(u)] + bias -----------
// batched MFMA GEMM, TRANSPOSED output (u-major rows for the trellis).
__global__ __launch_bounds__(256) void k_labg(const short* __restrict__ hsb,
                                              const short* __restrict__ Wg_hi,
                                              const short* __restrict__ Wg_lo,
                                              const int* __restrict__ ys,
                                              const float* __restrict__ bias,
                                              float* __restrict__ ll) {
  __shared__ short As[128 * 64];
  __shared__ short Bh[128 * 64];
  __shared__ short Bl[128 * 64];

  int mt = blockIdx.x, b = blockIdx.y;
  int t0 = mt * 128;
  int tid = threadIdx.x;
  int lane = tid & 63, wave = tid >> 6;
  int wm = wave >> 1, wn = wave & 1;
  int lrow = lane & 15, lkhi = lane >> 4;

  const short* gaBase = hsb + (size_t)(b * NT + t0 + wave * 32 + (lane >> 3)) * ND + (lane & 7) * 8;
  const short* ghBase = Wg_hi + (size_t)(b * 128 + wave * 32 + (lane >> 3)) * ND + (lane & 7) * 8;
  const short* glBase = Wg_lo + (size_t)(b * 128 + wave * 32 + (lane >> 3)) * ND + (lane & 7) * 8;

  float4v acc[4][4];
#pragma unroll
  for (int m = 0; m < 4; ++m)
#pragma unroll
    for (int n = 0; n < 4; ++n)
#pragma unroll
      for (int j = 0; j < 4; ++j) acc[m][n][j] = 0.f;

  for (int s = 0; s < 8; ++s) {
    int k0 = s * 64;
#pragma unroll
    for (int i = 0; i < 4; ++i) {
      g2lds16(gaBase + (size_t)(i * 8) * ND + k0, &As[(wave * 32 + i * 8) * 64]);
      g2lds16(ghBase + (size_t)(i * 8) * ND + k0, &Bh[(wave * 32 + i * 8) * 64]);
      g2lds16(glBase + (size_t)(i * 8) * ND + k0, &Bl[(wave * 32 + i * 8) * 64]);
    }
    __syncthreads();
#pragma unroll
    for (int kk = 0; kk < 2; ++kk) {
      short8v av[4], bhv[4], blv2[4];
#pragma unroll
      for (int m = 0; m < 4; ++m) {
        int r = wm * 64 + m * 16 + lrow;
        int col = (kk * 32 + lkhi * 8) ^ ((r & 7) << 3);
        av[m] = *(const short8v*)&As[r * 64 + col];
      }
#pragma unroll
      for (int n = 0; n < 4; ++n) {
        int r = wn * 64 + n * 16 + lrow;
        int col = (kk * 32 + lkhi * 8) ^ ((r & 7) << 3);
        bhv[n] = *(const short8v*)&Bh[r * 64 + col];
        blv2[n] = *(const short8v*)&Bl[r * 64 + col];
      }
#pragma unroll
      for (int m = 0; m < 4; ++m)
#pragma unroll
        for (int n = 0; n < 4; ++n) {
          acc[m][n] = __builtin_amdgcn_mfma_f32_16x16x32_bf16(av[m], bhv[n], acc[m][n], 0, 0, 0);
          acc[m][n] = __builtin_amdgcn_mfma_f32_16x16x32_bf16(av[m], blv2[n], acc[m][n], 0, 0, 0);
        }
    }
    __syncthreads();
  }

  // epilogue: bias per u-row; TRANSPOSED write ll[(b*128+u)*NT + t]
  float bu[4]; bool uval[4];
#pragma unroll
  for (int n = 0; n < 4; ++n) {
    int u = wn * 64 + n * 16 + lrow;
    uval[n] = u < NU + 1;
    int lab = (u == 0) ? 0 : (uval[n] ? ys[b * NU + u - 1] : 0);
    bu[n] = uval[n] ? bias[lab] : 0.f;
  }
#pragma unroll
  for (int m = 0; m < 4; ++m)
#pragma unroll
    for (int j = 0; j < 4; ++j) {
      int trow = t0 + wm * 64 + m * 16 + lkhi * 4 + j;
      if (trow < NT) {
#pragma unroll
        for (int n = 0; n < 4; ++n) {
          int u = wn * 64 + n * 16 + lrow;
          if (uval[n])
            ll[((size_t)(b * 128 + u)) * NT + trow] = acc[m][n][j] + bu[n];
        }
      }
    }
}

// -------- kernel 5: per-chunk partial logsumexp of hs@W + b (bf16 MFMA) ----
__global__ __launch_bounds__(256) void k_denom(const short* __restrict__ hsb,
                                               const short* __restrict__ WT,
                                               const float* __restrict__ bias,
                                               float* __restrict__ pm,
                                               float* __restrict__ ps) {
  __shared__ short As[128 * 64];
  __shared__ short Ws[128 * 64];
  __shared__ float mred[128][2];
  __shared__ float sred[128][2];

  int lin = blockIdx.x;                       // 5000 = 8 * 625
  int wg = (lin & 7) * 625 + (lin >> 3);      // XCD-contiguous
  int mt = wg / NCH, chunk = wg % NCH;        // m-major within XCD
  int t0 = mt * 128;
  int n0 = chunk * 128;
  int tid = threadIdx.x;
  int lane = tid & 63, wave = tid >> 6;
  int wm = wave >> 1, wn = wave & 1;
  int lrow = lane & 15, lkhi = lane >> 4;

  const short* gaBase = hsb + (size_t)(t0 + wave * 32 + (lane >> 3)) * ND + (lane & 7) * 8;
  const short* gwBase = WT + (size_t)(n0 + wave * 32 + (lane >> 3)) * ND + (lane & 7) * 8;

  float4v acc[4][4];
#pragma unroll
  for (int m = 0; m < 4; ++m)
#pragma unroll
    for (int n = 0; n < 4; ++n)
#pragma unroll
      for (int j = 0; j < 4; ++j) acc[m][n][j] = 0.f;

  auto stage = [&](int s) {
    int k0 = s * 64;
#pragma unroll
    for (int i = 0; i < 4; ++i) {
      g2lds16(gaBase + (size_t)(i * 8) * ND + k0, &As[(wave * 32 + i * 8) * 64]);
      g2lds16(gwBase + (size_t)(i * 8) * ND + k0, &Ws[(wave * 32 + i * 8) * 64]);
    }
  };
  auto compute = [&]() {
#pragma unroll
    for (int kk = 0; kk < 2; ++kk) {
      short8v av[4], wv[4];
#pragma unroll
      for (int m = 0; m < 4; ++m) {
        int r = wm * 64 + m * 16 + lrow;
        int col = (kk * 32 + lkhi * 8) ^ ((r & 7) << 3);
        av[m] = *(const short8v*)&As[r * 64 + col];
      }
#pragma unroll
      for (int n = 0; n < 4; ++n) {
        int r = wn * 64 + n * 16 + lrow;
        int col = (kk * 32 + lkhi * 8) ^ ((r & 7) << 3);
        wv[n] = *(const short8v*)&Ws[r * 64 + col];
      }
#pragma unroll
      for (int m = 0; m < 4; ++m)
#pragma unroll
        for (int n = 0; n < 4; ++n)
          acc[m][n] = __builtin_amdgcn_mfma_f32_16x16x32_bf16(av[m], wv[n], acc[m][n], 0, 0, 0);
    }
  };

  for (int s = 0; s < 8; ++s) {
    stage(s);
    __syncthreads();
    compute();
    __syncthreads();
  }

  float bcol[4]; bool cval[4];
#pragma unroll
  for (int n = 0; n < 4; ++n) {
    int c = n0 + wn * 64 + n * 16 + lrow;
    cval[n] = c < NV;
    bcol[n] = cval[n] ? bias[c] : 0.f;
  }
#pragma unroll
  for (int m = 0; m < 4; ++m)
#pragma unroll
    for (int j = 0; j < 4; ++j) {
      float mx = NEGINF;
#pragma unroll
      for (int n = 0; n < 4; ++n) {
        float v = cval[n] ? acc[m][n][j] + bcol[n] : NEGINF;
        mx = fmaxf(mx, v);
      }
#pragma unroll
      for (int d = 1; d < 16; d <<= 1) mx = fmaxf(mx, __shfl_xor(mx, d));
      float mxc = fmaxf(mx, -3.0e38f);   // NaN guard (all-invalid half-tile)
      float p = 0.f;
#pragma unroll
      for (int n = 0; n < 4; ++n) {
        float v = cval[n] ? acc[m][n][j] + bcol[n] : NEGINF;
        p += __expf(v - mxc);
      }
#pragma unroll
      for (int d = 1; d < 16; d <<= 1) p += __shfl_xor(p, d);
      if (lrow == 0) {
        int rloc = wm * 64 + m * 16 + lkhi * 4 + j;
        mred[rloc][wn] = mx;
        sred[rloc][wn] = p;
      }
    }
  __syncthreads();
  if (tid < 128) {
    int row = t0 + tid;
    float m0 = mred[tid][0], m1 = mred[tid][1];
    float m = fmaxf(m0, m1);
    float ss = 0.f;
    if (m != NEGINF)
      ss = ((m0 == NEGINF) ? 0.f : sred[tid][0] * __expf(m0 - m))
         + ((m1 == NEGINF) ? 0.f : sred[tid][1] * __expf(m1 - m));
    pm[(size_t)chunk * NM + row] = m;
    ps[(size_t)chunk * NM + row] = ss;
  }
}

// -------- kernel 5b: combine 40 chunk partials -> denom[row] ---------------
__global__ __launch_bounds__(256) void k_dred(const float* __restrict__ pm,
                                              const float* __restrict__ ps,
                                              float* __restrict__ denom) {
  int row = blockIdx.x * 256 + threadIdx.x;
  if (row >= NM) return;
  float m = NEGINF, s = 0.f;
  for (int c = 0; c < NCH; ++c) {
    float mc = pm[(size_t)c * NM + row];
    float sc = ps[(size_t)c * NM + row];
    if (mc == NEGINF) continue;
    if (mc > m) { s = s * __expf(m - mc) + sc; m = mc; }
    else        { s += sc * __expf(mc - m); }
  }
  denom[row] = m + __logf(s);
}

// -------- kernel 6: fwd (blocks 0..15) || bwd (blocks 16..31) --------------
// ll is [b][u][t] u-major: lane l reads its own contiguous t-row.
__global__ __launch_bounds__(64) void k_fwdbwd(const float* __restrict__ ll,
                                               const float* __restrict__ denom,
                                               const int* __restrict__ ys,
                                               float* __restrict__ aod,
                                               float* __restrict__ bp) {
  __shared__ float denS[NT];
  __shared__ float blkS[NT];
  int bid = blockIdx.x;
  int l = threadIdx.x;
  int b = (bid < NB) ? bid : bid - NB;
  const float* llb = ll + (size_t)b * 128 * NT;
  const float* denb = denom + b * NT;
#pragma unroll
  for (int i = 0; i < 16; ++i) {
    int idx = i * 64 + l;
    if (idx < NT) { denS[idx] = denb[idx]; blkS[idx] = llb[idx]; }  // row 0 = blank
  }
  __syncthreads();
  const float* lrow = llb + (size_t)(1 + l) * NT;   // this lane's label row

  if (bid < NB) {
    // ---------------- forward ----------------
    int lab = ys[b * NU + l];
    int labp = ys[b * NU + ((l >= 1) ? (l - 1) : 0)];
    bool skip = (l >= 1) && (lab != labp);
    float* aodb = aod + (size_t)b * NT * NU;

    float den = denS[0];
    float ae = (l == 0) ? (blkS[0] - den) * LOG2E : SENTL;
    float ao = (l == 0) ? (lrow[0] - den) * LOG2E : SENTL;
    aodb[l] = ao;

    float cl[16];
#pragma unroll
    for (int j = 0; j < 16; ++j) {
      int tt = 1 + j; if (tt > NT - 1) tt = NT - 1;
      cl[j] = lrow[tt];
    }
    for (int g = 0; g < 63; ++g) {
      float nl[16];
      if (g < 62) {
#pragma unroll
        for (int j = 0; j < 16; ++j) {
          int tt = 17 + g * 16 + j; if (tt > NT - 1) tt = NT - 1;
          nl[j] = lrow[tt];
        }
      } else {
#pragma unroll
        for (int j = 0; j < 16; ++j) nl[j] = 0.f;
      }
#pragma unroll
      for (int j = 0; j < 16; ++j) {
        int t = 1 + g * 16 + j;
        if (t < NT) {
          float d2 = denS[t];
          float pb = (blkS[t] - d2) * LOG2E, pl = (cl[j] - d2) * LOG2E;
          float po = dpp_shr1(ao); if (l == 0) po = SENTL;
          float aen = pb + lae2s(ae, po);
          float aon = pl + lae3s(ao, ae, skip ? po : SENTL);
          ae = aen; ao = aon;
          aodb[t * NU + l] = ao;
        }
      }
#pragma unroll
      for (int j = 0; j < 16; ++j) cl[j] = nl[j];
    }
  } else {
    // ---------------- backward ----------------
    int lab = ys[b * NU + l];
    int labn = ys[b * NU + ((l < NU - 1) ? (l + 1) : l)];
    bool skipn = (l < NU - 1) && (labn != lab);
    float* bpb = bp + (size_t)b * NT * NU;

    float bo = (l == NU - 1) ? 0.0f : SENTL;
    float be = SENTL;
    float b128 = 0.0f;
    bpb[(NT - 1) * NU + l] = bo;

    float blv[16];
#pragma unroll
    for (int j = 0; j < 16; ++j) {
      int tt = NT - 2 - j; if (tt < 0) tt = 0;
      blv[j] = lrow[tt + 1];
    }
    for (int g = 0; g < 63; ++g) {
      float nl2[16];
      if (g < 62) {
#pragma unroll
        for (int j = 0; j < 16; ++j) {
          int tt = NT - 2 - 16 * (g + 1) - j; if (tt < 0) tt = 0;
          nl2[j] = lrow[tt + 1];
        }
      } else {
#pragma unroll
        for (int j = 0; j < 16; ++j) nl2[j] = 0.f;
      }
#pragma unroll
      for (int j = 0; j < 16; ++j) {
        int t = NT - 2 - 16 * g - j;
        if (t >= 0) {
          float d2 = denS[t + 1];
          float pbv = (blkS[t + 1] - d2) * LOG2E, plv = (blv[j] - d2) * LOG2E;
          float me = pbv + be;
          float mo = plv + bo;
          float m128 = pbv + b128;
          float ne = dpp_shl1(me); if (l == NU - 1) ne = m128;
          float no = dpp_shl1(mo); if (l == NU - 1) no = SENTL;
          float ben = lae2s(me, mo);
          float bon = lae3s(mo, ne, skipn ? no : SENTL);
          bpb[t * NU + l] = lsub2(bon, mo);
          be = ben; bo = bon; b128 = m128;
        }
      }
#pragma unroll
      for (int j = 0; j < 16; ++j) blv[j] = nl2[j];
    }
  }
}

// -------- kernel 7: loss = mean_b( -sum_u lse_t(alpha+bp) / count ) --------
__global__ __launch_bounds__(512) void k_loss(const float* __restrict__ aod,
                                              const float* __restrict__ bp,
                                              const int* __restrict__ hlens,
                                              float* __restrict__ out) {
  __shared__ float ms[8][64], ss[8][64];
  int b = blockIdx.x, tid = threadIdx.x;
  int w = tid >> 6, l = tid & 63;
  const float* ab = aod + (size_t)b * NT * NU;
  const float* pb = bp + (size_t)b * NT * NU;
  float m = NEGINF, s = 0.f;
  int t0 = w * 125, t1 = t0 + 125;
  for (int t = t0; t < t1; ++t) {
    float x = ab[t * NU + l] + pb[t * NU + l];
    if (__builtin_isnan(x) || x < -1.0e29f) continue;   // sentinel == -inf
    if (x > m) { s = s * fexp2(m - x) + 1.0f; m = x; }
    else       { s += fexp2(x - m); }
  }
  ms[w][l] = m; ss[w][l] = s;
  __syncthreads();
  if (w == 0) {
    float mm = NEGINF;
#pragma unroll
    for (int i = 0; i < 8; ++i) mm = fmaxf(mm, ms[i][l]);
    float lu;
    if (mm == NEGINF) lu = NEGINF;
    else {
      float st = 0.f;
#pragma unroll
      for (int i = 0; i < 8; ++i)
        st += (ms[i][l] == NEGINF) ? 0.f : ss[i][l] * fexp2(ms[i][l] - mm);
      lu = (mm + flog2(st)) * LN2F;
    }
    bool msk = __builtin_isinf(lu);
    float sv = msk ? 0.f : lu;
    float cv = msk ? 0.f : 1.f;
#pragma unroll
    for (int d = 1; d < 64; d <<= 1) { sv += __shfl_xor(sv, d); cv += __shfl_xor(cv, d); }
    if (l == 0) {
      float lf = sv / cv;
      if (hlens[b] < NU) lf = 0.f;
      atomicAdd(out, -lf * (1.0f / NB));
    }
  }
}

// ---------------------------------------------------------------------------
extern "C" void kernel_launch(void* const* d_in, const int* in_sizes, int n_in,
                              void* d_out, int out_size, void* d_ws, size_t ws_size,
                              hipStream_t stream) {
  const float* hs    = (const float*)d_in[0];
  const int*   hlens = (const int*)d_in[1];
  const int*   ys    = (const int*)d_in[2];
  const float* W     = (const float*)d_in[4];
  const float* bias  = (const float*)d_in[5];
  float* out = (float*)d_out;

  char* ws = (char*)d_ws;
  short* hsb   = (short*)(ws + 0);           // 16,384,000 B  [16000][512] bf16 (swizzled)
  short* WT    = (short*)(ws + 16384000);    //  5,242,880 B  [5120][512] bf16 (swizzled); dead after k_denom
  float* pm    = (float*)(ws + 21626880);    //  2,560,000 B  [40][16000]; dead after k_dred
  float* psv   = (float*)(ws + 24186880);    //  2,560,000 B
  float* dnm   = (float*)(ws + 26746880);    //     64,000 B
  float* ll    = (float*)(ws + 26810880);    //  8,192,000 B  [16][128][1000] f32 u-major (end 35,002,880)
  // after k_denom: WT region dead -> Wg_hi/lo alias it
  short* Wg_hi = (short*)(ws + 16384000);    //  2,097,152 B  [16][128][512] bf16 (swizzled)
  short* Wg_lo = (short*)(ws + 18481152);    //  2,097,152 B
  // after k_labg: hsb dead -> aod/bp alias it
  float* aod   = (float*)(ws + 0);           //  4,096,000 B
  float* bpb   = (float*)(ws + 4096000);     //  4,096,000 B

  k_zero<<<1, 64, 0, stream>>>(out);
  k_cvt_hs<<<4000, 256, 0, stream>>>(hs, hsb);
  k_cvt_wt<<<dim3(80, 8), 256, 0, stream>>>(W, WT);
  k_denom<<<5000, 256, 0, stream>>>(hsb, WT, bias, pm, psv);
  k_dred<<<63, 256, 0, stream>>>(pm, psv, dnm);
  k_gather2<<<dim3(128, 16), 64, 0, stream>>>(W, ys, Wg_hi, Wg_lo);
  k_labg<<<dim3(8, 16), 256, 0, stream>>>(hsb, Wg_hi, Wg_lo, ys, bias, ll);
  k_fwdbwd<<<32, 64, 0, stream>>>(ll, dnm, ys, aod, bpb);
  k_loss<<<16, 512, 0, stream>>>(aod, bpb, hlens, out);
}

// Round 9
// 365.598 us; speedup vs baseline: 3.0522x; 1.0233x over previous
//
#include <hip/hip_runtime.h>

// Problem constants (SpeakerAwareCTC): B=16, T=1000, D=512, V=5000, U=64, S=2U+1=129
#define NB 16
#define NT 1000
#define ND 512
#define NV 5000
#define NVP 5120          // WT padded rows (zeros beyond 5000)
#define NU 64
#define NLL 72            // ll row stride (u-major rows, 65 used)
#define NM (NB * NT)      // 16000 flattened rows
#define NCH 40            // N-chunks of 128 cols

typedef short short8v __attribute__((ext_vector_type(8)));
typedef float float4v __attribute__((ext_vector_type(4)));

#define NEGINF (-__builtin_inff())
#define SENTL  (-1.0e30f)   // finite "-inf": exp2(SENTL - m) == 0 for any sane m
#define LOG2E 1.4426950408889634f
#define LN2F  0.6931471805599453f
// reference sentinel: -2001 + logf(expf(1)-1) = -2000.4586751f (natural), in base-2:
#define SENT2 (-2000.4586751f * LOG2E)

__device__ __forceinline__ float fexp2(float x) { return __builtin_amdgcn_exp2f(x); }
__device__ __forceinline__ float flog2(float x) { return __builtin_amdgcn_logf(x); }

// DPP lane shifts (VALU-latency; serial-chain friendly)
__device__ __forceinline__ float dpp_shr1(float x) {  // lane i <- lane i-1
  int xi = __builtin_bit_cast(int, x);
  int r = __builtin_amdgcn_update_dpp(xi, xi, 0x138, 0xf, 0xf, false);
  return __builtin_bit_cast(float, r);
}
__device__ __forceinline__ float dpp_shl1(float x) {  // lane i <- lane i+1
  int xi = __builtin_bit_cast(int, x);
  int r = __builtin_amdgcn_update_dpp(xi, xi, 0x130, 0xf, 0xf, false);
  return __builtin_bit_cast(float, r);
}

__device__ __forceinline__ short f2bf(float x) {
  unsigned int u = __builtin_bit_cast(unsigned int, x);
  unsigned int r = (u + 0x7fffu + ((u >> 16) & 1u)) >> 16;
  return (short)(unsigned short)r;
}
__device__ __forceinline__ float bf2f(short h) {
  unsigned int u = ((unsigned int)(unsigned short)h) << 16;
  return __builtin_bit_cast(float, u);
}

// async global->LDS, 16B per lane; LDS dest = wave-uniform base + lane*16
__device__ __forceinline__ void g2lds16(const short* g, short* l) {
  __builtin_amdgcn_global_load_lds(
      (const __attribute__((address_space(1))) void*)g,
      (__attribute__((address_space(3))) void*)l, 16, 0, 0);
}

// base-2 logaddexp on sentinel-finite values
__device__ __forceinline__ float lae2s(float a, float b) {
  float m = fmaxf(a, b);
  return m + flog2(fexp2(a - m) + fexp2(b - m));
}
__device__ __forceinline__ float lae3s(float a, float b, float c) {
  float m = fmaxf(fmaxf(a, b), c);
  return m + flog2(fexp2(a - m) + fexp2(b - m) + fexp2(c - m));
}
// base-2 port of reference log_substraction_exp (finite-sentinel inputs)
__device__ __forceinline__ float lsub2(float a, float b) {
  float tmp = b + flog2(fexp2(a - b) - 1.0f);
  if (__builtin_isinf(tmp)) tmp = SENT2;
  return tmp;
}

// ---------------- kernel 0: zero the scalar output -------------------------
__global__ void k_zero(float* out) {
  if (threadIdx.x == 0) out[0] = 0.0f;
}

// ---------------- kernel 1: hs f32 -> bf16, granule-swizzled ---------------
__global__ __launch_bounds__(256) void k_cvt_hs(const float* __restrict__ in,
                                                short* __restrict__ out) {
  size_t i = (size_t)blockIdx.x * 256 + threadIdx.x;  // granule id, 1,024,000 total
  const float4* p = (const float4*)in + i * 2;
  float4 v0 = p[0], v1 = p[1];
  short8v r;
  r[0] = f2bf(v0.x); r[1] = f2bf(v0.y); r[2] = f2bf(v0.z); r[3] = f2bf(v0.w);
  r[4] = f2bf(v1.x); r[5] = f2bf(v1.y); r[6] = f2bf(v1.z); r[7] = f2bf(v1.w);
  int row = (int)(i >> 6);        // 64 granules per 512-col row
  int g = (int)(i & 63);
  int gs = (g & ~7) | ((g & 7) ^ (row & 7));
  *(short8v*)(out + (size_t)row * ND + gs * 8) = r;
}

// ------- kernel 2: W [512][5000] f32 -> WT/WTlo [5120][512] bf16 -----------
// transposed, granule-swizzled rows; hi = bf16(w), lo = bf16(w - hi).
__global__ __launch_bounds__(256) void k_cvt_wt(const float* __restrict__ W,
                                                short* __restrict__ WT,
                                                short* __restrict__ WTlo) {
  __shared__ short tileH[64 * 72];
  __shared__ short tileL[64 * 72];
  int n0 = blockIdx.x * 64, k0 = blockIdx.y * 64;
  int tid = threadIdx.x;
  int kr = tid >> 2, part = tid & 3;
  const float* src = W + (size_t)(k0 + kr) * NV + n0 + part * 16;
#pragma unroll
  for (int jj = 0; jj < 4; ++jj) {
    int c = n0 + part * 16 + jj * 4;
    float4 v;
    if (c + 3 < NV) {
      v = *(const float4*)(src + jj * 4);
    } else {
      v.x = (c + 0 < NV) ? src[jj * 4 + 0] : 0.f;
      v.y = (c + 1 < NV) ? src[jj * 4 + 1] : 0.f;
      v.z = (c + 2 < NV) ? src[jj * 4 + 2] : 0.f;
      v.w = (c + 3 < NV) ? src[jj * 4 + 3] : 0.f;
    }
    int base = kr * 72 + part * 16 + jj * 4;
    float vv[4] = {v.x, v.y, v.z, v.w};
#pragma unroll
    for (int q = 0; q < 4; ++q) {
      short h = f2bf(vv[q]);
      tileH[base + q] = h;
      tileL[base + q] = f2bf(vv[q] - bf2f(h));
    }
  }
  __syncthreads();
  int n = tid & 63, kq = tid >> 6;
  int nn = n0 + n;
  if (nn < NVP) {
#pragma unroll
    for (int half = 0; half < 2; ++half) {
      short8v vh, vl;
#pragma unroll
      for (int jj = 0; jj < 8; ++jj) {
        vh[jj] = tileH[(kq * 16 + half * 8 + jj) * 72 + n];
        vl[jj] = tileL[(kq * 16 + half * 8 + jj) * 72 + n];
      }
      int g = (k0 >> 3) + kq * 2 + half;
      int gs = (g & ~7) | ((g & 7) ^ (nn & 7));
      *(short8v*)(WT + (size_t)nn * ND + gs * 8) = vh;
      *(short8v*)(WTlo + (size_t)nn * ND + gs * 8) = vl;
    }
  }
}

// -------- kernel 3: gather Wg_hi/lo[b][u][k] from WT/WTlo rows (coalesced) -
// re-swizzle: row lab uses XOR (lab&7); dest row u uses XOR (u&7).
__global__ __launch_bounds__(64) void k_gather2(const short* __restrict__ WT,
                                                const short* __restrict__ WTlo,
                                                const int* __restrict__ ys,
                                                short* __restrict__ Wg_hi,
                                                short* __restrict__ Wg_lo) {
  int u = blockIdx.x, b = blockIdx.y, t = threadIdx.x;  // t = logical granule
  short8v hi = {0,0,0,0,0,0,0,0}, lo = {0,0,0,0,0,0,0,0};
  if (u < NU + 1) {
    int lab = (u == 0) ? 0 : ys[b * NU + u - 1];
    int ps = (t & ~7) | ((t & 7) ^ (lab & 7));
    hi = *(const short8v*)(WT + (size_t)lab * ND + ps * 8);
    lo = *(const short8v*)(WTlo + (size_t)lab * ND + ps * 8);
  }
  int q = (t & ~7) | ((t & 7) ^ (u & 7));
  size_t base = ((size_t)(b * 128 + u)) * ND + q * 8;
  *(short8v*)(Wg_hi + base) = hi;
  *(short8v*)(Wg_lo + base) = lo;
}

// -------- kernel 4: ll[b][u][t] = hs[b,t,:] . W[:,lab(u)] + bias -----------
// batched MFMA GEMM, TRANSPOSED output (u-major rows, stride NLL).
__global__ __launch_bounds__(256) void k_labg(const short* __restrict__ hsb,
                                              const short* __restrict__ Wg_hi,
                                              const short* __restrict__ Wg_lo,
                                              const int* __restrict__ ys,
                                              const float* __restrict__ bias,
                                              float* __restrict__ ll) {
  __shared__ short As[128 * 64];
  __shared__ short Bh[128 * 64];
  __shared__ short Bl[128 * 64];

  int mt = blockIdx.x, b = blockIdx.y;
  int t0 = mt * 128;
  int tid = threadIdx.x;
  int lane = tid & 63, wave = tid >> 6;
  int wm = wave >> 1, wn = wave & 1;
  int lrow = lane & 15, lkhi = lane >> 4;

  const short* gaBase = hsb + (size_t)(b * NT + t0 + wave * 32 + (lane >> 3)) * ND + (lane & 7) * 8;
  const short* ghBase = Wg_hi + (size_t)(b * 128 + wave * 32 + (lane >> 3)) * ND + (lane & 7) * 8;
  const short* glBase = Wg_lo + (size_t)(b * 128 + wave * 32 + (lane >> 3)) * ND + (lane & 7) * 8;

  float4v acc[4][4];
#pragma unroll
  for (int m = 0; m < 4; ++m)
#pragma unroll
    for (int n = 0; n < 4; ++n)
#pragma unroll
      for (int j = 0; j < 4; ++j) acc[m][n][j] = 0.f;

  for (int s = 0; s < 8; ++s) {
    int k0 = s * 64;
#pragma unroll
    for (int i = 0; i < 4; ++i) {
      g2lds16(gaBase + (size_t)(i * 8) * ND + k0, &As[(wave * 32 + i * 8) * 64]);
      g2lds16(ghBase + (size_t)(i * 8) * ND + k0, &Bh[(wave * 32 + i * 8) * 64]);
      g2lds16(glBase + (size_t)(i * 8) * ND + k0, &Bl[(wave * 32 + i * 8) * 64]);
    }
    __syncthreads();
#pragma unroll
    for (int kk = 0; kk < 2; ++kk) {
      short8v av[4], bhv[4], blv2[4];
#pragma unroll
      for (int m = 0; m < 4; ++m) {
        int r = wm * 64 + m * 16 + lrow;
        int col = (kk * 32 + lkhi * 8) ^ ((r & 7) << 3);
        av[m] = *(const short8v*)&As[r * 64 + col];
      }
#pragma unroll
      for (int n = 0; n < 4; ++n) {
        int r = wn * 64 + n * 16 + lrow;
        int col = (kk * 32 + lkhi * 8) ^ ((r & 7) << 3);
        bhv[n] = *(const short8v*)&Bh[r * 64 + col];
        blv2[n] = *(const short8v*)&Bl[r * 64 + col];
      }
#pragma unroll
      for (int m = 0; m < 4; ++m)
#pragma unroll
        for (int n = 0; n < 4; ++n) {
          acc[m][n] = __builtin_amdgcn_mfma_f32_16x16x32_bf16(av[m], bhv[n], acc[m][n], 0, 0, 0);
          acc[m][n] = __builtin_amdgcn_mfma_f32_16x16x32_bf16(av[m], blv2[n], acc[m][n], 0, 0, 0);
        }
    }
    __syncthreads();
  }

  // epilogue: bias per u-row; TRANSPOSED write ll[(b*NLL+u)*NT + t]
  float bu[4]; bool uval[4];
#pragma unroll
  for (int n = 0; n < 4; ++n) {
    int u = wn * 64 + n * 16 + lrow;
    uval[n] = u < NU + 1;
    int lab = (u == 0) ? 0 : (uval[n] ? ys[b * NU + u - 1] : 0);
    bu[n] = uval[n] ? bias[lab] : 0.f;
  }
#pragma unroll
  for (int m = 0; m < 4; ++m)
#pragma unroll
    for (int j = 0; j < 4; ++j) {
      int trow = t0 + wm * 64 + m * 16 + lkhi * 4 + j;
      if (trow < NT) {
#pragma unroll
        for (int n = 0; n < 4; ++n) {
          int u = wn * 64 + n * 16 + lrow;
          if (uval[n])
            ll[((size_t)(b * NLL + u)) * NT + trow] = acc[m][n][j] + bu[n];
        }
      }
    }
}

// -------- kernel 5: per-chunk partial logsumexp of hs@W + b (bf16 MFMA) ----
// L2-aware order: XCD slab -> superblocks of 8 m-tiles, mloc fastest.
__global__ __launch_bounds__(256) void k_denom(const short* __restrict__ hsb,
                                               const short* __restrict__ WT,
                                               const float* __restrict__ bias,
                                               float* __restrict__ pm,
                                               float* __restrict__ ps) {
  __shared__ short As[128 * 64];
  __shared__ short Ws[128 * 64];
  __shared__ float mred[128][2];
  __shared__ float sred[128][2];

  int lin = blockIdx.x;                       // 5000 = 8 * 625
  int o = (lin & 7) * 625 + (lin >> 3);       // XCD-contiguous slab
  int mt, chunk;
  if (o < 4800) {                             // 15 superblocks x (8 mt x 40 ch)
    int sb = o / 320, w = o % 320;
    mt = sb * 8 + (w & 7);                    // mloc fastest: concurrent blocks
    chunk = w >> 3;                           //  share 8 hsb tiles + ~12 WT chunks
  } else {                                    // tail: 5 mt x 40 ch
    int w = o - 4800;
    mt = 120 + (w % 5);
    chunk = w / 5;
  }
  int t0 = mt * 128;
  int n0 = chunk * 128;
  int tid = threadIdx.x;
  int lane = tid & 63, wave = tid >> 6;
  int wm = wave >> 1, wn = wave & 1;
  int lrow = lane & 15, lkhi = lane >> 4;

  const short* gaBase = hsb + (size_t)(t0 + wave * 32 + (lane >> 3)) * ND + (lane & 7) * 8;
  const short* gwBase = WT + (size_t)(n0 + wave * 32 + (lane >> 3)) * ND + (lane & 7) * 8;

  float4v acc[4][4];
#pragma unroll
  for (int m = 0; m < 4; ++m)
#pragma unroll
    for (int n = 0; n < 4; ++n)
#pragma unroll
      for (int j = 0; j < 4; ++j) acc[m][n][j] = 0.f;

  auto stage = [&](int s) {
    int k0 = s * 64;
#pragma unroll
    for (int i = 0; i < 4; ++i) {
      g2lds16(gaBase + (size_t)(i * 8) * ND + k0, &As[(wave * 32 + i * 8) * 64]);
      g2lds16(gwBase + (size_t)(i * 8) * ND + k0, &Ws[(wave * 32 + i * 8) * 64]);
    }
  };
  auto compute = [&]() {
#pragma unroll
    for (int kk = 0; kk < 2; ++kk) {
      short8v av[4], wv[4];
#pragma unroll
      for (int m = 0; m < 4; ++m) {
        int r = wm * 64 + m * 16 + lrow;
        int col = (kk * 32 + lkhi * 8) ^ ((r & 7) << 3);
        av[m] = *(const short8v*)&As[r * 64 + col];
      }
#pragma unroll
      for (int n = 0; n < 4; ++n) {
        int r = wn * 64 + n * 16 + lrow;
        int col = (kk * 32 + lkhi * 8) ^ ((r & 7) << 3);
        wv[n] = *(const short8v*)&Ws[r * 64 + col];
      }
#pragma unroll
      for (int m = 0; m < 4; ++m)
#pragma unroll
        for (int n = 0; n < 4; ++n)
          acc[m][n] = __builtin_amdgcn_mfma_f32_16x16x32_bf16(av[m], wv[n], acc[m][n], 0, 0, 0);
    }
  };

  for (int s = 0; s < 8; ++s) {
    stage(s);
    __syncthreads();
    compute();
    __syncthreads();
  }

  float bcol[4]; bool cval[4];
#pragma unroll
  for (int n = 0; n < 4; ++n) {
    int c = n0 + wn * 64 + n * 16 + lrow;
    cval[n] = c < NV;
    bcol[n] = cval[n] ? bias[c] : 0.f;
  }
#pragma unroll
  for (int m = 0; m < 4; ++m)
#pragma unroll
    for (int j = 0; j < 4; ++j) {
      float mx = NEGINF;
#pragma unroll
      for (int n = 0; n < 4; ++n) {
        float v = cval[n] ? acc[m][n][j] + bcol[n] : NEGINF;
        mx = fmaxf(mx, v);
      }
#pragma unroll
      for (int d = 1; d < 16; d <<= 1) mx = fmaxf(mx, __shfl_xor(mx, d));
      float mxc = fmaxf(mx, -3.0e38f);   // NaN guard (all-invalid half-tile)
      float p = 0.f;
#pragma unroll
      for (int n = 0; n < 4; ++n) {
        float v = cval[n] ? acc[m][n][j] + bcol[n] : NEGINF;
        p += __expf(v - mxc);
      }
#pragma unroll
      for (int d = 1; d < 16; d <<= 1) p += __shfl_xor(p, d);
      if (lrow == 0) {
        int rloc = wm * 64 + m * 16 + lkhi * 4 + j;
        mred[rloc][wn] = mx;
        sred[rloc][wn] = p;
      }
    }
  __syncthreads();
  if (tid < 128) {
    int row = t0 + tid;
    float m0 = mred[tid][0], m1 = mred[tid][1];
    float m = fmaxf(m0, m1);
    float ss = 0.f;
    if (m != NEGINF)
      ss = ((m0 == NEGINF) ? 0.f : sred[tid][0] * __expf(m0 - m))
         + ((m1 == NEGINF) ? 0.f : sred[tid][1] * __expf(m1 - m));
    pm[(size_t)chunk * NM + row] = m;
    ps[(size_t)chunk * NM + row] = ss;
  }
}

// -------- kernel 5b: combine 40 chunk partials -> denom[row] ---------------
__global__ __launch_bounds__(256) void k_dred(const float* __restrict__ pm,
                                              const float* __restrict__ ps,
                                              float* __restrict__ denom) {
  int row = blockIdx.x * 256 + threadIdx.x;
  if (row >= NM) return;
  float m = NEGINF, s = 0.f;
  for (int c = 0; c < NCH; ++c) {
    float mc = pm[(size_t)c * NM + row];
    float sc = ps[(size_t)c * NM + row];
    if (mc == NEGINF) continue;
    if (mc > m) { s = s * __expf(m - mc) + sc; m = mc; }
    else        { s += sc * __expf(mc - m); }
  }
  denom[row] = m + __logf(s);
}

// -------- kernel 6: fwd (blocks 0..15) || bwd (blocks 16..31) --------------
// ll is [b][u][t] u-major (stride NLL rows): lane reads its own t-row.
__global__ __launch_bounds__(64) void k_fwdbwd(const float* __restrict__ ll,
                                               const float* __restrict__ denom,
                                               const int* __restrict__ ys,
                                               float* __restrict__ aod,
                                               float* __restrict__ bp) {
  __shared__ float denS[NT];
  __shared__ float blkS[NT];
  int bid = blockIdx.x;
  int l = threadIdx.x;
  int b = (bid < NB) ? bid : bid - NB;
  const float* llb = ll + (size_t)b * NLL * NT;
  const float* denb = denom + b * NT;
#pragma unroll
  for (int i = 0; i < 16; ++i) {
    int idx = i * 64 + l;
    if (idx < NT) { denS[idx] = denb[idx]; blkS[idx] = llb[idx]; }  // row 0 = blank
  }
  __syncthreads();
  const float* lrow = llb + (size_t)(1 + l) * NT;   // this lane's label row

  if (bid < NB) {
    // ---------------- forward ----------------
    int lab = ys[b * NU + l];
    int labp = ys[b * NU + ((l >= 1) ? (l - 1) : 0)];
    bool skip = (l >= 1) && (lab != labp);
    float* aodb = aod + (size_t)b * NT * NU;

    float den = denS[0];
    float ae = (l == 0) ? (blkS[0] - den) * LOG2E : SENTL;
    float ao = (l == 0) ? (lrow[0] - den) * LOG2E : SENTL;
    aodb[l] = ao;

    float cl[16];
#pragma unroll
    for (int j = 0; j < 16; ++j) {
      int tt = 1 + j; if (tt > NT - 1) tt = NT - 1;
      cl[j] = lrow[tt];
    }
    for (int g = 0; g < 63; ++g) {
      float nl[16];
      if (g < 62) {
#pragma unroll
        for (int j = 0; j < 16; ++j) {
          int tt = 17 + g * 16 + j; if (tt > NT - 1) tt = NT - 1;
          nl[j] = lrow[tt];
        }
      } else {
#pragma unroll
        for (int j = 0; j < 16; ++j) nl[j] = 0.f;
      }
#pragma unroll
      for (int j = 0; j < 16; ++j) {
        int t = 1 + g * 16 + j;
        if (t < NT) {
          float d2 = denS[t];
          float pb = (blkS[t] - d2) * LOG2E, pl = (cl[j] - d2) * LOG2E;
          float po = dpp_shr1(ao); if (l == 0) po = SENTL;
          float aen = pb + lae2s(ae, po);
          float aon = pl + lae3s(ao, ae, skip ? po : SENTL);
          ae = aen; ao = aon;
          aodb[t * NU + l] = ao;
        }
      }
#pragma unroll
      for (int j = 0; j < 16; ++j) cl[j] = nl[j];
    }
  } else {
    // ---------------- backward ----------------
    int lab = ys[b * NU + l];
    int labn = ys[b * NU + ((l < NU - 1) ? (l + 1) : l)];
    bool skipn = (l < NU - 1) && (labn != lab);
    float* bpb = bp + (size_t)b * NT * NU;

    float bo = (l == NU - 1) ? 0.0f : SENTL;
    float be = SENTL;
    float b128 = 0.0f;
    bpb[(NT - 1) * NU + l] = bo;

    float blv[16];
#pragma unroll
    for (int j = 0; j < 16; ++j) {
      int tt = NT - 2 - j; if (tt < 0) tt = 0;
      blv[j] = lrow[tt + 1];
    }
    for (int g = 0; g < 63; ++g) {
      float nl2[16];
      if (g < 62) {
#pragma unroll
        for (int j = 0; j < 16; ++j) {
          int tt = NT - 2 - 16 * (g + 1) - j; if (tt < 0) tt = 0;
          nl2[j] = lrow[tt + 1];
        }
      } else {
#pragma unroll
        for (int j = 0; j < 16; ++j) nl2[j] = 0.f;
      }
#pragma unroll
      for (int j = 0; j < 16; ++j) {
        int t = NT - 2 - 16 * g - j;
        if (t >= 0) {
          float d2 = denS[t + 1];
          float pbv = (blkS[t + 1] - d2) * LOG2E, plv = (blv[j] - d2) * LOG2E;
          float me = pbv + be;
          float mo = plv + bo;
          float m128 = pbv + b128;
          float ne = dpp_shl1(me); if (l == NU - 1) ne = m128;
          float no = dpp_shl1(mo); if (l == NU - 1) no = SENTL;
          float ben = lae2s(me, mo);
          float bon = lae3s(mo, ne, skipn ? no : SENTL);
          bpb[t * NU + l] = lsub2(bon, mo);
          be = ben; bo = bon; b128 = m128;
        }
      }
#pragma unroll
      for (int j = 0; j < 16; ++j) blv[j] = nl2[j];
    }
  }
}

// -------- kernel 7: loss = mean_b( -sum_u lse_t(alpha+bp) / count ) --------
__global__ __launch_bounds__(512) void k_loss(const float* __restrict__ aod,
                                              const float* __restrict__ bp,
                                              const int* __restrict__ hlens,
                                              float* __restrict__ out) {
  __shared__ float ms[8][64], ss[8][64];
  int b = blockIdx.x, tid = threadIdx.x;
  int w = tid >> 6, l = tid & 63;
  const float* ab = aod + (size_t)b * NT * NU;
  const float* pb = bp + (size_t)b * NT * NU;
  float m = NEGINF, s = 0.f;
  int t0 = w * 125, t1 = t0 + 125;
  for (int t = t0; t < t1; ++t) {
    float x = ab[t * NU + l] + pb[t * NU + l];
    if (__builtin_isnan(x) || x < -1.0e29f) continue;   // sentinel == -inf
    if (x > m) { s = s * fexp2(m - x) + 1.0f; m = x; }
    else       { s += fexp2(x - m); }
  }
  ms[w][l] = m; ss[w][l] = s;
  __syncthreads();
  if (w == 0) {
    float mm = NEGINF;
#pragma unroll
    for (int i = 0; i < 8; ++i) mm = fmaxf(mm, ms[i][l]);
    float lu;
    if (mm == NEGINF) lu = NEGINF;
    else {
      float st = 0.f;
#pragma unroll
      for (int i = 0; i < 8; ++i)
        st += (ms[i][l] == NEGINF) ? 0.f : ss[i][l] * fexp2(ms[i][l] - mm);
      lu = (mm + flog2(st)) * LN2F;
    }
    bool msk = __builtin_isinf(lu);
    float sv = msk ? 0.f : lu;
    float cv = msk ? 0.f : 1.f;
#pragma unroll
    for (int d = 1; d < 64; d <<= 1) { sv += __shfl_xor(sv, d); cv += __shfl_xor(cv, d); }
    if (l == 0) {
      float lf = sv / cv;
      if (hlens[b] < NU) lf = 0.f;
      atomicAdd(out, -lf * (1.0f / NB));
    }
  }
}

// ---------------------------------------------------------------------------
extern "C" void kernel_launch(void* const* d_in, const int* in_sizes, int n_in,
                              void* d_out, int out_size, void* d_ws, size_t ws_size,
                              hipStream_t stream) {
  const float* hs    = (const float*)d_in[0];
  const int*   hlens = (const int*)d_in[1];
  const int*   ys    = (const int*)d_in[2];
  const float* W     = (const float*)d_in[4];
  const float* bias  = (const float*)d_in[5];
  float* out = (float*)d_out;

  char* ws = (char*)d_ws;
  short* hsb   = (short*)(ws + 0);           // 16,384,000 B  [16000][512] bf16 (swizzled)
  short* WT    = (short*)(ws + 16384000);    //  5,242,880 B  [5120][512] bf16 hi (swizzled)
  short* WTlo  = (short*)(ws + 21626880);    //  5,242,880 B  [5120][512] bf16 lo (swizzled)
  float* pm    = (float*)(ws + 26869760);    //  2,560,000 B  [40][16000]; dead after k_dred
  float* psv   = (float*)(ws + 29429760);    //  2,560,000 B
  float* dnm   = (float*)(ws + 31989760);    //     64,000 B
  float* ll    = (float*)(ws + 32053760);    //  4,608,000 B  [16][72][1000] f32 (end 36,661,760)
  // after k_dred: pm/psv dead -> Wg_hi/lo alias them
  short* Wg_hi = (short*)(ws + 26869760);    //  2,097,152 B  [16][128][512] bf16 (swizzled)
  short* Wg_lo = (short*)(ws + 28966912);    //  2,097,152 B  (ends 31,064,064)
  // after k_labg: hsb dead -> aod/bp alias it
  float* aod   = (float*)(ws + 0);           //  4,096,000 B
  float* bpb   = (float*)(ws + 4096000);     //  4,096,000 B

  k_zero<<<1, 64, 0, stream>>>(out);
  k_cvt_hs<<<4000, 256, 0, stream>>>(hs, hsb);
  k_cvt_wt<<<dim3(80, 8), 256, 0, stream>>>(W, WT, WTlo);
  k_denom<<<5000, 256, 0, stream>>>(hsb, WT, bias, pm, psv);
  k_dred<<<63, 256, 0, stream>>>(pm, psv, dnm);
  k_gather2<<<dim3(128, 16), 64, 0, stream>>>(WT, WTlo, ys, Wg_hi, Wg_lo);
  k_labg<<<dim3(8, 16), 256, 0, stream>>>(hsb, Wg_hi, Wg_lo, ys, bias, ll);
  k_fwdbwd<<<32, 64, 0, stream>>>(ll, dnm, ys, aod, bpb);
  k_loss<<<16, 512, 0, stream>>>(aod, bpb, hlens, out);
}